// Round 1
// baseline (3687.843 us; speedup 1.0000x reference)
//
#include <hip/hip_runtime.h>
#include <math.h>
#include <stdint.h>

#define N0   3000
#define NE   96000
#define INC  512
#define HIDF 256
#define OUTC 64
#define KP1  2000
#define KP2  1000
#define KP3  500

#define TS 64
#define BK 16

// ---------------- adjacency build ----------------
static __global__ void build_A_k(const int* __restrict__ ei, float* __restrict__ A) {
  int e = blockIdx.x * blockDim.x + threadIdx.x;
  if (e < NE) {
    int s = ei[e], d = ei[NE + e];
    atomicAdd(&A[(long long)d * N0 + s], 1.0f);
  }
}

static __global__ void count_src_k(const int* __restrict__ ei, int* __restrict__ cnt) {
  int e = blockIdx.x * blockDim.x + threadIdx.x;
  if (e < NE) atomicAdd(&cnt[ei[e]], 1);
}

static __global__ __launch_bounds__(1024) void scan_excl_k(const int* __restrict__ cnt,
                                                           int* __restrict__ start, int n) {
  __shared__ int s[4096];
  int tid = threadIdx.x;
  for (int i = tid; i < 4096; i += blockDim.x) s[i] = (i < n) ? cnt[i] : 0;
  __syncthreads();
  for (int d = 1; d < 4096; d <<= 1) {
    int v[4];
    int r = 0;
    for (int i = tid; i < 4096; i += blockDim.x, ++r) v[r] = (i >= d) ? s[i - d] : 0;
    __syncthreads();
    r = 0;
    for (int i = tid; i < 4096; i += blockDim.x, ++r) s[i] += v[r];
    __syncthreads();
  }
  for (int i = tid; i < n; i += blockDim.x) start[i] = (i == 0) ? 0 : s[i - 1];
  if (tid == 0) start[n] = s[n - 1];
}

static __global__ void scatter_edges_k(const int* __restrict__ ei, const int* __restrict__ start,
                                       int* __restrict__ fill, int* __restrict__ bucket) {
  int e = blockIdx.x * blockDim.x + threadIdx.x;
  if (e < NE) {
    int s = ei[e], d = ei[NE + e];
    int pos = start[s] + atomicAdd(&fill[s], 1);
    bucket[pos] = d;
  }
}

// B[i,j] += A[i,k]*A[k,j]  via  edge e2=(j->k) x out-edges (k->i)
static __global__ void spgemm_k(const int* __restrict__ ei, const int* __restrict__ start,
                                const int* __restrict__ bucket, float* __restrict__ B) {
  int e = blockIdx.x * blockDim.x + threadIdx.x;
  if (e < NE) {
    int j = ei[e], k = ei[NE + e];
    int b = start[k], en = start[k + 1];
    for (int t = b; t < en; ++t) {
      int i = bucket[t];
      atomicAdd(&B[(long long)i * N0 + j], 1.0f);
    }
  }
}

// B = (B + 2A) with zeroed diagonal   (augment(A) = (A^2 + 2A) offdiag)
static __global__ void augment_finish_k(float* __restrict__ B, const float* __restrict__ A, int n) {
  int idx = blockIdx.x * blockDim.x + threadIdx.x;
  int tot = n * n;
  if (idx < tot) {
    int i = idx / n, j = idx - i * n;
    float v = B[idx] + 2.0f * A[idx];
    B[idx] = (i == j) ? 0.0f : v;
  }
}

// ---------------- dense fp32 GEMM: C = A @ B ----------------
static __global__ __launch_bounds__(256) void sgemm_k(const float* __restrict__ A,
                                                      const float* __restrict__ B,
                                                      float* __restrict__ C,
                                                      int M, int N, int K) {
  __shared__ float As[BK][TS + 4];
  __shared__ float Bs[BK][TS + 4];
  int tid = threadIdx.x;
  int tx = tid & 15, ty = tid >> 4;
  int bm = blockIdx.y * TS, bn = blockIdx.x * TS;
  float acc[4][4] = {};
  for (int k0 = 0; k0 < K; k0 += BK) {
    for (int t = tid; t < TS * BK; t += 256) {
      int r = t >> 4, c = t & 15;
      int gr = bm + r, gc = k0 + c;
      As[c][r] = (gr < M && gc < K) ? A[(long long)gr * K + gc] : 0.0f;
    }
    for (int t = tid; t < TS * BK; t += 256) {
      int r = t >> 6, c = t & 63;
      int gr = k0 + r, gc = bn + c;
      Bs[r][c] = (gr < K && gc < N) ? B[(long long)gr * N + gc] : 0.0f;
    }
    __syncthreads();
#pragma unroll
    for (int kk = 0; kk < BK; ++kk) {
      float a[4], b[4];
#pragma unroll
      for (int i = 0; i < 4; ++i) a[i] = As[kk][ty * 4 + i];
#pragma unroll
      for (int j = 0; j < 4; ++j) b[j] = Bs[kk][tx * 4 + j];
#pragma unroll
      for (int i = 0; i < 4; ++i)
#pragma unroll
        for (int j = 0; j < 4; ++j) acc[i][j] += a[i] * b[j];
    }
    __syncthreads();
  }
  for (int i = 0; i < 4; ++i) {
    int gm = bm + ty * 4 + i;
    if (gm < M) {
      for (int j = 0; j < 4; ++j) {
        int gn = bn + tx * 4 + j;
        if (gn < N) C[(long long)gm * N + gn] = acc[i][j];
      }
    }
  }
}

// ---------------- gcn_conv helpers ----------------
static __global__ void rowsum_dis_k(const float* __restrict__ A, int n, float* __restrict__ dis) {
  int row = blockIdx.x;
  float s = 0.f;
  for (int j = threadIdx.x; j < n; j += blockDim.x) s += A[(long long)row * n + j];
  __shared__ float sh[8];
  int lane = threadIdx.x & 63, wid = threadIdx.x >> 6;
#pragma unroll
  for (int o = 32; o > 0; o >>= 1) s += __shfl_down(s, o, 64);
  if (lane == 0) sh[wid] = s;
  __syncthreads();
  if (threadIdx.x == 0) {
    float t = 0.f;
    int nw = (blockDim.x + 63) >> 6;
    for (int w = 0; w < nw; ++w) t += sh[w];
    // deg = rowsum + 2 (Ah = A + 2I), always > 0
    dis[row] = rsqrtf(t + 2.0f);
  }
}

static __global__ void scale_rows_k(const float* __restrict__ xw, const float* __restrict__ dis,
                                    float* __restrict__ y, int n, int f) {
  int idx = blockIdx.x * blockDim.x + threadIdx.x;
  if (idx < n * f) y[idx] = xw[idx] * dis[idx / f];
}

static __global__ void conv_epi_k(const float* __restrict__ z, const float* __restrict__ xw,
                                  const float* __restrict__ dis, const float* __restrict__ b,
                                  float* __restrict__ out, int n, int f, int relu) {
  int idx = blockIdx.x * blockDim.x + threadIdx.x;
  if (idx < n * f) {
    int i = idx / f, j = idx - i * f;
    float di = dis[i];
    float v = di * z[idx] + 2.0f * di * di * xw[idx] + b[j];
    if (relu) v = fmaxf(v, 0.0f);
    out[idx] = v;
  }
}

// ---------------- pooling ----------------
static __global__ void norm_k(const float* __restrict__ w, int n, float* __restrict__ out) {
  float s = 0.f;
  for (int i = threadIdx.x; i < n; i += blockDim.x) { float v = w[i]; s += v * v; }
  __shared__ float sh[8];
  int lane = threadIdx.x & 63, wid = threadIdx.x >> 6;
#pragma unroll
  for (int o = 32; o > 0; o >>= 1) s += __shfl_down(s, o, 64);
  if (lane == 0) sh[wid] = s;
  __syncthreads();
  if (threadIdx.x == 0) {
    float t = 0.f;
    int nw = (blockDim.x + 63) >> 6;
    for (int w2 = 0; w2 < nw; ++w2) t += sh[w2];
    out[0] = sqrtf(t);
  }
}

static __global__ void score_k(const float* __restrict__ x, const float* __restrict__ w,
                               const float* __restrict__ nrm, float* __restrict__ sc, int f) {
  int row = blockIdx.x;
  float s = 0.f;
  for (int j = threadIdx.x; j < f; j += blockDim.x) s += x[(long long)row * f + j] * w[j];
  __shared__ float sh[8];
  int lane = threadIdx.x & 63, wid = threadIdx.x >> 6;
#pragma unroll
  for (int o = 32; o > 0; o >>= 1) s += __shfl_down(s, o, 64);
  if (lane == 0) sh[wid] = s;
  __syncthreads();
  if (threadIdx.x == 0) {
    float t = 0.f;
    int nw = (blockDim.x + 63) >> 6;
    for (int w2 = 0; w2 < nw; ++w2) t += sh[w2];
    sc[row] = tanhf(t / nrm[0]);
  }
}

// full bitonic sort of 4096 (value desc, index asc) -> exact top_k semantics
static __global__ __launch_bounds__(1024) void topk_sort_k(const float* __restrict__ sc, int n, int k,
                                                           int* __restrict__ perm, float* __restrict__ sv) {
  __shared__ float v[4096];
  __shared__ int ix[4096];
  int tid = threadIdx.x;
  for (int i = tid; i < 4096; i += 1024) {
    v[i] = (i < n) ? sc[i] : -INFINITY;
    ix[i] = i;
  }
  __syncthreads();
  for (int size = 2; size <= 4096; size <<= 1) {
    for (int stride = size >> 1; stride > 0; stride >>= 1) {
      for (int i = tid; i < 4096; i += 1024) {
        int j = i ^ stride;
        if (j > i) {
          bool up = ((i & size) == 0);  // descending region
          float vi = v[i], vj = v[j];
          int ii = ix[i], ij = ix[j];
          bool iBefore = (vi > vj) || (vi == vj && ii < ij);
          if (up ? !iBefore : iBefore) {
            v[i] = vj; v[j] = vi; ix[i] = ij; ix[j] = ii;
          }
        }
      }
      __syncthreads();
    }
  }
  for (int i = tid; i < k; i += 1024) { perm[i] = ix[i]; sv[i] = v[i]; }
}

static __global__ void gather2d_k(const float* __restrict__ B, const int* __restrict__ perm,
                                  float* __restrict__ Aout, int k, int ldB) {
  int idx = blockIdx.x * blockDim.x + threadIdx.x;
  if (idx < k * k) {
    int r = idx / k, c = idx - r * k;
    Aout[idx] = B[(long long)perm[r] * ldB + perm[c]];
  }
}

static __global__ void gather_scale_k(const float* __restrict__ x, const int* __restrict__ perm,
                                      const float* __restrict__ sv, float* __restrict__ out,
                                      int k, int f) {
  int idx = blockIdx.x * blockDim.x + threadIdx.x;
  if (idx < k * f) {
    int r = idx / f, j = idx - r * f;
    out[idx] = x[(long long)perm[r] * f + j] * sv[r];
  }
}

static __global__ void copy_k(const float* __restrict__ a, float* __restrict__ b, int n) {
  int idx = blockIdx.x * blockDim.x + threadIdx.x;
  if (idx < n) b[idx] = a[idx];
}

static __global__ void scatter_add_k(float* __restrict__ out, const int* __restrict__ perm,
                                     const float* __restrict__ h, int k, int f) {
  int idx = blockIdx.x * blockDim.x + threadIdx.x;
  if (idx < k * f) {
    int r = idx / f, j = idx - r * f;
    out[(long long)perm[r] * f + j] += h[idx];
  }
}

static __global__ void log_softmax_k(const float* __restrict__ h, float* __restrict__ out, int f) {
  int row = blockIdx.x;
  int j = threadIdx.x;  // blockDim = 64 == f
  float vv = h[row * f + j];
  float m = vv;
#pragma unroll
  for (int o = 32; o > 0; o >>= 1) m = fmaxf(m, __shfl_xor(m, o, 64));
  float e = expf(vv - m), s = e;
#pragma unroll
  for (int o = 32; o > 0; o >>= 1) s += __shfl_xor(s, o, 64);
  out[row * f + j] = vv - m - logf(s);
}

// ---------------- host ----------------
extern "C" void kernel_launch(void* const* d_in, const int* in_sizes, int n_in,
                              void* d_out, int out_size, void* d_ws, size_t ws_size,
                              hipStream_t stream) {
  const float* x  = (const float*)d_in[0];
  const int* ei   = (const int*)d_in[1];
  const float* W0 = (const float*)d_in[2];
  const float* b0 = (const float*)d_in[3];
  const float* W1 = (const float*)d_in[4];
  const float* b1 = (const float*)d_in[5];
  const float* W2 = (const float*)d_in[6];
  const float* b2 = (const float*)d_in[7];
  const float* W3 = (const float*)d_in[8];
  const float* b3 = (const float*)d_in[9];
  const float* p1 = (const float*)d_in[10];
  const float* p2 = (const float*)d_in[11];
  const float* p3 = (const float*)d_in[12];
  const float* U0 = (const float*)d_in[13];
  const float* c0 = (const float*)d_in[14];
  const float* U1 = (const float*)d_in[15];
  const float* c1 = (const float*)d_in[16];
  const float* U2 = (const float*)d_in[17];
  const float* c2 = (const float*)d_in[18];
  (void)in_sizes; (void)n_in; (void)out_size; (void)ws_size;

  char* basep = (char*)d_ws;
  size_t off = 0;
  auto alloc = [&](size_t bytes) {
    void* p = basep + off;
    off += (bytes + 255) & ~(size_t)255;
    return p;
  };

  float* A    = (float*)alloc((size_t)N0 * N0 * 4);    // 36 MB, lives whole call
  float* Bm   = (float*)alloc((size_t)N0 * N0 * 4);    // 36 MB, augment scratch (reused per level)
  float* A1   = (float*)alloc((size_t)KP1 * KP1 * 4);  // 16 MB
  float* A2   = (float*)alloc((size_t)KP2 * KP2 * 4);  // 4 MB
  float* A3   = (float*)alloc((size_t)KP3 * KP3 * 4);  // 1 MB
  float* xw   = (float*)alloc((size_t)N0 * HIDF * 4);
  float* yb   = (float*)alloc((size_t)N0 * HIDF * 4);
  float* zb   = (float*)alloc((size_t)N0 * HIDF * 4);
  float* x0   = (float*)alloc((size_t)N0 * HIDF * 4);
  float* x1   = (float*)alloc((size_t)KP1 * HIDF * 4);
  float* x2   = (float*)alloc((size_t)KP2 * HIDF * 4);
  float* x3   = (float*)alloc((size_t)KP3 * HIDF * 4);
  float* xin  = (float*)alloc((size_t)N0 * HIDF * 4);  // pooled-features / final-conv out
  float* ha   = (float*)alloc((size_t)N0 * HIDF * 4);
  float* hb   = (float*)alloc((size_t)N0 * HIDF * 4);
  float* sc   = (float*)alloc(N0 * 4);
  float* sv   = (float*)alloc(KP1 * 4);
  int* perm1  = (int*)alloc(KP1 * 4);
  int* perm2  = (int*)alloc(KP2 * 4);
  int* perm3  = (int*)alloc(KP3 * 4);
  float* dis  = (float*)alloc(N0 * 4);
  float* nrm  = (float*)alloc(256);
  int* cnt    = (int*)alloc(N0 * 4);
  int* startb = (int*)alloc((N0 + 4) * 4);
  int* fillb  = (int*)alloc(N0 * 4);
  int* bucket = (int*)alloc(NE * 4);

  auto gemm = [&](const float* Am, const float* Bmat, float* C, int M, int N, int K) {
    dim3 g((N + TS - 1) / TS, (M + TS - 1) / TS);
    sgemm_k<<<g, 256, 0, stream>>>(Am, Bmat, C, M, N, K);
  };

  // out = relu?(dis*(Adj@(dis*xW)) + 2*dis^2*xW + b)
  auto conv = [&](const float* Adj, int n, const float* xinp, int fin,
                  const float* W, const float* bias, int fout, float* out, int relu) {
    gemm(xinp, W, xw, n, fout, fin);
    rowsum_dis_k<<<n, 256, 0, stream>>>(Adj, n, dis);
    int nf = n * fout;
    scale_rows_k<<<(nf + 255) / 256, 256, 0, stream>>>(xw, dis, yb, n, fout);
    gemm(Adj, yb, zb, n, fout, n);
    conv_epi_k<<<(nf + 255) / 256, 256, 0, stream>>>(zb, xw, dis, bias, out, n, fout, relu);
  };

  auto pool = [&](const float* Baug, int n, const float* xfeat, const float* p, int k,
                  int* perm, float* Asub, float* xout) {
    norm_k<<<1, 256, 0, stream>>>(p, HIDF, nrm);
    score_k<<<n, 256, 0, stream>>>(xfeat, p, nrm, sc, HIDF);
    topk_sort_k<<<1, 1024, 0, stream>>>(sc, n, k, perm, sv);
    gather_scale_k<<<(k * HIDF + 255) / 256, 256, 0, stream>>>(xfeat, perm, sv, xout, k, HIDF);
    gather2d_k<<<(k * k + 255) / 256, 256, 0, stream>>>(Baug, perm, Asub, k, n);
  };

  // ---- build A ----
  hipMemsetAsync(A, 0, (size_t)N0 * N0 * 4, stream);
  build_A_k<<<(NE + 255) / 256, 256, 0, stream>>>(ei, A);

  // ---- down conv 0 ----
  conv(A, N0, x, INC, W0, b0, HIDF, x0, 1);

  // ---- augment(A) sparse: Bm = A^2 (+2A, zero diag) ----
  hipMemsetAsync(cnt, 0, N0 * 4, stream);
  hipMemsetAsync(fillb, 0, N0 * 4, stream);
  count_src_k<<<(NE + 255) / 256, 256, 0, stream>>>(ei, cnt);
  scan_excl_k<<<1, 1024, 0, stream>>>(cnt, startb, N0);
  scatter_edges_k<<<(NE + 255) / 256, 256, 0, stream>>>(ei, startb, fillb, bucket);
  hipMemsetAsync(Bm, 0, (size_t)N0 * N0 * 4, stream);
  spgemm_k<<<(NE + 255) / 256, 256, 0, stream>>>(ei, startb, bucket, Bm);
  augment_finish_k<<<(N0 * N0 + 255) / 256, 256, 0, stream>>>(Bm, A, N0);

  // ---- pool 1 / conv 1 ----
  pool(Bm, N0, x0, p1, KP1, perm1, A1, xin);
  conv(A1, KP1, xin, HIDF, W1, b1, HIDF, x1, 1);

  // ---- augment(A1) dense ----
  gemm(A1, A1, Bm, KP1, KP1, KP1);
  augment_finish_k<<<(KP1 * KP1 + 255) / 256, 256, 0, stream>>>(Bm, A1, KP1);

  // ---- pool 2 / conv 2 ----
  pool(Bm, KP1, x1, p2, KP2, perm2, A2, xin);
  conv(A2, KP2, xin, HIDF, W2, b2, HIDF, x2, 1);

  // ---- augment(A2) dense ----
  gemm(A2, A2, Bm, KP2, KP2, KP2);
  augment_finish_k<<<(KP2 * KP2 + 255) / 256, 256, 0, stream>>>(Bm, A2, KP2);

  // ---- pool 3 / conv 3 ----
  pool(Bm, KP2, x2, p3, KP3, perm3, A3, xin);
  conv(A3, KP3, xin, HIDF, W3, b3, HIDF, x3, 1);

  // ---- up path ----
  copy_k<<<(KP2 * HIDF + 255) / 256, 256, 0, stream>>>(x2, ha, KP2 * HIDF);
  scatter_add_k<<<(KP3 * HIDF + 255) / 256, 256, 0, stream>>>(ha, perm3, x3, KP3, HIDF);
  conv(A2, KP2, ha, HIDF, U0, c0, HIDF, hb, 1);

  copy_k<<<(KP1 * HIDF + 255) / 256, 256, 0, stream>>>(x1, ha, KP1 * HIDF);
  scatter_add_k<<<(KP2 * HIDF + 255) / 256, 256, 0, stream>>>(ha, perm2, hb, KP2, HIDF);
  conv(A1, KP1, ha, HIDF, U1, c1, HIDF, hb, 1);

  copy_k<<<(N0 * HIDF + 255) / 256, 256, 0, stream>>>(x0, ha, N0 * HIDF);
  scatter_add_k<<<(KP1 * HIDF + 255) / 256, 256, 0, stream>>>(ha, perm1, hb, KP1, HIDF);
  conv(A, N0, ha, HIDF, U2, c2, OUTC, xin, 0);

  // ---- log_softmax ----
  log_softmax_k<<<N0, 64, 0, stream>>>(xin, (float*)d_out, OUTC);
}

// Round 2
// 1357.289 us; speedup vs baseline: 2.7171x; 2.7171x over previous
//
#include <hip/hip_runtime.h>
#include <math.h>
#include <stdint.h>

#define N0   3000
#define NE   96000
#define INC  512
#define HIDF 256
#define OUTC 64
#define KP1  2000
#define KP2  1000
#define KP3  500

typedef __bf16 bf16x8 __attribute__((ext_vector_type(8)));
typedef float f32x4 __attribute__((ext_vector_type(4)));

// ---------------- CSR build ----------------
static __global__ void count2_k(const int* __restrict__ ei, int* __restrict__ cs, int* __restrict__ cd) {
  int e = blockIdx.x * blockDim.x + threadIdx.x;
  if (e < NE) { atomicAdd(&cs[ei[e]], 1); atomicAdd(&cd[ei[NE + e]], 1); }
}

static __global__ __launch_bounds__(1024) void scan_excl_k(const int* __restrict__ cnt,
                                                           int* __restrict__ start, int n) {
  __shared__ int s[4096];
  int tid = threadIdx.x;
  for (int i = tid; i < 4096; i += blockDim.x) s[i] = (i < n) ? cnt[i] : 0;
  __syncthreads();
  for (int d = 1; d < 4096; d <<= 1) {
    int v[4]; int r = 0;
    for (int i = tid; i < 4096; i += blockDim.x, ++r) v[r] = (i >= d) ? s[i - d] : 0;
    __syncthreads();
    r = 0;
    for (int i = tid; i < 4096; i += blockDim.x, ++r) s[i] += v[r];
    __syncthreads();
  }
  for (int i = tid; i < n; i += blockDim.x) start[i] = (i == 0) ? 0 : s[i - 1];
  if (tid == 0) start[n] = s[n - 1];
}

static __global__ void scatter2_k(const int* __restrict__ ei, const int* __restrict__ ss,
                                  const int* __restrict__ sd, int* __restrict__ fs,
                                  int* __restrict__ fd, int* __restrict__ bs, int* __restrict__ bd) {
  int e = blockIdx.x * blockDim.x + threadIdx.x;
  if (e < NE) {
    int s = ei[e], d = ei[NE + e];
    bs[ss[s] + atomicAdd(&fs[s], 1)] = d;   // out-neighbors by src
    bd[sd[d] + atomicAdd(&fd[d], 1)] = s;   // in-neighbors by dst
  }
}

static __global__ void dis0_k(const int* __restrict__ cd, float* __restrict__ dis0) {
  int i = blockIdx.x * blockDim.x + threadIdx.x;
  if (i < N0) dis0[i] = rsqrtf((float)cd[i] + 2.0f);
}

// ---------------- sparse A^2 (augment level 0) ----------------
static __global__ void spgemm_k(const int* __restrict__ ei, const int* __restrict__ start,
                                const int* __restrict__ bucket, float* __restrict__ B) {
  int e = blockIdx.x * blockDim.x + threadIdx.x;
  if (e < NE) {
    int j = ei[e], k = ei[NE + e];
    int b = start[k], en = start[k + 1];
    for (int t = b; t < en; ++t) atomicAdd(&B[(size_t)bucket[t] * N0 + j], 1.0f);
  }
}

static __global__ void add2A_k(const int* __restrict__ ei, float* __restrict__ B) {
  int e = blockIdx.x * blockDim.x + threadIdx.x;
  if (e < NE) atomicAdd(&B[(size_t)ei[NE + e] * N0 + ei[e]], 2.0f);
}

static __global__ void zdiag_k(float* __restrict__ B, int n) {
  int i = blockIdx.x * blockDim.x + threadIdx.x;
  if (i < n) B[(size_t)i * n + i] = 0.0f;
}

// B = (B + 2A) offdiag (levels 1-2, dense A)
static __global__ void augment_finish_k(float* __restrict__ B, const float* __restrict__ A, int n) {
  int idx = blockIdx.x * blockDim.x + threadIdx.x;
  if (idx < n * n) {
    int i = idx / n, j = idx - i * n;
    float v = B[idx] + 2.0f * A[idx];
    B[idx] = (i == j) ? 0.0f : v;
  }
}

// ---------------- SpMM: out[i][f] = sum over in-edges (s->i) y[s][f] ----------------
static __global__ void spmm_k(const int* __restrict__ start, const int* __restrict__ idx,
                              const float* __restrict__ y, float* __restrict__ out, int F) {
  int row = blockIdx.x;
  int b = start[row], e = start[row + 1];
  int f = threadIdx.x;  // blockDim == F
  __shared__ int nb[256];
  float acc = 0.f;
  for (int t0 = b; t0 < e; t0 += blockDim.x) {
    int m = min((int)blockDim.x, e - t0);
    __syncthreads();
    if (f < m) nb[f] = idx[t0 + f];
    __syncthreads();
    for (int t = 0; t < m; ++t) acc += y[(size_t)nb[t] * F + f];
  }
  out[(size_t)row * F + f] = acc;
}

// ---------------- bf16 converters ----------------
// row-major f32 [R][C] -> bf16 [R][Cp] hi (+lo), K-pad zeros
static __global__ void conv_hilo_k(const float* __restrict__ in, int R, int C, int Cp,
                                   __bf16* __restrict__ oh, __bf16* __restrict__ ol) {
  int idx = blockIdx.x * blockDim.x + threadIdx.x;
  if (idx < R * Cp) {
    int r = idx / Cp, c = idx - r * Cp;
    float v = (c < C) ? in[(size_t)r * C + c] : 0.f;
    __bf16 h = (__bf16)v;
    oh[idx] = h;
    if (ol) ol[idx] = (__bf16)(v - (float)h);
  }
}

// transpose+convert: f32 in[R][C] -> bf16 out[C][Rp] hi (+lo), pad zeros
static __global__ __launch_bounds__(256) void tconv_k(const float* __restrict__ in, int R, int C, int Rp,
                                                      __bf16* __restrict__ oh, __bf16* __restrict__ ol) {
  __shared__ float t[32][33];
  int r0 = blockIdx.x * 32, c0 = blockIdx.y * 32;
  int lr = threadIdx.x >> 5, lc = threadIdx.x & 31;
#pragma unroll
  for (int i = 0; i < 4; ++i) {
    int r = r0 + lr + i * 8, c = c0 + lc;
    t[lr + i * 8][lc] = (r < R && c < C) ? in[(size_t)r * C + c] : 0.f;
  }
  __syncthreads();
#pragma unroll
  for (int i = 0; i < 4; ++i) {
    int c = c0 + lr + i * 8, r = r0 + lc;
    if (c < C) {
      float v = t[lc][lr + i * 8];
      __bf16 h = (__bf16)v;
      oh[(size_t)c * Rp + r] = h;
      if (ol) ol[(size_t)c * Rp + r] = (__bf16)(v - (float)h);
    }
  }
}

// ---------------- MFMA GEMM: C = sum_seg A_s @ B_s^T ----------------
// A segs row-major [M][Kp] bf16, B segs row-major [N][Kp] bf16 (i.e. B transposed), Kp % 32 == 0
template <int BM, int BN>
static __global__ __launch_bounds__(256) void mgemm_k(
    const __bf16* __restrict__ A0, const __bf16* __restrict__ A1g, const __bf16* __restrict__ A2g,
    const __bf16* __restrict__ B0, const __bf16* __restrict__ B1g, const __bf16* __restrict__ B2g,
    int nseg, float* __restrict__ C, int M, int N, int Kp) {
  constexpr int FM = BM / 32, FN = BN / 32;
  __shared__ __bf16 As[BM][40];  // +8 pad: row stride 80B -> conflict-free-ish b128
  __shared__ __bf16 Bs[BN][40];
  int tid = threadIdx.x;
  int lane = tid & 63, wave = tid >> 6;
  int wx = wave & 1, wy = wave >> 1;
  int l15 = lane & 15, l4 = lane >> 4;
  int brow = blockIdx.y * BM, bcol = blockIdx.x * BN;
  int wrow = wy * (BM / 2), wcol = wx * (BN / 2);
  int srow = tid >> 2, scol = (tid & 3) * 8;
  f32x4 acc[FM][FN] = {};
  for (int s = 0; s < nseg; ++s) {
    const __bf16* Ag = (s == 0) ? A0 : (s == 1) ? A1g : A2g;
    const __bf16* Bg = (s == 0) ? B0 : (s == 1) ? B1g : B2g;
    for (int k0 = 0; k0 < Kp; k0 += 32) {
      __syncthreads();
#pragma unroll
      for (int r0 = 0; r0 < BM; r0 += 64) {
        int gr = brow + r0 + srow;
        bf16x8 v = {};
        if (gr < M) v = *(const bf16x8*)(Ag + (size_t)gr * Kp + k0 + scol);
        *(bf16x8*)(&As[r0 + srow][scol]) = v;
      }
#pragma unroll
      for (int r0 = 0; r0 < BN; r0 += 64) {
        int gc = bcol + r0 + srow;
        bf16x8 v = {};
        if (gc < N) v = *(const bf16x8*)(Bg + (size_t)gc * Kp + k0 + scol);
        *(bf16x8*)(&Bs[r0 + srow][scol]) = v;
      }
      __syncthreads();
      bf16x8 af[FM], bfv[FN];
#pragma unroll
      for (int i = 0; i < FM; ++i) af[i] = *(const bf16x8*)(&As[wrow + i * 16 + l15][l4 * 8]);
#pragma unroll
      for (int j = 0; j < FN; ++j) bfv[j] = *(const bf16x8*)(&Bs[wcol + j * 16 + l15][l4 * 8]);
#pragma unroll
      for (int i = 0; i < FM; ++i)
#pragma unroll
        for (int j = 0; j < FN; ++j)
          acc[i][j] = __builtin_amdgcn_mfma_f32_16x16x32_bf16(af[i], bfv[j], acc[i][j], 0, 0, 0);
    }
  }
#pragma unroll
  for (int i = 0; i < FM; ++i)
#pragma unroll
    for (int j = 0; j < FN; ++j) {
      int col = bcol + wcol + j * 16 + l15;
      if (col < N) {
#pragma unroll
        for (int q = 0; q < 4; ++q) {
          int row = brow + wrow + i * 16 + l4 * 4 + q;
          if (row < M) C[(size_t)row * N + col] = acc[i][j][q];
        }
      }
    }
}

// ---------------- gcn_conv helpers ----------------
static __global__ void rowsum_dis_k(const float* __restrict__ A, int n, float* __restrict__ dis) {
  int row = blockIdx.x;
  float s = 0.f;
  for (int j = threadIdx.x; j < n; j += blockDim.x) s += A[(size_t)row * n + j];
  __shared__ float sh[8];
  int lane = threadIdx.x & 63, wid = threadIdx.x >> 6;
#pragma unroll
  for (int o = 32; o > 0; o >>= 1) s += __shfl_down(s, o, 64);
  if (lane == 0) sh[wid] = s;
  __syncthreads();
  if (threadIdx.x == 0) {
    float t = 0.f;
    int nw = (blockDim.x + 63) >> 6;
    for (int w = 0; w < nw; ++w) t += sh[w];
    dis[row] = rsqrtf(t + 2.0f);
  }
}

static __global__ void scale_rows_k(const float* __restrict__ xw, const float* __restrict__ dis,
                                    float* __restrict__ y, int n, int f) {
  int idx = blockIdx.x * blockDim.x + threadIdx.x;
  if (idx < n * f) y[idx] = xw[idx] * dis[idx / f];
}

static __global__ void conv_epi_k(const float* __restrict__ z, const float* __restrict__ xw,
                                  const float* __restrict__ dis, const float* __restrict__ b,
                                  float* __restrict__ out, int n, int f, int relu) {
  int idx = blockIdx.x * blockDim.x + threadIdx.x;
  if (idx < n * f) {
    int i = idx / f, j = idx - i * f;
    float di = dis[i];
    float v = di * z[idx] + 2.0f * di * di * xw[idx] + b[j];
    if (relu) v = fmaxf(v, 0.0f);
    out[idx] = v;
  }
}

// ---------------- pooling ----------------
static __global__ void norm_k(const float* __restrict__ w, int n, float* __restrict__ out) {
  float s = 0.f;
  for (int i = threadIdx.x; i < n; i += blockDim.x) { float v = w[i]; s += v * v; }
  __shared__ float sh[8];
  int lane = threadIdx.x & 63, wid = threadIdx.x >> 6;
#pragma unroll
  for (int o = 32; o > 0; o >>= 1) s += __shfl_down(s, o, 64);
  if (lane == 0) sh[wid] = s;
  __syncthreads();
  if (threadIdx.x == 0) {
    float t = 0.f;
    int nw = (blockDim.x + 63) >> 6;
    for (int w2 = 0; w2 < nw; ++w2) t += sh[w2];
    out[0] = sqrtf(t);
  }
}

static __global__ void score_k(const float* __restrict__ x, const float* __restrict__ w,
                               const float* __restrict__ nrm, float* __restrict__ sc, int f) {
  int row = blockIdx.x;
  float s = 0.f;
  for (int j = threadIdx.x; j < f; j += blockDim.x) s += x[(size_t)row * f + j] * w[j];
  __shared__ float sh[8];
  int lane = threadIdx.x & 63, wid = threadIdx.x >> 6;
#pragma unroll
  for (int o = 32; o > 0; o >>= 1) s += __shfl_down(s, o, 64);
  if (lane == 0) sh[wid] = s;
  __syncthreads();
  if (threadIdx.x == 0) {
    float t = 0.f;
    int nw = (blockDim.x + 63) >> 6;
    for (int w2 = 0; w2 < nw; ++w2) t += sh[w2];
    sc[row] = tanhf(t / nrm[0]);
  }
}

static __global__ __launch_bounds__(1024) void topk_sort_k(const float* __restrict__ sc, int n, int k,
                                                           int* __restrict__ perm, float* __restrict__ sv) {
  __shared__ float v[4096];
  __shared__ int ix[4096];
  int tid = threadIdx.x;
  for (int i = tid; i < 4096; i += 1024) { v[i] = (i < n) ? sc[i] : -INFINITY; ix[i] = i; }
  __syncthreads();
  for (int size = 2; size <= 4096; size <<= 1) {
    for (int stride = size >> 1; stride > 0; stride >>= 1) {
      for (int i = tid; i < 4096; i += 1024) {
        int j = i ^ stride;
        if (j > i) {
          bool up = ((i & size) == 0);
          float vi = v[i], vj = v[j];
          int ii = ix[i], ij = ix[j];
          bool iBefore = (vi > vj) || (vi == vj && ii < ij);
          if (up ? !iBefore : iBefore) { v[i] = vj; v[j] = vi; ix[i] = ij; ix[j] = ii; }
        }
      }
      __syncthreads();
    }
  }
  for (int i = tid; i < k; i += 1024) { perm[i] = ix[i]; sv[i] = v[i]; }
}

static __global__ void gather2d_k(const float* __restrict__ B, const int* __restrict__ perm,
                                  float* __restrict__ Aout, int k, int ldB) {
  int idx = blockIdx.x * blockDim.x + threadIdx.x;
  if (idx < k * k) {
    int r = idx / k, c = idx - r * k;
    Aout[idx] = B[(size_t)perm[r] * ldB + perm[c]];
  }
}

static __global__ void gather_scale_k(const float* __restrict__ x, const int* __restrict__ perm,
                                      const float* __restrict__ sv, float* __restrict__ out,
                                      int k, int f) {
  int idx = blockIdx.x * blockDim.x + threadIdx.x;
  if (idx < k * f) {
    int r = idx / f, j = idx - r * f;
    out[idx] = x[(size_t)perm[r] * f + j] * sv[r];
  }
}

static __global__ void copy_k(const float* __restrict__ a, float* __restrict__ b, int n) {
  int idx = blockIdx.x * blockDim.x + threadIdx.x;
  if (idx < n) b[idx] = a[idx];
}

static __global__ void scatter_add_k(float* __restrict__ out, const int* __restrict__ perm,
                                     const float* __restrict__ h, int k, int f) {
  int idx = blockIdx.x * blockDim.x + threadIdx.x;
  if (idx < k * f) {
    int r = idx / f, j = idx - r * f;
    out[(size_t)perm[r] * f + j] += h[idx];
  }
}

static __global__ void log_softmax_k(const float* __restrict__ h, float* __restrict__ out, int f) {
  int row = blockIdx.x;
  int j = threadIdx.x;  // blockDim = 64 == f
  float vv = h[row * f + j];
  float m = vv;
#pragma unroll
  for (int o = 32; o > 0; o >>= 1) m = fmaxf(m, __shfl_xor(m, o, 64));
  float e = expf(vv - m), s = e;
#pragma unroll
  for (int o = 32; o > 0; o >>= 1) s += __shfl_xor(s, o, 64);
  out[row * f + j] = vv - m - logf(s);
}

// ---------------- host ----------------
extern "C" void kernel_launch(void* const* d_in, const int* in_sizes, int n_in,
                              void* d_out, int out_size, void* d_ws, size_t ws_size,
                              hipStream_t stream) {
  const float* x  = (const float*)d_in[0];
  const int* ei   = (const int*)d_in[1];
  const float* W0 = (const float*)d_in[2];
  const float* b0 = (const float*)d_in[3];
  const float* W1 = (const float*)d_in[4];
  const float* b1 = (const float*)d_in[5];
  const float* W2 = (const float*)d_in[6];
  const float* b2 = (const float*)d_in[7];
  const float* W3 = (const float*)d_in[8];
  const float* b3 = (const float*)d_in[9];
  const float* p1 = (const float*)d_in[10];
  const float* p2 = (const float*)d_in[11];
  const float* p3 = (const float*)d_in[12];
  const float* U0 = (const float*)d_in[13];
  const float* c0 = (const float*)d_in[14];
  const float* U1 = (const float*)d_in[15];
  const float* c1 = (const float*)d_in[16];
  const float* U2 = (const float*)d_in[17];
  const float* c2 = (const float*)d_in[18];
  (void)in_sizes; (void)n_in; (void)out_size; (void)ws_size;

  char* basep = (char*)d_ws;
  size_t off = 0;
  auto alloc = [&](size_t bytes) {
    void* p = basep + off;
    off += (bytes + 255) & ~(size_t)255;
    return p;
  };
  auto pad32 = [](int k) { return (k + 31) & ~31; };

  // fp32
  float* Bm  = (float*)alloc((size_t)N0 * N0 * 4);
  float* A1  = (float*)alloc((size_t)KP1 * KP1 * 4);
  float* A2  = (float*)alloc((size_t)KP2 * KP2 * 4);
  float* A3  = (float*)alloc((size_t)KP3 * KP3 * 4);
  float* xw  = (float*)alloc((size_t)N0 * HIDF * 4);
  float* yb  = (float*)alloc((size_t)N0 * HIDF * 4);
  float* zb  = (float*)alloc((size_t)N0 * HIDF * 4);
  float* x0  = (float*)alloc((size_t)N0 * HIDF * 4);
  float* x1  = (float*)alloc((size_t)KP1 * HIDF * 4);
  float* x2  = (float*)alloc((size_t)KP2 * HIDF * 4);
  float* x3  = (float*)alloc((size_t)KP3 * HIDF * 4);
  float* xin = (float*)alloc((size_t)N0 * HIDF * 4);
  float* ha  = (float*)alloc((size_t)N0 * HIDF * 4);
  float* hb  = (float*)alloc((size_t)N0 * HIDF * 4);
  // bf16 scratch
  __bf16* bfAh = (__bf16*)alloc((size_t)N0 * INC * 2);
  __bf16* bfAl = (__bf16*)alloc((size_t)N0 * INC * 2);
  __bf16* bfBh = (__bf16*)alloc((size_t)HIDF * 2016 * 2);
  __bf16* bfBl = (__bf16*)alloc((size_t)HIDF * 2016 * 2);
  __bf16* A1bf  = (__bf16*)alloc((size_t)KP1 * 2016 * 2);
  __bf16* A1tbf = (__bf16*)alloc((size_t)KP1 * 2016 * 2);
  __bf16* A2bh  = (__bf16*)alloc((size_t)KP2 * 1024 * 2);
  __bf16* A2bl  = (__bf16*)alloc((size_t)KP2 * 1024 * 2);
  __bf16* A2tbh = (__bf16*)alloc((size_t)KP2 * 1024 * 2);
  __bf16* A2tbl = (__bf16*)alloc((size_t)KP2 * 1024 * 2);
  __bf16* A3bh  = (__bf16*)alloc((size_t)KP3 * 512 * 2);
  __bf16* A3bl  = (__bf16*)alloc((size_t)KP3 * 512 * 2);
  // small
  float* sc   = (float*)alloc(N0 * 4);
  float* sv   = (float*)alloc(KP1 * 4);
  int* perm1  = (int*)alloc(KP1 * 4);
  int* perm2  = (int*)alloc(KP2 * 4);
  int* perm3  = (int*)alloc(KP3 * 4);
  float* dis  = (float*)alloc(N0 * 4);
  float* dis0 = (float*)alloc(N0 * 4);
  float* nrm  = (float*)alloc(256);
  int* cnt_s  = (int*)alloc(N0 * 4);
  int* cnt_d  = (int*)alloc(N0 * 4);
  int* st_s   = (int*)alloc((N0 + 4) * 4);
  int* st_d   = (int*)alloc((N0 + 4) * 4);
  int* fl_s   = (int*)alloc(N0 * 4);
  int* fl_d   = (int*)alloc(N0 * 4);
  int* bk_s   = (int*)alloc(NE * 4);
  int* bk_d   = (int*)alloc(NE * 4);

  auto mg64 = [&](const __bf16* a0, const __bf16* a1, const __bf16* a2,
                  const __bf16* bb0, const __bf16* bb1, const __bf16* bb2,
                  int nseg, float* C, int M, int N, int Kp) {
    dim3 g((N + 63) / 64, (M + 63) / 64);
    mgemm_k<64, 64><<<g, 256, 0, stream>>>(a0, a1, a2, bb0, bb1, bb2, nseg, C, M, N, Kp);
  };

  // feature GEMM: out[n][fout] = xin @ W, 3-seg hi/lo
  auto featgemm = [&](const float* xf, int n, int fin, const float* W, int fout, float* out) {
    int Kp = pad32(fin);
    conv_hilo_k<<<((size_t)n * Kp + 255) / 256, 256, 0, stream>>>(xf, n, fin, Kp, bfAh, bfAl);
    dim3 tg(Kp / 32, (fout + 31) / 32);
    tconv_k<<<tg, 256, 0, stream>>>(W, fin, fout, Kp, bfBh, bfBl);
    mg64(bfAh, bfAh, bfAl, bfBh, bfBl, bfBh, 3, out, n, fout, Kp);
  };

  auto tconv_y = [&](const float* y, int n) {
    int Rp = pad32(n);
    dim3 tg(Rp / 32, (HIDF + 31) / 32);
    tconv_k<<<tg, 256, 0, stream>>>(y, n, HIDF, Rp, bfBh, bfBl);
  };

  auto pool = [&](const float* Baug, int n, const float* xfeat, const float* p, int k,
                  int* perm, float* Asub, float* xout) {
    norm_k<<<1, 256, 0, stream>>>(p, HIDF, nrm);
    score_k<<<n, 256, 0, stream>>>(xfeat, p, nrm, sc, HIDF);
    topk_sort_k<<<1, 1024, 0, stream>>>(sc, n, k, perm, sv);
    gather_scale_k<<<(k * HIDF + 255) / 256, 256, 0, stream>>>(xfeat, perm, sv, xout, k, HIDF);
    gather2d_k<<<(k * k + 255) / 256, 256, 0, stream>>>(Baug, perm, Asub, k, n);
  };

  // ---- CSR build ----
  hipMemsetAsync(cnt_s, 0, N0 * 4, stream);
  hipMemsetAsync(cnt_d, 0, N0 * 4, stream);
  hipMemsetAsync(fl_s, 0, N0 * 4, stream);
  hipMemsetAsync(fl_d, 0, N0 * 4, stream);
  count2_k<<<(NE + 255) / 256, 256, 0, stream>>>(ei, cnt_s, cnt_d);
  scan_excl_k<<<1, 1024, 0, stream>>>(cnt_s, st_s, N0);
  scan_excl_k<<<1, 1024, 0, stream>>>(cnt_d, st_d, N0);
  scatter2_k<<<(NE + 255) / 256, 256, 0, stream>>>(ei, st_s, st_d, fl_s, fl_d, bk_s, bk_d);
  dis0_k<<<(N0 + 255) / 256, 256, 0, stream>>>(cnt_d, dis0);

  // ---- down conv 0 (sparse propagation) ----
  featgemm(x, N0, INC, W0, HIDF, xw);
  scale_rows_k<<<(N0 * HIDF + 255) / 256, 256, 0, stream>>>(xw, dis0, yb, N0, HIDF);
  spmm_k<<<N0, HIDF, 0, stream>>>(st_d, bk_d, yb, zb, HIDF);
  conv_epi_k<<<(N0 * HIDF + 255) / 256, 256, 0, stream>>>(zb, xw, dis0, b0, x0, N0, HIDF, 1);

  // ---- augment(A) sparse: Bm = (A^2 + 2A) offdiag ----
  hipMemsetAsync(Bm, 0, (size_t)N0 * N0 * 4, stream);
  spgemm_k<<<(NE + 255) / 256, 256, 0, stream>>>(ei, st_s, bk_s, Bm);
  add2A_k<<<(NE + 255) / 256, 256, 0, stream>>>(ei, Bm);
  zdiag_k<<<(N0 + 255) / 256, 256, 0, stream>>>(Bm, N0);

  // ---- pool 1 / conv 1 (A1 exact in bf16) ----
  pool(Bm, N0, x0, p1, KP1, perm1, A1, xin);
  conv_hilo_k<<<((size_t)KP1 * 2016 + 255) / 256, 256, 0, stream>>>(A1, KP1, KP1, 2016, A1bf, nullptr);
  {
    dim3 tg(2016 / 32, (KP1 + 31) / 32);
    tconv_k<<<tg, 256, 0, stream>>>(A1, KP1, KP1, 2016, A1tbf, nullptr);
  }
  featgemm(xin, KP1, HIDF, W1, HIDF, xw);
  rowsum_dis_k<<<KP1, 256, 0, stream>>>(A1, KP1, dis);
  scale_rows_k<<<(KP1 * HIDF + 255) / 256, 256, 0, stream>>>(xw, dis, yb, KP1, HIDF);
  tconv_y(yb, KP1);
  mg64(A1bf, A1bf, nullptr, bfBh, bfBl, nullptr, 2, zb, KP1, HIDF, 2016);
  conv_epi_k<<<(KP1 * HIDF + 255) / 256, 256, 0, stream>>>(zb, xw, dis, b1, x1, KP1, HIDF, 1);

  // ---- augment(A1): exact 1-seg MFMA, big tile ----
  {
    dim3 g((KP1 + 127) / 128, (KP1 + 127) / 128);
    mgemm_k<128, 128><<<g, 256, 0, stream>>>(A1bf, nullptr, nullptr, A1tbf, nullptr, nullptr,
                                             1, Bm, KP1, KP1, 2016);
  }
  augment_finish_k<<<((size_t)KP1 * KP1 + 255) / 256, 256, 0, stream>>>(Bm, A1, KP1);

  // ---- pool 2 / conv 2 (A2 hi/lo) ----
  pool(Bm, KP1, x1, p2, KP2, perm2, A2, xin);
  conv_hilo_k<<<((size_t)KP2 * 1024 + 255) / 256, 256, 0, stream>>>(A2, KP2, KP2, 1024, A2bh, A2bl);
  {
    dim3 tg(1024 / 32, (KP2 + 31) / 32);
    tconv_k<<<tg, 256, 0, stream>>>(A2, KP2, KP2, 1024, A2tbh, A2tbl);
  }
  featgemm(xin, KP2, HIDF, W2, HIDF, xw);
  rowsum_dis_k<<<KP2, 256, 0, stream>>>(A2, KP2, dis);
  scale_rows_k<<<(KP2 * HIDF + 255) / 256, 256, 0, stream>>>(xw, dis, yb, KP2, HIDF);
  tconv_y(yb, KP2);
  mg64(A2bh, A2bh, A2bl, bfBh, bfBl, bfBh, 3, zb, KP2, HIDF, 1024);
  conv_epi_k<<<(KP2 * HIDF + 255) / 256, 256, 0, stream>>>(zb, xw, dis, b2, x2, KP2, HIDF, 1);

  // ---- augment(A2): 3-seg hi/lo ----
  mg64(A2bh, A2bh, A2bl, A2tbh, A2tbl, A2tbh, 3, Bm, KP2, KP2, 1024);
  augment_finish_k<<<((size_t)KP2 * KP2 + 255) / 256, 256, 0, stream>>>(Bm, A2, KP2);

  // ---- pool 3 / conv 3 ----
  pool(Bm, KP2, x2, p3, KP3, perm3, A3, xin);
  conv_hilo_k<<<((size_t)KP3 * 512 + 255) / 256, 256, 0, stream>>>(A3, KP3, KP3, 512, A3bh, A3bl);
  featgemm(xin, KP3, HIDF, W3, HIDF, xw);
  rowsum_dis_k<<<KP3, 256, 0, stream>>>(A3, KP3, dis);
  scale_rows_k<<<(KP3 * HIDF + 255) / 256, 256, 0, stream>>>(xw, dis, yb, KP3, HIDF);
  tconv_y(yb, KP3);
  mg64(A3bh, A3bh, A3bl, bfBh, bfBl, bfBh, 3, zb, KP3, HIDF, 512);
  conv_epi_k<<<(KP3 * HIDF + 255) / 256, 256, 0, stream>>>(zb, xw, dis, b3, x3, KP3, HIDF, 1);

  // ---- up path ----
  copy_k<<<(KP2 * HIDF + 255) / 256, 256, 0, stream>>>(x2, ha, KP2 * HIDF);
  scatter_add_k<<<(KP3 * HIDF + 255) / 256, 256, 0, stream>>>(ha, perm3, x3, KP3, HIDF);
  featgemm(ha, KP2, HIDF, U0, HIDF, xw);
  rowsum_dis_k<<<KP2, 256, 0, stream>>>(A2, KP2, dis);
  scale_rows_k<<<(KP2 * HIDF + 255) / 256, 256, 0, stream>>>(xw, dis, yb, KP2, HIDF);
  tconv_y(yb, KP2);
  mg64(A2bh, A2bh, A2bl, bfBh, bfBl, bfBh, 3, zb, KP2, HIDF, 1024);
  conv_epi_k<<<(KP2 * HIDF + 255) / 256, 256, 0, stream>>>(zb, xw, dis, c0, hb, KP2, HIDF, 1);

  copy_k<<<(KP1 * HIDF + 255) / 256, 256, 0, stream>>>(x1, ha, KP1 * HIDF);
  scatter_add_k<<<(KP2 * HIDF + 255) / 256, 256, 0, stream>>>(ha, perm2, hb, KP2, HIDF);
  featgemm(ha, KP1, HIDF, U1, HIDF, xw);
  rowsum_dis_k<<<KP1, 256, 0, stream>>>(A1, KP1, dis);
  scale_rows_k<<<(KP1 * HIDF + 255) / 256, 256, 0, stream>>>(xw, dis, yb, KP1, HIDF);
  tconv_y(yb, KP1);
  mg64(A1bf, A1bf, nullptr, bfBh, bfBl, nullptr, 2, zb, KP1, HIDF, 2016);
  conv_epi_k<<<(KP1 * HIDF + 255) / 256, 256, 0, stream>>>(zb, xw, dis, c1, hb, KP1, HIDF, 1);

  copy_k<<<(N0 * HIDF + 255) / 256, 256, 0, stream>>>(x0, ha, N0 * HIDF);
  scatter_add_k<<<(KP1 * HIDF + 255) / 256, 256, 0, stream>>>(ha, perm1, hb, KP1, HIDF);
  featgemm(ha, N0, HIDF, U2, OUTC, xw);
  scale_rows_k<<<(N0 * OUTC + 255) / 256, 256, 0, stream>>>(xw, dis0, yb, N0, OUTC);
  spmm_k<<<N0, OUTC, 0, stream>>>(st_d, bk_d, yb, zb, OUTC);
  conv_epi_k<<<(N0 * OUTC + 255) / 256, 256, 0, stream>>>(zb, xw, dis0, c2, xin, N0, OUTC, 0);

  // ---- log_softmax ----
  log_softmax_k<<<N0, 64, 0, stream>>>(xin, (float*)d_out, OUTC);
}

// Round 3
// 1023.679 us; speedup vs baseline: 3.6025x; 1.3259x over previous
//
#include <hip/hip_runtime.h>
#include <math.h>
#include <stdint.h>

#define N0   3000
#define NE   96000
#define INC  512
#define HIDF 256
#define OUTC 64
#define KP1  2000
#define KP2  1000
#define KP3  500

typedef __bf16 bf16x8 __attribute__((ext_vector_type(8)));
typedef float f32x4 __attribute__((ext_vector_type(4)));

// ---------------- CSR build (in-edges by dst only) ----------------
static __global__ void count_k(const int* __restrict__ ei, int* __restrict__ cd) {
  int e = blockIdx.x * blockDim.x + threadIdx.x;
  if (e < NE) atomicAdd(&cd[ei[NE + e]], 1);
}

static __global__ __launch_bounds__(1024) void scan_excl_k(const int* __restrict__ cnt,
                                                           int* __restrict__ start, int n) {
  __shared__ int s[4096];
  int tid = threadIdx.x;
  for (int i = tid; i < 4096; i += blockDim.x) s[i] = (i < n) ? cnt[i] : 0;
  __syncthreads();
  for (int d = 1; d < 4096; d <<= 1) {
    int v[4]; int r = 0;
    for (int i = tid; i < 4096; i += blockDim.x, ++r) v[r] = (i >= d) ? s[i - d] : 0;
    __syncthreads();
    r = 0;
    for (int i = tid; i < 4096; i += blockDim.x, ++r) s[i] += v[r];
    __syncthreads();
  }
  for (int i = tid; i < n; i += blockDim.x) start[i] = (i == 0) ? 0 : s[i - 1];
  if (tid == 0) start[n] = s[n - 1];
}

static __global__ void scatter_k(const int* __restrict__ ei, const int* __restrict__ sd,
                                 int* __restrict__ fd, int* __restrict__ bd) {
  int e = blockIdx.x * blockDim.x + threadIdx.x;
  if (e < NE) {
    int d = ei[NE + e];
    bd[sd[d] + atomicAdd(&fd[d], 1)] = ei[e];  // in-neighbors (sources) by dst
  }
}

static __global__ void dis0_k(const int* __restrict__ cd, float* __restrict__ dis0) {
  int i = blockIdx.x * blockDim.x + threadIdx.x;
  if (i < N0) dis0[i] = rsqrtf((float)cd[i] + 2.0f);
}

// ---------------- masked augment level 0: A1 = (A^2 + 2A)[perm,perm] offdiag ----------------
// B[i,j] = sum_k A[i,k] A[k,j]; A[i,k] = #edges k->i. Per selected row i: LDS row accum.
static __global__ __launch_bounds__(256) void augA_masked_k(
    const int* __restrict__ st, const int* __restrict__ bk,
    const int* __restrict__ perm, const int* __restrict__ pos,
    float* __restrict__ A1, float* __restrict__ dis1) {
  __shared__ float row[KP1];
  __shared__ float sh[4];
  int tid = threadIdx.x, lane = tid & 63, wave = tid >> 6;
  int r = blockIdx.x;
  int vi = perm[r];
  for (int c = tid; c < KP1; c += 256) row[c] = 0.f;
  __syncthreads();
  int b = st[vi], e = st[vi + 1];
  for (int t = b + wave; t < e; t += 4) {
    int k = bk[t];
    int jb = st[k], je = st[k + 1];
    for (int u = jb + lane; u < je; u += 64) {
      int p = pos[bk[u]];
      if (p >= 0) atomicAdd(&row[p], 1.0f);
    }
  }
  if (wave == 0)
    for (int t = b + lane; t < e; t += 64) {
      int p = pos[bk[t]];
      if (p >= 0) atomicAdd(&row[p], 2.0f);
    }
  __syncthreads();
  if (tid == 0) row[r] = 0.f;
  __syncthreads();
  float s = 0.f;
  for (int c = tid; c < KP1; c += 256) {
    float v = row[c];
    A1[(size_t)r * KP1 + c] = v;
    s += v;
  }
#pragma unroll
  for (int o = 32; o > 0; o >>= 1) s += __shfl_down(s, o, 64);
  if (lane == 0) sh[wave] = s;
  __syncthreads();
  if (tid == 0) dis1[r] = rsqrtf(sh[0] + sh[1] + sh[2] + sh[3] + 2.0f);
}

// ---------------- SpMM (level 0 propagation) ----------------
static __global__ void spmm_k(const int* __restrict__ start, const int* __restrict__ idx,
                              const float* __restrict__ y, float* __restrict__ out, int F) {
  int row = blockIdx.x;
  int b = start[row], e = start[row + 1];
  int f = threadIdx.x;  // blockDim == F
  __shared__ int nb[256];
  float acc = 0.f;
  for (int t0 = b; t0 < e; t0 += blockDim.x) {
    int m = min((int)blockDim.x, e - t0);
    __syncthreads();
    if (f < m) nb[f] = idx[t0 + f];
    __syncthreads();
    for (int t = 0; t < m; ++t) acc += y[(size_t)nb[t] * F + f];
  }
  out[(size_t)row * F + f] = acc;
}

// ---------------- converters ----------------
// row-major f32 [R][C] -> bf16 [R][Cp] hi (+lo), K-pad zeros
static __global__ void conv_hilo_k(const float* __restrict__ in, int R, int C, int Cp,
                                   __bf16* __restrict__ oh, __bf16* __restrict__ ol) {
  int idx = blockIdx.x * blockDim.x + threadIdx.x;
  if (idx < R * Cp) {
    int r = idx / Cp, c = idx - r * Cp;
    float v = (c < C) ? in[(size_t)r * C + c] : 0.f;
    __bf16 h = (__bf16)v;
    oh[idx] = h;
    if (ol) ol[idx] = (__bf16)(v - (float)h);
  }
}

// transpose+convert (+optional per-input-row scale): f32 in[R][C] -> bf16 out[C][Rp] hi (+lo)
static __global__ __launch_bounds__(256) void tconv_k(const float* __restrict__ in, int R, int C, int Rp,
                                                      __bf16* __restrict__ oh, __bf16* __restrict__ ol,
                                                      const float* __restrict__ disv) {
  __shared__ float t[32][33];
  int r0 = blockIdx.x * 32, c0 = blockIdx.y * 32;
  int lr = threadIdx.x >> 5, lc = threadIdx.x & 31;
#pragma unroll
  for (int i = 0; i < 4; ++i) {
    int r = r0 + lr + i * 8, c = c0 + lc;
    t[lr + i * 8][lc] = (r < R && c < C) ? in[(size_t)r * C + c] : 0.f;
  }
  __syncthreads();
#pragma unroll
  for (int i = 0; i < 4; ++i) {
    int c = c0 + lr + i * 8, r = r0 + lc;
    if (c < C) {
      float v = t[lc][lr + i * 8];
      if (disv && r < R) v *= disv[r];
      __bf16 h = (__bf16)v;
      oh[(size_t)c * Rp + r] = h;
      if (ol) ol[(size_t)c * Rp + r] = (__bf16)(v - (float)h);
    }
  }
}

// row gather bf16 (+2 at column == source-row index, for the +2I trick)
static __global__ void grows_k(const __bf16* __restrict__ src, const int* __restrict__ perm,
                               __bf16* __restrict__ dst, int k, int L, int addI) {
  int idx = blockIdx.x * blockDim.x + threadIdx.x;
  int nv = L >> 3;
  if (idx < k * nv) {
    int r = idx / nv, c8 = (idx - r * nv) << 3;
    int sr = perm[r];
    bf16x8 v = *(const bf16x8*)(src + (size_t)sr * L + c8);
    if (addI && sr >= c8 && sr < c8 + 8) v[sr - c8] = (__bf16)((float)v[sr - c8] + 2.0f);
    *(bf16x8*)(dst + (size_t)r * L + c8) = v;
  }
}

// fused gather+scale+hilo: out[r][c] = hilo(src[perm[r]][c] * sv[r]), C == HIDF
static __global__ void ghilo_k(const float* __restrict__ src, const int* __restrict__ perm,
                               const float* __restrict__ sv, __bf16* __restrict__ oh,
                               __bf16* __restrict__ ol, int k) {
  int idx = blockIdx.x * blockDim.x + threadIdx.x;
  if (idx < k * HIDF) {
    int r = idx >> 8;
    float v = src[(size_t)perm[r] * HIDF + (idx & 255)] * sv[r];
    __bf16 h = (__bf16)v;
    oh[idx] = h;
    ol[idx] = (__bf16)(v - (float)h);
  }
}

// ---------------- MFMA GEMM: C = sum_seg A_s @ B_s^T ----------------
template <int BM, int BN>
static __global__ __launch_bounds__(256) void mgemm_k(
    const __bf16* __restrict__ A0, const __bf16* __restrict__ A1g, const __bf16* __restrict__ A2g,
    const __bf16* __restrict__ B0, const __bf16* __restrict__ B1g, const __bf16* __restrict__ B2g,
    int nseg, float* __restrict__ C, int M, int N, int Kp) {
  constexpr int FM = BM / 32, FN = BN / 32;
  __shared__ __bf16 As[BM][40];
  __shared__ __bf16 Bs[BN][40];
  int tid = threadIdx.x;
  int lane = tid & 63, wave = tid >> 6;
  int wx = wave & 1, wy = wave >> 1;
  int l15 = lane & 15, l4 = lane >> 4;
  int brow = blockIdx.y * BM, bcol = blockIdx.x * BN;
  int wrow = wy * (BM / 2), wcol = wx * (BN / 2);
  int srow = tid >> 2, scol = (tid & 3) * 8;
  f32x4 acc[FM][FN] = {};
  for (int s = 0; s < nseg; ++s) {
    const __bf16* Ag = (s == 0) ? A0 : (s == 1) ? A1g : A2g;
    const __bf16* Bg = (s == 0) ? B0 : (s == 1) ? B1g : B2g;
    for (int k0 = 0; k0 < Kp; k0 += 32) {
      __syncthreads();
#pragma unroll
      for (int r0 = 0; r0 < BM; r0 += 64) {
        int gr = brow + r0 + srow;
        bf16x8 v = {};
        if (gr < M) v = *(const bf16x8*)(Ag + (size_t)gr * Kp + k0 + scol);
        *(bf16x8*)(&As[r0 + srow][scol]) = v;
      }
#pragma unroll
      for (int r0 = 0; r0 < BN; r0 += 64) {
        int gc = bcol + r0 + srow;
        bf16x8 v = {};
        if (gc < N) v = *(const bf16x8*)(Bg + (size_t)gc * Kp + k0 + scol);
        *(bf16x8*)(&Bs[r0 + srow][scol]) = v;
      }
      __syncthreads();
      bf16x8 af[FM], bfv[FN];
#pragma unroll
      for (int i = 0; i < FM; ++i) af[i] = *(const bf16x8*)(&As[wrow + i * 16 + l15][l4 * 8]);
#pragma unroll
      for (int j = 0; j < FN; ++j) bfv[j] = *(const bf16x8*)(&Bs[wcol + j * 16 + l15][l4 * 8]);
#pragma unroll
      for (int i = 0; i < FM; ++i)
#pragma unroll
        for (int j = 0; j < FN; ++j)
          acc[i][j] = __builtin_amdgcn_mfma_f32_16x16x32_bf16(af[i], bfv[j], acc[i][j], 0, 0, 0);
    }
  }
#pragma unroll
  for (int i = 0; i < FM; ++i)
#pragma unroll
    for (int j = 0; j < FN; ++j) {
      int col = bcol + wcol + j * 16 + l15;
      if (col < N) {
#pragma unroll
        for (int q = 0; q < 4; ++q) {
          int row = brow + wrow + i * 16 + l4 * 4 + q;
          if (row < M) C[(size_t)row * N + col] = acc[i][j][q];
        }
      }
    }
}

// ---------------- misc ----------------
static __global__ void scale_rows_k(const float* __restrict__ xw, const float* __restrict__ dis,
                                    float* __restrict__ y, int n, int f) {
  int idx = blockIdx.x * blockDim.x + threadIdx.x;
  if (idx < n * f) y[idx] = xw[idx] * dis[idx / f];
}

static __global__ void conv_epi_k(const float* __restrict__ z, const float* __restrict__ xw,
                                  const float* __restrict__ dis, const float* __restrict__ b,
                                  float* __restrict__ out, int n, int f, int relu) {
  int idx = blockIdx.x * blockDim.x + threadIdx.x;
  if (idx < n * f) {
    int i = idx / f, j = idx - i * f;
    float di = dis[i];
    float v = di * z[idx] + 2.0f * di * di * xw[idx] + b[j];
    if (relu) v = fmaxf(v, 0.0f);
    out[idx] = v;
  }
}

// zero diag + rowsum -> dis (for masked-augment outputs)
static __global__ __launch_bounds__(256) void aug_epi_k(float* __restrict__ C, int n,
                                                        float* __restrict__ dis) {
  __shared__ float sh[4];
  int r = blockIdx.x;
  int tid = threadIdx.x, lane = tid & 63, wave = tid >> 6;
  float s = 0.f;
  for (int c = tid; c < n; c += 256) {
    float v = C[(size_t)r * n + c];
    if (c == r) { v = 0.f; C[(size_t)r * n + c] = 0.f; }
    s += v;
  }
#pragma unroll
  for (int o = 32; o > 0; o >>= 1) s += __shfl_down(s, o, 64);
  if (lane == 0) sh[wave] = s;
  __syncthreads();
  if (tid == 0) dis[r] = rsqrtf(sh[0] + sh[1] + sh[2] + sh[3] + 2.0f);
}

// ---------------- pooling ----------------
static __global__ void norm_k(const float* __restrict__ w, int n, float* __restrict__ out) {
  float s = 0.f;
  for (int i = threadIdx.x; i < n; i += blockDim.x) { float v = w[i]; s += v * v; }
  __shared__ float sh[8];
  int lane = threadIdx.x & 63, wid = threadIdx.x >> 6;
#pragma unroll
  for (int o = 32; o > 0; o >>= 1) s += __shfl_down(s, o, 64);
  if (lane == 0) sh[wid] = s;
  __syncthreads();
  if (threadIdx.x == 0) {
    float t = 0.f;
    int nw = (blockDim.x + 63) >> 6;
    for (int w2 = 0; w2 < nw; ++w2) t += sh[w2];
    out[0] = sqrtf(t);
  }
}

static __global__ void score_k(const float* __restrict__ x, const float* __restrict__ w,
                               const float* __restrict__ nrm, float* __restrict__ sc, int f) {
  int row = blockIdx.x;
  float s = 0.f;
  for (int j = threadIdx.x; j < f; j += blockDim.x) s += x[(size_t)row * f + j] * w[j];
  __shared__ float sh[8];
  int lane = threadIdx.x & 63, wid = threadIdx.x >> 6;
#pragma unroll
  for (int o = 32; o > 0; o >>= 1) s += __shfl_down(s, o, 64);
  if (lane == 0) sh[wid] = s;
  __syncthreads();
  if (threadIdx.x == 0) {
    float t = 0.f;
    int nw = (blockDim.x + 63) >> 6;
    for (int w2 = 0; w2 < nw; ++w2) t += sh[w2];
    sc[row] = tanhf(t / nrm[0]);
  }
}

// exact jax.lax.top_k via O(n^2) rank: rank = #{s_j > s_i} + #{j<i: s_j == s_i}
static __global__ __launch_bounds__(256) void topk_rank_k(const float* __restrict__ sc, int n, int k,
                                                          int* __restrict__ perm, float* __restrict__ sv) {
  __shared__ float s[N0 + 8];
  int tid = threadIdx.x;
  for (int i = tid; i < n; i += 256) s[i] = sc[i];
  __syncthreads();
  int i = blockIdx.x * 256 + tid;
  if (i < n) {
    float si = s[i];
    int rank = 0;
    for (int j = 0; j < n; ++j) {
      float sj = s[j];
      rank += (sj > si) || (sj == si && j < i);
    }
    if (rank < k) { perm[rank] = i; sv[rank] = si; }
  }
}

static __global__ void setpos_k(const int* __restrict__ perm, int k, int* __restrict__ pos) {
  int i = blockIdx.x * blockDim.x + threadIdx.x;
  if (i < k) pos[perm[i]] = i;
}

static __global__ void unpool_k(const float* __restrict__ base, const float* __restrict__ up,
                                const int* __restrict__ pos, float* __restrict__ out, int n, int f) {
  int idx = blockIdx.x * blockDim.x + threadIdx.x;
  if (idx < n * f) {
    int i = idx / f, j = idx - i * f;
    int p = pos[i];
    out[idx] = base[idx] + (p >= 0 ? up[(size_t)p * f + j] : 0.f);
  }
}

static __global__ void log_softmax_k(const float* __restrict__ h, float* __restrict__ out, int f) {
  int row = blockIdx.x;
  int j = threadIdx.x;  // blockDim = 64 == f
  float vv = h[row * f + j];
  float m = vv;
#pragma unroll
  for (int o = 32; o > 0; o >>= 1) m = fmaxf(m, __shfl_xor(m, o, 64));
  float e = expf(vv - m), s = e;
#pragma unroll
  for (int o = 32; o > 0; o >>= 1) s += __shfl_xor(s, o, 64);
  out[row * f + j] = vv - m - logf(s);
}

// ---------------- host ----------------
extern "C" void kernel_launch(void* const* d_in, const int* in_sizes, int n_in,
                              void* d_out, int out_size, void* d_ws, size_t ws_size,
                              hipStream_t stream) {
  const float* x  = (const float*)d_in[0];
  const int* ei   = (const int*)d_in[1];
  const float* W0 = (const float*)d_in[2];
  const float* b0 = (const float*)d_in[3];
  const float* W1 = (const float*)d_in[4];
  const float* b1 = (const float*)d_in[5];
  const float* W2 = (const float*)d_in[6];
  const float* b2 = (const float*)d_in[7];
  const float* W3 = (const float*)d_in[8];
  const float* b3 = (const float*)d_in[9];
  const float* p1 = (const float*)d_in[10];
  const float* p2 = (const float*)d_in[11];
  const float* p3 = (const float*)d_in[12];
  const float* U0 = (const float*)d_in[13];
  const float* c0 = (const float*)d_in[14];
  const float* U1 = (const float*)d_in[15];
  const float* c1 = (const float*)d_in[16];
  const float* U2 = (const float*)d_in[17];
  const float* c2 = (const float*)d_in[18];
  (void)in_sizes; (void)n_in; (void)out_size; (void)ws_size;

  char* basep = (char*)d_ws;
  size_t off = 0;
  auto alloc = [&](size_t bytes) {
    void* p = basep + off;
    off += (bytes + 255) & ~(size_t)255;
    return p;
  };
  auto pad32 = [](int k) { return (k + 31) & ~31; };

  // fp32 mats
  float* A1  = (float*)alloc((size_t)KP1 * KP1 * 4);
  float* A2  = (float*)alloc((size_t)KP2 * KP2 * 4);
  float* A3  = (float*)alloc((size_t)KP3 * KP3 * 4);
  float* xw  = (float*)alloc((size_t)N0 * HIDF * 4);
  float* yb  = (float*)alloc((size_t)N0 * HIDF * 4);
  float* zb  = (float*)alloc((size_t)N0 * HIDF * 4);
  float* x0  = (float*)alloc((size_t)N0 * HIDF * 4);
  float* x1  = (float*)alloc((size_t)KP1 * HIDF * 4);
  float* x2  = (float*)alloc((size_t)KP2 * HIDF * 4);
  float* x3  = (float*)alloc((size_t)KP3 * HIDF * 4);
  float* ha  = (float*)alloc((size_t)N0 * HIDF * 4);
  float* hb  = (float*)alloc((size_t)N0 * HIDF * 4);
  float* xfin = (float*)alloc((size_t)N0 * OUTC * 4);
  // bf16 scratch
  __bf16* bfAh = (__bf16*)alloc((size_t)N0 * INC * 2);
  __bf16* bfAl = (__bf16*)alloc((size_t)N0 * INC * 2);
  __bf16* bfBh = (__bf16*)alloc((size_t)HIDF * 2016 * 2);
  __bf16* bfBl = (__bf16*)alloc((size_t)HIDF * 2016 * 2);
  __bf16* A1bf  = (__bf16*)alloc((size_t)KP1 * 2016 * 2);
  __bf16* A1tbf = (__bf16*)alloc((size_t)KP1 * 2016 * 2);
  __bf16* Ag    = (__bf16*)alloc((size_t)KP2 * 2016 * 2);
  __bf16* Bg    = (__bf16*)alloc((size_t)KP2 * 2016 * 2);
  __bf16* A2bh  = (__bf16*)alloc((size_t)KP2 * 1024 * 2);
  __bf16* A2bl  = (__bf16*)alloc((size_t)KP2 * 1024 * 2);
  __bf16* A2tbh = (__bf16*)alloc((size_t)KP2 * 1024 * 2);
  __bf16* A2tbl = (__bf16*)alloc((size_t)KP2 * 1024 * 2);
  __bf16* Agh   = (__bf16*)alloc((size_t)KP3 * 1024 * 2);
  __bf16* Agl   = (__bf16*)alloc((size_t)KP3 * 1024 * 2);
  __bf16* Bgh   = (__bf16*)alloc((size_t)KP3 * 1024 * 2);
  __bf16* Bgl   = (__bf16*)alloc((size_t)KP3 * 1024 * 2);
  __bf16* A3bh  = (__bf16*)alloc((size_t)KP3 * 512 * 2);
  __bf16* A3bl  = (__bf16*)alloc((size_t)KP3 * 512 * 2);
  // small
  float* sc   = (float*)alloc(N0 * 4);
  float* sv   = (float*)alloc(KP1 * 4);
  int* perm1  = (int*)alloc(KP1 * 4);
  int* perm2  = (int*)alloc(KP2 * 4);
  int* perm3  = (int*)alloc(KP3 * 4);
  int* pos1   = (int*)alloc(N0 * 4);
  int* pos2   = (int*)alloc(KP1 * 4);
  int* pos3   = (int*)alloc(KP2 * 4);
  float* dis0 = (float*)alloc(N0 * 4);
  float* dis1 = (float*)alloc(KP1 * 4);
  float* dis2 = (float*)alloc(KP2 * 4);
  float* dis3 = (float*)alloc(KP3 * 4);
  float* nrm  = (float*)alloc(256);
  int* cnt_d  = (int*)alloc(N0 * 4);
  int* st_d   = (int*)alloc((N0 + 4) * 4);
  int* fl_d   = (int*)alloc(N0 * 4);
  int* bk_d   = (int*)alloc(NE * 4);

  auto mg64 = [&](const __bf16* a0, const __bf16* a1, const __bf16* a2,
                  const __bf16* bb0, const __bf16* bb1, const __bf16* bb2,
                  int nseg, float* C, int M, int N, int Kp) {
    dim3 g((N + 63) / 64, (M + 63) / 64);
    mgemm_k<64, 64><<<g, 256, 0, stream>>>(a0, a1, a2, bb0, bb1, bb2, nseg, C, M, N, Kp);
  };

  // weight GEMM assuming bfAh/bfAl already hold the hi/lo A operand [n][pad32(fin)]
  auto wgemm = [&](const float* W, int fin, int fout, int n, float* out) {
    int Kp = pad32(fin);
    dim3 tg(Kp / 32, (fout + 31) / 32);
    tconv_k<<<tg, 256, 0, stream>>>(W, fin, fout, Kp, bfBh, bfBl, nullptr);
    mg64(bfAh, bfAh, bfAl, bfBh, bfBl, bfBh, 3, out, n, fout, Kp);
  };

  // dense propagation + epilogue: out = relu?(dis*(A@(dis*xw)) + 2 dis^2 xw + b)
  auto prop = [&](const __bf16* Abh, const __bf16* Abl, int asegs, int n, int Kp,
                  const float* disv, const float* bias, float* outx, int relu) {
    dim3 tg(Kp / 32, (HIDF + 31) / 32);
    tconv_k<<<tg, 256, 0, stream>>>(xw, n, HIDF, Kp, bfBh, bfBl, disv);
    if (asegs == 1) mg64(Abh, Abh, nullptr, bfBh, bfBl, nullptr, 2, zb, n, HIDF, Kp);
    else            mg64(Abh, Abh, Abl, bfBh, bfBl, bfBh, 3, zb, n, HIDF, Kp);
    conv_epi_k<<<(n * HIDF + 255) / 256, 256, 0, stream>>>(zb, xw, disv, bias, outx, n, HIDF, relu);
  };

  auto pool = [&](const float* xfeat, int n, const float* p, int k, int* perm, int* pos) {
    norm_k<<<1, 256, 0, stream>>>(p, HIDF, nrm);
    score_k<<<n, 256, 0, stream>>>(xfeat, p, nrm, sc, HIDF);
    topk_rank_k<<<(n + 255) / 256, 256, 0, stream>>>(sc, n, k, perm, sv);
    hipMemsetAsync(pos, 0xFF, n * 4, stream);
    setpos_k<<<(k + 255) / 256, 256, 0, stream>>>(perm, k, pos);
  };

  // ---- CSR build (in-edges by dst) ----
  hipMemsetAsync(cnt_d, 0, N0 * 4, stream);
  hipMemsetAsync(fl_d, 0, N0 * 4, stream);
  count_k<<<(NE + 255) / 256, 256, 0, stream>>>(ei, cnt_d);
  scan_excl_k<<<1, 1024, 0, stream>>>(cnt_d, st_d, N0);
  scatter_k<<<(NE + 255) / 256, 256, 0, stream>>>(ei, st_d, fl_d, bk_d);
  dis0_k<<<(N0 + 255) / 256, 256, 0, stream>>>(cnt_d, dis0);

  // ---- down conv 0 (sparse propagation) ----
  conv_hilo_k<<<((size_t)N0 * INC + 255) / 256, 256, 0, stream>>>(x, N0, INC, INC, bfAh, bfAl);
  wgemm(W0, INC, HIDF, N0, xw);
  scale_rows_k<<<(N0 * HIDF + 255) / 256, 256, 0, stream>>>(xw, dis0, yb, N0, HIDF);
  spmm_k<<<N0, HIDF, 0, stream>>>(st_d, bk_d, yb, zb, HIDF);
  conv_epi_k<<<(N0 * HIDF + 255) / 256, 256, 0, stream>>>(zb, xw, dis0, b0, x0, N0, HIDF, 1);

  // ---- pool 1 + masked augment(A) -> A1 dense + dis1 ----
  pool(x0, N0, p1, KP1, perm1, pos1);
  augA_masked_k<<<KP1, 256, 0, stream>>>(st_d, bk_d, perm1, pos1, A1, dis1);

  // ---- conv 1 ----
  ghilo_k<<<((size_t)KP1 * HIDF + 255) / 256, 256, 0, stream>>>(x0, perm1, sv, bfAh, bfAl, KP1);
  wgemm(W1, HIDF, HIDF, KP1, xw);
  conv_hilo_k<<<((size_t)KP1 * 2016 + 255) / 256, 256, 0, stream>>>(A1, KP1, KP1, 2016, A1bf, nullptr);
  prop(A1bf, nullptr, 1, KP1, 2016, dis1, b1, x1, 1);

  // ---- pool 2 + masked augment(A1): A2 = A1[perm2,:] @ (A1+2I)[:,perm2] ----
  pool(x1, KP1, p2, KP2, perm2, pos2);
  {
    dim3 tg(2016 / 32, (KP1 + 31) / 32);
    tconv_k<<<tg, 256, 0, stream>>>(A1, KP1, KP1, 2016, A1tbf, nullptr, nullptr);
  }
  grows_k<<<((size_t)KP2 * (2016 / 8) + 255) / 256, 256, 0, stream>>>(A1bf, perm2, Ag, KP2, 2016, 0);
  grows_k<<<((size_t)KP2 * (2016 / 8) + 255) / 256, 256, 0, stream>>>(A1tbf, perm2, Bg, KP2, 2016, 1);
  mg64(Ag, nullptr, nullptr, Bg, nullptr, nullptr, 1, A2, KP2, KP2, 2016);
  aug_epi_k<<<KP2, 256, 0, stream>>>(A2, KP2, dis2);

  // ---- conv 2 ----
  ghilo_k<<<((size_t)KP2 * HIDF + 255) / 256, 256, 0, stream>>>(x1, perm2, sv, bfAh, bfAl, KP2);
  wgemm(W2, HIDF, HIDF, KP2, xw);
  conv_hilo_k<<<((size_t)KP2 * 1024 + 255) / 256, 256, 0, stream>>>(A2, KP2, KP2, 1024, A2bh, A2bl);
  prop(A2bh, A2bl, 2, KP2, 1024, dis2, b2, x2, 1);

  // ---- pool 3 + masked augment(A2), hi/lo 3-seg ----
  pool(x2, KP2, p3, KP3, perm3, pos3);
  {
    dim3 tg(1024 / 32, (KP2 + 31) / 32);
    tconv_k<<<tg, 256, 0, stream>>>(A2, KP2, KP2, 1024, A2tbh, A2tbl, nullptr);
  }
  grows_k<<<((size_t)KP3 * (1024 / 8) + 255) / 256, 256, 0, stream>>>(A2bh, perm3, Agh, KP3, 1024, 0);
  grows_k<<<((size_t)KP3 * (1024 / 8) + 255) / 256, 256, 0, stream>>>(A2bl, perm3, Agl, KP3, 1024, 0);
  grows_k<<<((size_t)KP3 * (1024 / 8) + 255) / 256, 256, 0, stream>>>(A2tbh, perm3, Bgh, KP3, 1024, 0);
  grows_k<<<((size_t)KP3 * (1024 / 8) + 255) / 256, 256, 0, stream>>>(A2tbl, perm3, Bgl, KP3, 1024, 1);
  mg64(Agh, Agh, Agl, Bgh, Bgl, Bgh, 3, A3, KP3, KP3, 1024);
  aug_epi_k<<<KP3, 256, 0, stream>>>(A3, KP3, dis3);

  // ---- conv 3 ----
  ghilo_k<<<((size_t)KP3 * HIDF + 255) / 256, 256, 0, stream>>>(x2, perm3, sv, bfAh, bfAl, KP3);
  wgemm(W3, HIDF, HIDF, KP3, xw);
  conv_hilo_k<<<((size_t)KP3 * 512 + 255) / 256, 256, 0, stream>>>(A3, KP3, KP3, 512, A3bh, A3bl);
  prop(A3bh, A3bl, 2, KP3, 512, dis3, b3, x3, 1);

  // ---- up path ----
  unpool_k<<<(KP2 * HIDF + 255) / 256, 256, 0, stream>>>(x2, x3, pos3, ha, KP2, HIDF);
  conv_hilo_k<<<((size_t)KP2 * HIDF + 255) / 256, 256, 0, stream>>>(ha, KP2, HIDF, HIDF, bfAh, bfAl);
  wgemm(U0, HIDF, HIDF, KP2, xw);
  prop(A2bh, A2bl, 2, KP2, 1024, dis2, c0, hb, 1);

  unpool_k<<<(KP1 * HIDF + 255) / 256, 256, 0, stream>>>(x1, hb, pos2, ha, KP1, HIDF);
  conv_hilo_k<<<((size_t)KP1 * HIDF + 255) / 256, 256, 0, stream>>>(ha, KP1, HIDF, HIDF, bfAh, bfAl);
  wgemm(U1, HIDF, HIDF, KP1, xw);
  prop(A1bf, nullptr, 1, KP1, 2016, dis1, c1, hb, 1);

  unpool_k<<<(N0 * HIDF + 255) / 256, 256, 0, stream>>>(x0, hb, pos1, ha, N0, HIDF);
  conv_hilo_k<<<((size_t)N0 * HIDF + 255) / 256, 256, 0, stream>>>(ha, N0, HIDF, HIDF, bfAh, bfAl);
  wgemm(U2, HIDF, OUTC, N0, xw);
  scale_rows_k<<<(N0 * OUTC + 255) / 256, 256, 0, stream>>>(xw, dis0, yb, N0, OUTC);
  spmm_k<<<N0, OUTC, 0, stream>>>(st_d, bk_d, yb, zb, OUTC);
  conv_epi_k<<<(N0 * OUTC + 255) / 256, 256, 0, stream>>>(zb, xw, dis0, c2, xfin, N0, OUTC, 0);

  // ---- log_softmax ----
  log_softmax_k<<<N0, 64, 0, stream>>>(xfin, (float*)d_out, OUTC);
}

// Round 4
// 638.039 us; speedup vs baseline: 5.7800x; 1.6044x over previous
//
#include <hip/hip_runtime.h>
#include <math.h>
#include <stdint.h>

#define N0   3000
#define NE   96000
#define INC  512
#define HIDF 256
#define OUTC 64
#define KP1  2000
#define KP2  1000
#define KP3  500
#define KP1P 2048
#define KP2P 1024
#define KP3P 512

typedef __bf16 bf16x8 __attribute__((ext_vector_type(8)));
typedef float f32x4 __attribute__((ext_vector_type(4)));

// ---------------- CSR build (in-edges by dst) ----------------
static __global__ void count_k(const int* __restrict__ ei, int* __restrict__ cd) {
  int e = blockIdx.x * blockDim.x + threadIdx.x;
  if (e < NE) atomicAdd(&cd[ei[NE + e]], 1);
}

static __global__ __launch_bounds__(1024) void scan_excl_k(const int* __restrict__ cnt,
                                                           int* __restrict__ start, int n) {
  __shared__ int s[4096];
  int tid = threadIdx.x;
  for (int i = tid; i < 4096; i += blockDim.x) s[i] = (i < n) ? cnt[i] : 0;
  __syncthreads();
  for (int d = 1; d < 4096; d <<= 1) {
    int v[4]; int r = 0;
    for (int i = tid; i < 4096; i += blockDim.x, ++r) v[r] = (i >= d) ? s[i - d] : 0;
    __syncthreads();
    r = 0;
    for (int i = tid; i < 4096; i += blockDim.x, ++r) s[i] += v[r];
    __syncthreads();
  }
  for (int i = tid; i < n; i += blockDim.x) start[i] = (i == 0) ? 0 : s[i - 1];
  if (tid == 0) start[n] = s[n - 1];
}

static __global__ void scatter_k(const int* __restrict__ ei, const int* __restrict__ sd,
                                 int* __restrict__ fd, int* __restrict__ bd) {
  int e = blockIdx.x * blockDim.x + threadIdx.x;
  if (e < NE) {
    int d = ei[NE + e];
    bd[sd[d] + atomicAdd(&fd[d], 1)] = ei[e];
  }
}

static __global__ void dis0_k(const int* __restrict__ cd, float* __restrict__ dis0) {
  int i = blockIdx.x * blockDim.x + threadIdx.x;
  if (i < N0) dis0[i] = rsqrtf((float)cd[i] + 2.0f);
}

// ---------------- masked augment level 0 ----------------
// A1[r,c] = ((A^2 + 2A) offdiag)[perm[r], perm[c]]; fused: f32 + exact-bf16 (padded) + dis1
static __global__ __launch_bounds__(256) void augA_masked_k(
    const int* __restrict__ st, const int* __restrict__ bk,
    const int* __restrict__ perm, const int* __restrict__ pos,
    float* __restrict__ A1, __bf16* __restrict__ A1bf, float* __restrict__ dis1) {
  __shared__ float row[KP1];
  __shared__ float sh[4];
  int tid = threadIdx.x, lane = tid & 63, wave = tid >> 6;
  int r = blockIdx.x;
  int vi = perm[r];
  for (int c = tid; c < KP1; c += 256) row[c] = 0.f;
  __syncthreads();
  int b = st[vi], e = st[vi + 1];
  for (int t = b + wave; t < e; t += 4) {
    int k = bk[t];
    int jb = st[k], je = st[k + 1];
    for (int u = jb + lane; u < je; u += 64) {
      int p = pos[bk[u]];
      if (p >= 0) atomicAdd(&row[p], 1.0f);
    }
  }
  if (wave == 0)
    for (int t = b + lane; t < e; t += 64) {
      int p = pos[bk[t]];
      if (p >= 0) atomicAdd(&row[p], 2.0f);
    }
  __syncthreads();
  if (tid == 0) row[r] = 0.f;
  __syncthreads();
  float s = 0.f;
  for (int c = tid; c < KP1P; c += 256) {
    float v = (c < KP1) ? row[c] : 0.f;
    if (c < KP1) A1[(size_t)r * KP1 + c] = v;
    A1bf[(size_t)r * KP1P + c] = (__bf16)v;  // counts <= ~16: exact
    s += v;
  }
#pragma unroll
  for (int o = 32; o > 0; o >>= 1) s += __shfl_down(s, o, 64);
  if (lane == 0) sh[wave] = s;
  __syncthreads();
  if (tid == 0) dis1[r] = rsqrtf(sh[0] + sh[1] + sh[2] + sh[3] + 2.0f);
}

// ---------------- SpMM with fused source scaling ----------------
static __global__ void spmm_sc_k(const int* __restrict__ start, const int* __restrict__ idx,
                                 const float* __restrict__ xw, const float* __restrict__ dis,
                                 float* __restrict__ out, int F) {
  int row = blockIdx.x;
  int b = start[row], e = start[row + 1];
  int f = threadIdx.x;  // blockDim == F
  __shared__ int nb[256];
  __shared__ float nd[256];
  float acc = 0.f;
  for (int t0 = b; t0 < e; t0 += blockDim.x) {
    int m = min((int)blockDim.x, e - t0);
    __syncthreads();
    if (f < m) { int s = idx[t0 + f]; nb[f] = s; nd[f] = dis[s]; }
    __syncthreads();
    for (int t = 0; t < m; ++t) acc += xw[(size_t)nb[t] * F + f] * nd[t];
  }
  out[(size_t)row * F + f] = acc;
}

// ---------------- converters ----------------
static __global__ void conv_hilo_k(const float* __restrict__ in, int R, int C, int Cp,
                                   __bf16* __restrict__ oh, __bf16* __restrict__ ol) {
  int idx = blockIdx.x * blockDim.x + threadIdx.x;
  if (idx < R * Cp) {
    int r = idx / Cp, c = idx - r * Cp;
    float v = (c < C) ? in[(size_t)r * C + c] : 0.f;
    __bf16 h = (__bf16)v;
    oh[idx] = h;
    if (ol) ol[idx] = (__bf16)(v - (float)h);
  }
}

// transpose+convert (+optional per-input-row scale): f32 in[R][C] -> bf16 out[C][Rp]
static __global__ __launch_bounds__(256) void tconv_k(const float* __restrict__ in, int R, int C, int Rp,
                                                      __bf16* __restrict__ oh, __bf16* __restrict__ ol,
                                                      const float* __restrict__ disv) {
  __shared__ float t[32][33];
  int r0 = blockIdx.x * 32, c0 = blockIdx.y * 32;
  int lr = threadIdx.x >> 5, lc = threadIdx.x & 31;
#pragma unroll
  for (int i = 0; i < 4; ++i) {
    int r = r0 + lr + i * 8, c = c0 + lc;
    t[lr + i * 8][lc] = (r < R && c < C) ? in[(size_t)r * C + c] : 0.f;
  }
  __syncthreads();
#pragma unroll
  for (int i = 0; i < 4; ++i) {
    int c = c0 + lr + i * 8, r = r0 + lc;
    if (c < C) {
      float v = t[lc][lr + i * 8];
      if (disv && r < R) v *= disv[r];
      __bf16 h = (__bf16)v;
      oh[(size_t)c * Rp + r] = h;
      if (ol) ol[(size_t)c * Rp + r] = (__bf16)(v - (float)h);
    }
  }
}

static __global__ void grows_k(const __bf16* __restrict__ src, const int* __restrict__ perm,
                               __bf16* __restrict__ dst, int k, int L, int addI) {
  int idx = blockIdx.x * blockDim.x + threadIdx.x;
  int nv = L >> 3;
  if (idx < k * nv) {
    int r = idx / nv, c8 = (idx - r * nv) << 3;
    int sr = perm[r];
    bf16x8 v = *(const bf16x8*)(src + (size_t)sr * L + c8);
    if (addI && sr >= c8 && sr < c8 + 8) v[sr - c8] = (__bf16)((float)v[sr - c8] + 2.0f);
    *(bf16x8*)(dst + (size_t)r * L + c8) = v;
  }
}

static __global__ void ghilo_k(const float* __restrict__ src, const int* __restrict__ perm,
                               const float* __restrict__ sv, __bf16* __restrict__ oh,
                               __bf16* __restrict__ ol, int k) {
  int idx = blockIdx.x * blockDim.x + threadIdx.x;
  if (idx < k * HIDF) {
    int r = idx >> 8;
    float v = src[(size_t)perm[r] * HIDF + (idx & 255)] * sv[r];
    __bf16 h = (__bf16)v;
    oh[idx] = h;
    ol[idx] = (__bf16)(v - (float)h);
  }
}

// ---------------- MFMA GEMM with split-K partials ----------------
// C_partial[z] = sum_seg A_s @ B_s^T over K range [z*kchunk, z*kchunk+kchunk)
// A segs [M][Kp] bf16 row-major, B segs [N][Kp] bf16 row-major; Kp % 64 == 0, kchunk % 64 == 0.
// LDS: [64 rows][64 elems], 16B-slot XOR swizzle (slot ^= row&7) -> 2-way max on r/w (free).
static __global__ __launch_bounds__(256) void mgemm_k(
    const __bf16* __restrict__ A0, const __bf16* __restrict__ A1g, const __bf16* __restrict__ A2g,
    const __bf16* __restrict__ B0, const __bf16* __restrict__ B1g, const __bf16* __restrict__ B2g,
    int nseg, float* __restrict__ Cp, int M, int N, int Kp, int kchunk) {
  __shared__ __bf16 As[64 * 64];
  __shared__ __bf16 Bs[64 * 64];
  int tid = threadIdx.x;
  int lane = tid & 63, wave = tid >> 6;
  int wx = wave & 1, wy = wave >> 1;
  int l15 = lane & 15, l4 = lane >> 4;
  int brow = blockIdx.y * 64, bcol = blockIdx.x * 64;
  int wrow = wy * 32, wcol = wx * 32;
  int sr = tid >> 2, s0 = tid & 3;
  int x7 = sr & 7;
  int k_beg = blockIdx.z * kchunk;
  int k_end = min(k_beg + kchunk, Kp);
  int garow = brow + sr, gbrow = bcol + sr;
  f32x4 acc[2][2] = {};
  for (int s = 0; s < nseg; ++s) {
    const __bf16* Ag = (s == 0) ? A0 : (s == 1) ? A1g : A2g;
    const __bf16* Bg = (s == 0) ? B0 : (s == 1) ? B1g : B2g;
    const __bf16* ap = Ag + (size_t)garow * Kp;
    const __bf16* bp = Bg + (size_t)gbrow * Kp;
    for (int k0 = k_beg; k0 < k_end; k0 += 64) {
      __syncthreads();
      {
        bf16x8 va0 = {}, va1 = {}, vb0 = {}, vb1 = {};
        if (garow < M) {
          va0 = *(const bf16x8*)(ap + k0 + s0 * 8);
          va1 = *(const bf16x8*)(ap + k0 + (s0 + 4) * 8);
        }
        if (gbrow < N) {
          vb0 = *(const bf16x8*)(bp + k0 + s0 * 8);
          vb1 = *(const bf16x8*)(bp + k0 + (s0 + 4) * 8);
        }
        *(bf16x8*)(&As[sr * 64 + ((s0 ^ x7) << 3)]) = va0;
        *(bf16x8*)(&As[sr * 64 + (((s0 + 4) ^ x7) << 3)]) = va1;
        *(bf16x8*)(&Bs[sr * 64 + ((s0 ^ x7) << 3)]) = vb0;
        *(bf16x8*)(&Bs[sr * 64 + (((s0 + 4) ^ x7) << 3)]) = vb1;
      }
      __syncthreads();
#pragma unroll
      for (int sub = 0; sub < 2; ++sub) {
        bf16x8 af[2], bfv[2];
#pragma unroll
        for (int i = 0; i < 2; ++i) {
          int r = wrow + i * 16 + l15;
          af[i] = *(const bf16x8*)(&As[r * 64 + (((sub * 4 + l4) ^ (r & 7)) << 3)]);
        }
#pragma unroll
        for (int j = 0; j < 2; ++j) {
          int r = wcol + j * 16 + l15;
          bfv[j] = *(const bf16x8*)(&Bs[r * 64 + (((sub * 4 + l4) ^ (r & 7)) << 3)]);
        }
#pragma unroll
        for (int i = 0; i < 2; ++i)
#pragma unroll
          for (int j = 0; j < 2; ++j)
            acc[i][j] = __builtin_amdgcn_mfma_f32_16x16x32_bf16(af[i], bfv[j], acc[i][j], 0, 0, 0);
      }
    }
  }
  size_t zoff = (size_t)blockIdx.z * M * N;
#pragma unroll
  for (int i = 0; i < 2; ++i)
#pragma unroll
    for (int j = 0; j < 2; ++j) {
      int col = bcol + wcol + j * 16 + l15;
      if (col < N) {
#pragma unroll
        for (int q = 0; q < 4; ++q) {
          int row = brow + wrow + i * 16 + l4 * 4 + q;
          if (row < M) Cp[zoff + (size_t)row * N + col] = acc[i][j][q];
        }
      }
    }
}

// ---------------- reductions / epilogues ----------------
static __global__ void reduce_k(const float* __restrict__ p, int ks, int mn, float* __restrict__ out) {
  int idx = blockIdx.x * blockDim.x + threadIdx.x;
  if (idx < mn) {
    float s = 0.f;
    for (int z = 0; z < ks; ++z) s += p[(size_t)z * mn + idx];
    out[idx] = s;
  }
}

static __global__ void conv_epi_k(const float* __restrict__ zp, int ks, int mn,
                                  const float* __restrict__ xw, const float* __restrict__ dis,
                                  const float* __restrict__ b, float* __restrict__ out,
                                  int n, int f, int relu) {
  int idx = blockIdx.x * blockDim.x + threadIdx.x;
  if (idx < n * f) {
    float zv = 0.f;
    for (int z = 0; z < ks; ++z) zv += zp[(size_t)z * mn + idx];
    int i = idx / f, j = idx - i * f;
    float di = dis[i];
    float v = di * zv + 2.0f * di * di * xw[idx] + b[j];
    if (relu) v = fmaxf(v, 0.0f);
    out[idx] = v;
  }
}

// split-K reduce + zero diag + rowsum->dis + f32 + hi/lo bf16 (padded), all in one pass
static __global__ __launch_bounds__(256) void aug_epi_k(const float* __restrict__ Cp, int ks, int mn,
                                                        int n, int Kpad, float* __restrict__ Af,
                                                        __bf16* __restrict__ bh, __bf16* __restrict__ bl,
                                                        float* __restrict__ dis) {
  __shared__ float sh[4];
  int r = blockIdx.x;
  int tid = threadIdx.x, lane = tid & 63, wave = tid >> 6;
  float ssum = 0.f;
  for (int c = tid; c < Kpad; c += 256) {
    float v = 0.f;
    if (c < n && c != r)
      for (int z = 0; z < ks; ++z) v += Cp[(size_t)z * mn + (size_t)r * n + c];
    if (c < n) Af[(size_t)r * n + c] = v;
    __bf16 h = (__bf16)v;
    bh[(size_t)r * Kpad + c] = h;
    bl[(size_t)r * Kpad + c] = (__bf16)(v - (float)h);
    ssum += v;
  }
#pragma unroll
  for (int o = 32; o > 0; o >>= 1) ssum += __shfl_down(ssum, o, 64);
  if (lane == 0) sh[wave] = ssum;
  __syncthreads();
  if (tid == 0) dis[r] = rsqrtf(sh[0] + sh[1] + sh[2] + sh[3] + 2.0f);
}

// ---------------- pooling ----------------
static __global__ void norm_k(const float* __restrict__ w, int n, float* __restrict__ out) {
  float s = 0.f;
  for (int i = threadIdx.x; i < n; i += blockDim.x) { float v = w[i]; s += v * v; }
  __shared__ float sh[8];
  int lane = threadIdx.x & 63, wid = threadIdx.x >> 6;
#pragma unroll
  for (int o = 32; o > 0; o >>= 1) s += __shfl_down(s, o, 64);
  if (lane == 0) sh[wid] = s;
  __syncthreads();
  if (threadIdx.x == 0) {
    float t = 0.f;
    int nw = (blockDim.x + 63) >> 6;
    for (int w2 = 0; w2 < nw; ++w2) t += sh[w2];
    out[0] = sqrtf(t);
  }
}

static __global__ void score_k(const float* __restrict__ x, const float* __restrict__ w,
                               const float* __restrict__ nrm, float* __restrict__ sc, int f) {
  int row = blockIdx.x;
  float s = 0.f;
  for (int j = threadIdx.x; j < f; j += blockDim.x) s += x[(size_t)row * f + j] * w[j];
  __shared__ float sh[8];
  int lane = threadIdx.x & 63, wid = threadIdx.x >> 6;
#pragma unroll
  for (int o = 32; o > 0; o >>= 1) s += __shfl_down(s, o, 64);
  if (lane == 0) sh[wid] = s;
  __syncthreads();
  if (threadIdx.x == 0) {
    float t = 0.f;
    int nw = (blockDim.x + 63) >> 6;
    for (int w2 = 0; w2 < nw; ++w2) t += sh[w2];
    sc[row] = tanhf(t / nrm[0]);
  }
}

static __global__ __launch_bounds__(256) void topk_rank_k(const float* __restrict__ sc, int n, int k,
                                                          int* __restrict__ perm, float* __restrict__ sv) {
  __shared__ float s[N0 + 8];
  int tid = threadIdx.x;
  for (int i = tid; i < n; i += 256) s[i] = sc[i];
  __syncthreads();
  int i = blockIdx.x * 256 + tid;
  if (i < n) {
    float si = s[i];
    int rank = 0;
    for (int j = 0; j < n; ++j) {
      float sj = s[j];
      rank += (sj > si) || (sj == si && j < i);
    }
    if (rank < k) { perm[rank] = i; sv[rank] = si; }
  }
}

static __global__ void setpos_k(const int* __restrict__ perm, int k, int* __restrict__ pos) {
  int i = blockIdx.x * blockDim.x + threadIdx.x;
  if (i < k) pos[perm[i]] = i;
}

// unpool (base + scatter(up)) fused with hi/lo bf16 conversion, f == HIDF
static __global__ void unpool_hilo_k(const float* __restrict__ base, const float* __restrict__ up,
                                     const int* __restrict__ pos, __bf16* __restrict__ oh,
                                     __bf16* __restrict__ ol, int n) {
  int idx = blockIdx.x * blockDim.x + threadIdx.x;
  if (idx < n * HIDF) {
    int i = idx >> 8;
    int p = pos[i];
    float v = base[idx] + (p >= 0 ? up[(size_t)p * HIDF + (idx & 255)] : 0.f);
    __bf16 h = (__bf16)v;
    oh[idx] = h;
    ol[idx] = (__bf16)(v - (float)h);
  }
}

static __global__ void log_softmax_k(const float* __restrict__ h, float* __restrict__ out, int f) {
  int row = blockIdx.x;
  int j = threadIdx.x;  // blockDim = 64 == f
  float vv = h[row * f + j];
  float m = vv;
#pragma unroll
  for (int o = 32; o > 0; o >>= 1) m = fmaxf(m, __shfl_xor(m, o, 64));
  float e = expf(vv - m), s = e;
#pragma unroll
  for (int o = 32; o > 0; o >>= 1) s += __shfl_xor(s, o, 64);
  out[row * f + j] = vv - m - logf(s);
}

// ---------------- host ----------------
extern "C" void kernel_launch(void* const* d_in, const int* in_sizes, int n_in,
                              void* d_out, int out_size, void* d_ws, size_t ws_size,
                              hipStream_t stream) {
  const float* x  = (const float*)d_in[0];
  const int* ei   = (const int*)d_in[1];
  const float* W0 = (const float*)d_in[2];
  const float* b0 = (const float*)d_in[3];
  const float* W1 = (const float*)d_in[4];
  const float* b1 = (const float*)d_in[5];
  const float* W2 = (const float*)d_in[6];
  const float* b2 = (const float*)d_in[7];
  const float* W3 = (const float*)d_in[8];
  const float* b3 = (const float*)d_in[9];
  const float* p1 = (const float*)d_in[10];
  const float* p2 = (const float*)d_in[11];
  const float* p3 = (const float*)d_in[12];
  const float* U0 = (const float*)d_in[13];
  const float* c0 = (const float*)d_in[14];
  const float* U1 = (const float*)d_in[15];
  const float* c1 = (const float*)d_in[16];
  const float* U2 = (const float*)d_in[17];
  const float* c2 = (const float*)d_in[18];
  (void)in_sizes; (void)n_in; (void)out_size; (void)ws_size;

  char* basep = (char*)d_ws;
  size_t off = 0;
  auto alloc = [&](size_t bytes) {
    void* p = basep + off;
    off += (bytes + 255) & ~(size_t)255;
    return p;
  };

  // fp32 mats
  float* A1  = (float*)alloc((size_t)KP1 * KP1 * 4);
  float* A2  = (float*)alloc((size_t)KP2 * KP2 * 4);
  float* A3  = (float*)alloc((size_t)KP3 * KP3 * 4);
  float* xw  = (float*)alloc((size_t)N0 * HIDF * 4);
  float* zb  = (float*)alloc((size_t)N0 * HIDF * 4);
  float* x0  = (float*)alloc((size_t)N0 * HIDF * 4);
  float* x1  = (float*)alloc((size_t)KP1 * HIDF * 4);
  float* x2  = (float*)alloc((size_t)KP2 * HIDF * 4);
  float* x3  = (float*)alloc((size_t)KP3 * HIDF * 4);
  float* hb  = (float*)alloc((size_t)N0 * HIDF * 4);
  float* xfin = (float*)alloc((size_t)N0 * OUTC * 4);
  float* Cpart = (float*)alloc((size_t)16 * 1024 * 1024);  // split-K partials (max 12.3 MB)
  // bf16 scratch
  __bf16* bfAh = (__bf16*)alloc((size_t)N0 * INC * 2);
  __bf16* bfAl = (__bf16*)alloc((size_t)N0 * INC * 2);
  __bf16* bfBh = (__bf16*)alloc((size_t)HIDF * KP1P * 2);
  __bf16* bfBl = (__bf16*)alloc((size_t)HIDF * KP1P * 2);
  __bf16* A1bf  = (__bf16*)alloc((size_t)KP1 * KP1P * 2);
  __bf16* A1tbf = (__bf16*)alloc((size_t)KP1 * KP1P * 2);
  __bf16* Ag    = (__bf16*)alloc((size_t)KP2 * KP1P * 2);
  __bf16* Bg    = (__bf16*)alloc((size_t)KP2 * KP1P * 2);
  __bf16* A2bh  = (__bf16*)alloc((size_t)KP2 * KP2P * 2);
  __bf16* A2bl  = (__bf16*)alloc((size_t)KP2 * KP2P * 2);
  __bf16* A2tbh = (__bf16*)alloc((size_t)KP2 * KP2P * 2);
  __bf16* A2tbl = (__bf16*)alloc((size_t)KP2 * KP2P * 2);
  __bf16* Agh   = (__bf16*)alloc((size_t)KP3 * KP2P * 2);
  __bf16* Agl   = (__bf16*)alloc((size_t)KP3 * KP2P * 2);
  __bf16* Bgh   = (__bf16*)alloc((size_t)KP3 * KP2P * 2);
  __bf16* Bgl   = (__bf16*)alloc((size_t)KP3 * KP2P * 2);
  __bf16* A3bh  = (__bf16*)alloc((size_t)KP3 * KP3P * 2);
  __bf16* A3bl  = (__bf16*)alloc((size_t)KP3 * KP3P * 2);
  // small
  float* sc   = (float*)alloc(N0 * 4);
  float* sv   = (float*)alloc(KP1 * 4);
  int* perm1  = (int*)alloc(KP1 * 4);
  int* perm2  = (int*)alloc(KP2 * 4);
  int* perm3  = (int*)alloc(KP3 * 4);
  int* pos1   = (int*)alloc(N0 * 4);
  int* pos2   = (int*)alloc(KP1 * 4);
  int* pos3   = (int*)alloc(KP2 * 4);
  float* dis0 = (float*)alloc(N0 * 4);
  float* dis1 = (float*)alloc(KP1 * 4);
  float* dis2 = (float*)alloc(KP2 * 4);
  float* dis3 = (float*)alloc(KP3 * 4);
  float* nrm  = (float*)alloc(256);
  int* cnt_d  = (int*)alloc(N0 * 4);
  int* st_d   = (int*)alloc((N0 + 4) * 4);
  int* fl_d   = (int*)alloc(N0 * 4);
  int* bk_d   = (int*)alloc(NE * 4);

  // mgemm with split-K into Cpart
  auto mg = [&](const __bf16* a0, const __bf16* a1, const __bf16* a2,
                const __bf16* bb0, const __bf16* bb1, const __bf16* bb2,
                int nseg, float* Cp, int M, int N, int Kp, int ks, int kchunk) {
    dim3 g((N + 63) / 64, (M + 63) / 64, ks);
    mgemm_k<<<g, 256, 0, stream>>>(a0, a1, a2, bb0, bb1, bb2, nseg, Cp, M, N, Kp, kchunk);
  };

  // weight GEMM (bfAh/bfAl hold hi/lo A [n][Kp]); result reduced into xw
  auto wgemm = [&](const float* W, int fin, int fout, int n, int ks, int kchunk) {
    int Kp = (fin + 63) & ~63;
    dim3 tg(Kp / 32, (fout + 31) / 32);
    tconv_k<<<tg, 256, 0, stream>>>(W, fin, fout, Kp, bfBh, bfBl, nullptr);
    mg(bfAh, bfAh, bfAl, bfBh, bfBl, bfBh, 3, Cpart, n, fout, Kp, ks, kchunk);
    int mn = n * fout;
    reduce_k<<<(mn + 255) / 256, 256, 0, stream>>>(Cpart, ks, mn, xw);
  };

  // dense propagation: out = relu?(dis*(A@(dis*xw)) + 2 dis^2 xw + b)
  auto prop = [&](const __bf16* Abh, const __bf16* Abl, int asegs, int n, int Kp, int ks, int kchunk,
                  const float* disv, const float* bias, float* outx, int relu) {
    dim3 tg(Kp / 32, HIDF / 32);
    tconv_k<<<tg, 256, 0, stream>>>(xw, n, HIDF, Kp, bfBh, bfBl, disv);
    if (asegs == 1) mg(Abh, Abh, nullptr, bfBh, bfBl, nullptr, 2, Cpart, n, HIDF, Kp, ks, kchunk);
    else            mg(Abh, Abh, Abl, bfBh, bfBl, bfBh, 3, Cpart, n, HIDF, Kp, ks, kchunk);
    conv_epi_k<<<(n * HIDF + 255) / 256, 256, 0, stream>>>(Cpart, ks, n * HIDF, xw, disv, bias,
                                                           outx, n, HIDF, relu);
  };

  auto pool = [&](const float* xfeat, int n, const float* p, int k, int* perm, int* pos) {
    norm_k<<<1, 256, 0, stream>>>(p, HIDF, nrm);
    score_k<<<n, 256, 0, stream>>>(xfeat, p, nrm, sc, HIDF);
    topk_rank_k<<<(n + 255) / 256, 256, 0, stream>>>(sc, n, k, perm, sv);
    hipMemsetAsync(pos, 0xFF, n * 4, stream);
    setpos_k<<<(k + 255) / 256, 256, 0, stream>>>(perm, k, pos);
  };

  // ---- CSR build ----
  hipMemsetAsync(cnt_d, 0, N0 * 4, stream);
  hipMemsetAsync(fl_d, 0, N0 * 4, stream);
  count_k<<<(NE + 255) / 256, 256, 0, stream>>>(ei, cnt_d);
  scan_excl_k<<<1, 1024, 0, stream>>>(cnt_d, st_d, N0);
  scatter_k<<<(NE + 255) / 256, 256, 0, stream>>>(ei, st_d, fl_d, bk_d);
  dis0_k<<<(N0 + 255) / 256, 256, 0, stream>>>(cnt_d, dis0);

  // ---- down conv 0 (sparse propagation) ----
  conv_hilo_k<<<((size_t)N0 * INC + 255) / 256, 256, 0, stream>>>(x, N0, INC, INC, bfAh, bfAl);
  wgemm(W0, INC, HIDF, N0, 4, 128);
  spmm_sc_k<<<N0, HIDF, 0, stream>>>(st_d, bk_d, xw, dis0, zb, HIDF);
  conv_epi_k<<<(N0 * HIDF + 255) / 256, 256, 0, stream>>>(zb, 1, 0, xw, dis0, b0, x0, N0, HIDF, 1);

  // ---- pool 1 + masked augment(A) -> A1 (f32 + exact bf16) + dis1 ----
  pool(x0, N0, p1, KP1, perm1, pos1);
  augA_masked_k<<<KP1, 256, 0, stream>>>(st_d, bk_d, perm1, pos1, A1, A1bf, dis1);

  // ---- conv 1 ----
  ghilo_k<<<((size_t)KP1 * HIDF + 255) / 256, 256, 0, stream>>>(x0, perm1, sv, bfAh, bfAl, KP1);
  wgemm(W1, HIDF, HIDF, KP1, 4, 64);
  prop(A1bf, nullptr, 1, KP1, KP1P, 4, 512, dis1, b1, x1, 1);

  // ---- pool 2 + masked augment(A1): A2 = A1[perm2,:] @ (A1+2I)[:,perm2] ----
  pool(x1, KP1, p2, KP2, perm2, pos2);
  {
    dim3 tg(KP1P / 32, (KP1 + 31) / 32);
    tconv_k<<<tg, 256, 0, stream>>>(A1, KP1, KP1, KP1P, A1tbf, nullptr, nullptr);
  }
  grows_k<<<((size_t)KP2 * (KP1P / 8) + 255) / 256, 256, 0, stream>>>(A1bf, perm2, Ag, KP2, KP1P, 0);
  grows_k<<<((size_t)KP2 * (KP1P / 8) + 255) / 256, 256, 0, stream>>>(A1tbf, perm2, Bg, KP2, KP1P, 1);
  mg(Ag, nullptr, nullptr, Bg, nullptr, nullptr, 1, Cpart, KP2, KP2, KP1P, 2, 1024);
  aug_epi_k<<<KP2, 256, 0, stream>>>(Cpart, 2, KP2 * KP2, KP2, KP2P, A2, A2bh, A2bl, dis2);

  // ---- conv 2 ----
  ghilo_k<<<((size_t)KP2 * HIDF + 255) / 256, 256, 0, stream>>>(x1, perm2, sv, bfAh, bfAl, KP2);
  wgemm(W2, HIDF, HIDF, KP2, 4, 64);
  prop(A2bh, A2bl, 2, KP2, KP2P, 8, 128, dis2, b2, x2, 1);

  // ---- pool 3 + masked augment(A2), hi/lo 3-seg ----
  pool(x2, KP2, p3, KP3, perm3, pos3);
  {
    dim3 tg(KP2P / 32, (KP2 + 31) / 32);
    tconv_k<<<tg, 256, 0, stream>>>(A2, KP2, KP2, KP2P, A2tbh, A2tbl, nullptr);
  }
  grows_k<<<((size_t)KP3 * (KP2P / 8) + 255) / 256, 256, 0, stream>>>(A2bh, perm3, Agh, KP3, KP2P, 0);
  grows_k<<<((size_t)KP3 * (KP2P / 8) + 255) / 256, 256, 0, stream>>>(A2bl, perm3, Agl, KP3, KP2P, 0);
  grows_k<<<((size_t)KP3 * (KP2P / 8) + 255) / 256, 256, 0, stream>>>(A2tbh, perm3, Bgh, KP3, KP2P, 0);
  grows_k<<<((size_t)KP3 * (KP2P / 8) + 255) / 256, 256, 0, stream>>>(A2tbl, perm3, Bgl, KP3, KP2P, 1);
  mg(Agh, Agh, Agl, Bgh, Bgl, Bgh, 3, Cpart, KP3, KP3, KP2P, 8, 128);
  aug_epi_k<<<KP3, 256, 0, stream>>>(Cpart, 8, KP3 * KP3, KP3, KP3P, A3, A3bh, A3bl, dis3);

  // ---- conv 3 ----
  ghilo_k<<<((size_t)KP3 * HIDF + 255) / 256, 256, 0, stream>>>(x2, perm3, sv, bfAh, bfAl, KP3);
  wgemm(W3, HIDF, HIDF, KP3, 4, 64);
  prop(A3bh, A3bl, 2, KP3, KP3P, 8, 64, dis3, b3, x3, 1);

  // ---- up path ----
  unpool_hilo_k<<<(KP2 * HIDF + 255) / 256, 256, 0, stream>>>(x2, x3, pos3, bfAh, bfAl, KP2);
  wgemm(U0, HIDF, HIDF, KP2, 4, 64);
  prop(A2bh, A2bl, 2, KP2, KP2P, 8, 128, dis2, c0, hb, 1);

  unpool_hilo_k<<<(KP1 * HIDF + 255) / 256, 256, 0, stream>>>(x1, hb, pos2, bfAh, bfAl, KP1);
  wgemm(U1, HIDF, HIDF, KP1, 4, 64);
  prop(A1bf, nullptr, 1, KP1, KP1P, 4, 512, dis1, c1, hb, 1);

  unpool_hilo_k<<<(N0 * HIDF + 255) / 256, 256, 0, stream>>>(x0, hb, pos1, bfAh, bfAl, N0);
  wgemm(U2, HIDF, OUTC, N0, 4, 64);
  spmm_sc_k<<<N0, OUTC, 0, stream>>>(st_d, bk_d, xw, dis0, zb, OUTC);
  conv_epi_k<<<(N0 * OUTC + 255) / 256, 256, 0, stream>>>(zb, 1, 0, xw, dis0, c2, xfin, N0, OUTC, 0);

  // ---- log_softmax ----
  log_softmax_k<<<N0, 64, 0, stream>>>(xfin, (float*)d_out, OUTC);
}

// Round 5
// 578.680 us; speedup vs baseline: 6.3729x; 1.1026x over previous
//
#include <hip/hip_runtime.h>
#include <math.h>
#include <stdint.h>

#define N0   3000
#define NE   96000
#define INC  512
#define HIDF 256
#define OUTC 64
#define KP1  2000
#define KP2  1000
#define KP3  500
#define KP1P 2048
#define KP2P 1024
#define KP3P 512

typedef __bf16 bf16x8 __attribute__((ext_vector_type(8)));
typedef float f32x4 __attribute__((ext_vector_type(4)));

// ---------------- CSR build (in-edges by dst) ----------------
static __global__ void count_k(const int* __restrict__ ei, int* __restrict__ cd) {
  int e = blockIdx.x * blockDim.x + threadIdx.x;
  if (e < NE) atomicAdd(&cd[ei[NE + e]], 1);
}

static __global__ __launch_bounds__(1024) void scan_excl_k(const int* __restrict__ cnt,
                                                           int* __restrict__ start, int n) {
  __shared__ int s[4096];
  int tid = threadIdx.x;
  for (int i = tid; i < 4096; i += blockDim.x) s[i] = (i < n) ? cnt[i] : 0;
  __syncthreads();
  for (int d = 1; d < 4096; d <<= 1) {
    int v[4]; int r = 0;
    for (int i = tid; i < 4096; i += blockDim.x, ++r) v[r] = (i >= d) ? s[i - d] : 0;
    __syncthreads();
    r = 0;
    for (int i = tid; i < 4096; i += blockDim.x, ++r) s[i] += v[r];
    __syncthreads();
  }
  for (int i = tid; i < n; i += blockDim.x) start[i] = (i == 0) ? 0 : s[i - 1];
  if (tid == 0) start[n] = s[n - 1];
}

static __global__ void scatter_k(const int* __restrict__ ei, const int* __restrict__ sd,
                                 int* __restrict__ fd, int* __restrict__ bd) {
  int e = blockIdx.x * blockDim.x + threadIdx.x;
  if (e < NE) {
    int d = ei[NE + e];
    bd[sd[d] + atomicAdd(&fd[d], 1)] = ei[e];
  }
}

static __global__ void dis0_k(const int* __restrict__ cd, float* __restrict__ dis0) {
  int i = blockIdx.x * blockDim.x + threadIdx.x;
  if (i < N0) dis0[i] = rsqrtf((float)cd[i] + 2.0f);
}

// ---------------- masked augment level 0 ----------------
static __global__ __launch_bounds__(256) void augA_masked_k(
    const int* __restrict__ st, const int* __restrict__ bk,
    const int* __restrict__ perm, const int* __restrict__ pos,
    float* __restrict__ A1, __bf16* __restrict__ A1bf, float* __restrict__ dis1) {
  __shared__ float row[KP1];
  __shared__ float sh[4];
  int tid = threadIdx.x, lane = tid & 63, wave = tid >> 6;
  int r = blockIdx.x;
  int vi = perm[r];
  for (int c = tid; c < KP1; c += 256) row[c] = 0.f;
  __syncthreads();
  int b = st[vi], e = st[vi + 1];
  for (int t = b + wave; t < e; t += 4) {
    int k = bk[t];
    int jb = st[k], je = st[k + 1];
    for (int u = jb + lane; u < je; u += 64) {
      int p = pos[bk[u]];
      if (p >= 0) atomicAdd(&row[p], 1.0f);
    }
  }
  if (wave == 0)
    for (int t = b + lane; t < e; t += 64) {
      int p = pos[bk[t]];
      if (p >= 0) atomicAdd(&row[p], 2.0f);
    }
  __syncthreads();
  if (tid == 0) row[r] = 0.f;
  __syncthreads();
  float s = 0.f;
  for (int c = tid; c < KP1P; c += 256) {
    float v = (c < KP1) ? row[c] : 0.f;
    if (c < KP1) A1[(size_t)r * KP1 + c] = v;
    A1bf[(size_t)r * KP1P + c] = (__bf16)v;  // small counts: exact in bf16
    s += v;
  }
#pragma unroll
  for (int o = 32; o > 0; o >>= 1) s += __shfl_down(s, o, 64);
  if (lane == 0) sh[wave] = s;
  __syncthreads();
  if (tid == 0) dis1[r] = rsqrtf(sh[0] + sh[1] + sh[2] + sh[3] + 2.0f);
}

// ---------------- SpMM with fused source scaling ----------------
static __global__ void spmm_sc_k(const int* __restrict__ start, const int* __restrict__ idx,
                                 const float* __restrict__ xw, const float* __restrict__ dis,
                                 float* __restrict__ out, int F) {
  int row = blockIdx.x;
  int b = start[row], e = start[row + 1];
  int f = threadIdx.x;  // blockDim == F
  __shared__ int nb[256];
  __shared__ float nd[256];
  float acc = 0.f;
  for (int t0 = b; t0 < e; t0 += blockDim.x) {
    int m = min((int)blockDim.x, e - t0);
    __syncthreads();
    if (f < m) { int s = idx[t0 + f]; nb[f] = s; nd[f] = dis[s]; }
    __syncthreads();
    for (int t = 0; t < m; ++t) acc += xw[(size_t)nb[t] * F + f] * nd[t];
  }
  out[(size_t)row * F + f] = acc;
}

// ---------------- converters ----------------
static __global__ void conv_hilo_k(const float* __restrict__ in, int R, int C, int Cp,
                                   __bf16* __restrict__ oh, __bf16* __restrict__ ol) {
  int idx = blockIdx.x * blockDim.x + threadIdx.x;
  if (idx < R * Cp) {
    int r = idx / Cp, c = idx - r * Cp;
    float v = (c < C) ? in[(size_t)r * C + c] : 0.f;
    __bf16 h = (__bf16)v;
    oh[idx] = h;
    if (ol) ol[idx] = (__bf16)(v - (float)h);
  }
}

// transpose+convert (+optional per-input-row scale)
static __global__ __launch_bounds__(256) void tconv_k(const float* __restrict__ in, int R, int C, int Rp,
                                                      __bf16* __restrict__ oh, __bf16* __restrict__ ol,
                                                      const float* __restrict__ disv) {
  __shared__ float t[32][33];
  int r0 = blockIdx.x * 32, c0 = blockIdx.y * 32;
  int lr = threadIdx.x >> 5, lc = threadIdx.x & 31;
#pragma unroll
  for (int i = 0; i < 4; ++i) {
    int r = r0 + lr + i * 8, c = c0 + lc;
    t[lr + i * 8][lc] = (r < R && c < C) ? in[(size_t)r * C + c] : 0.f;
  }
  __syncthreads();
#pragma unroll
  for (int i = 0; i < 4; ++i) {
    int c = c0 + lr + i * 8, r = r0 + lc;
    if (c < C) {
      float v = t[lc][lr + i * 8];
      if (disv && r < R) v *= disv[r];
      __bf16 h = (__bf16)v;
      oh[(size_t)c * Rp + r] = h;
      if (ol) ol[(size_t)c * Rp + r] = (__bf16)(v - (float)h);
    }
  }
}

static __global__ void grows_k(const __bf16* __restrict__ src, const int* __restrict__ perm,
                               __bf16* __restrict__ dst, int k, int L, int addI) {
  int idx = blockIdx.x * blockDim.x + threadIdx.x;
  int nv = L >> 3;
  if (idx < k * nv) {
    int r = idx / nv, c8 = (idx - r * nv) << 3;
    int sr = perm[r];
    bf16x8 v = *(const bf16x8*)(src + (size_t)sr * L + c8);
    if (addI && sr >= c8 && sr < c8 + 8) v[sr - c8] = (__bf16)((float)v[sr - c8] + 2.0f);
    *(bf16x8*)(dst + (size_t)r * L + c8) = v;
  }
}

static __global__ void ghilo_k(const float* __restrict__ src, const int* __restrict__ perm,
                               const float* __restrict__ sv, __bf16* __restrict__ oh,
                               __bf16* __restrict__ ol, int k) {
  int idx = blockIdx.x * blockDim.x + threadIdx.x;
  if (idx < k * HIDF) {
    int r = idx >> 8;
    float v = src[(size_t)perm[r] * HIDF + (idx & 255)] * sv[r];
    __bf16 h = (__bf16)v;
    oh[idx] = h;
    ol[idx] = (__bf16)(v - (float)h);
  }
}

// ---------------- MFMA GEMM with split-K partials ----------------
// C_partial[z] = sum_seg A_s @ B_s^T over K range [z*kchunk, ...); Kp % 64 == 0, kchunk % 64 == 0.
// LDS rows are 64 bf16 (128 B); 16B-slot XOR swizzle (slot ^= row&7): writes and reads both <=2-way.
template <int BM, int BN>
static __global__ __launch_bounds__(256) void mgemm_k(
    const __bf16* __restrict__ A0, const __bf16* __restrict__ A1g, const __bf16* __restrict__ A2g,
    const __bf16* __restrict__ B0, const __bf16* __restrict__ B1g, const __bf16* __restrict__ B2g,
    int nseg, float* __restrict__ Cp, int M, int N, int Kp, int kchunk) {
  constexpr int FM = BM / 32, FN = BN / 32;  // wave tile (BM/2)x(BN/2), 16x16 frags
  __shared__ __bf16 As[BM * 64];
  __shared__ __bf16 Bs[BN * 64];
  int tid = threadIdx.x;
  int lane = tid & 63, wave = tid >> 6;
  int wx = wave & 1, wy = wave >> 1;
  int l15 = lane & 15, l4 = lane >> 4;
  int brow = blockIdx.y * BM, bcol = blockIdx.x * BN;
  int wrow = wy * (BM / 2), wcol = wx * (BN / 2);
  int sr = tid >> 3, s0 = tid & 7;  // one 16B slot per thread, 8 threads/row, 32 rows/iter
  int k_beg = blockIdx.z * kchunk;
  int k_end = min(k_beg + kchunk, Kp);
  f32x4 acc[FM][FN] = {};
  for (int s = 0; s < nseg; ++s) {
    const __bf16* Ag = (s == 0) ? A0 : (s == 1) ? A1g : A2g;
    const __bf16* Bg = (s == 0) ? B0 : (s == 1) ? B1g : B2g;
    for (int k0 = k_beg; k0 < k_end; k0 += 64) {
      __syncthreads();
#pragma unroll
      for (int r0 = 0; r0 < BM; r0 += 32) {
        int row = r0 + sr;
        int gr = brow + row;
        bf16x8 v = {};
        if (gr < M) v = *(const bf16x8*)(Ag + (size_t)gr * Kp + k0 + s0 * 8);
        *(bf16x8*)(&As[row * 64 + ((s0 ^ (row & 7)) << 3)]) = v;
      }
#pragma unroll
      for (int r0 = 0; r0 < BN; r0 += 32) {
        int row = r0 + sr;
        int gc = bcol + row;
        bf16x8 v = {};
        if (gc < N) v = *(const bf16x8*)(Bg + (size_t)gc * Kp + k0 + s0 * 8);
        *(bf16x8*)(&Bs[row * 64 + ((s0 ^ (row & 7)) << 3)]) = v;
      }
      __syncthreads();
#pragma unroll
      for (int sub = 0; sub < 2; ++sub) {
        bf16x8 af[FM], bfv[FN];
#pragma unroll
        for (int i = 0; i < FM; ++i) {
          int r = wrow + i * 16 + l15;
          af[i] = *(const bf16x8*)(&As[r * 64 + (((sub * 4 + l4) ^ (r & 7)) << 3)]);
        }
#pragma unroll
        for (int j = 0; j < FN; ++j) {
          int r = wcol + j * 16 + l15;
          bfv[j] = *(const bf16x8*)(&Bs[r * 64 + (((sub * 4 + l4) ^ (r & 7)) << 3)]);
        }
#pragma unroll
        for (int i = 0; i < FM; ++i)
#pragma unroll
          for (int j = 0; j < FN; ++j)
            acc[i][j] = __builtin_amdgcn_mfma_f32_16x16x32_bf16(af[i], bfv[j], acc[i][j], 0, 0, 0);
      }
    }
  }
  size_t zoff = (size_t)blockIdx.z * M * N;
#pragma unroll
  for (int i = 0; i < FM; ++i)
#pragma unroll
    for (int j = 0; j < FN; ++j) {
      int col = bcol + wcol + j * 16 + l15;
      if (col < N) {
#pragma unroll
        for (int q = 0; q < 4; ++q) {
          int row = brow + wrow + i * 16 + l4 * 4 + q;
          if (row < M) Cp[zoff + (size_t)row * N + col] = acc[i][j][q];
        }
      }
    }
}

// ---------------- reductions / epilogues ----------------
static __global__ void reduce_k(const float* __restrict__ p, int ks, int mn, float* __restrict__ out) {
  int idx = blockIdx.x * blockDim.x + threadIdx.x;
  if (idx < mn) {
    float s = 0.f;
    for (int z = 0; z < ks; ++z) s += p[(size_t)z * mn + idx];
    out[idx] = s;
  }
}

static __global__ void conv_epi_k(const float* __restrict__ zp, int ks, int mn,
                                  const float* __restrict__ xw, const float* __restrict__ dis,
                                  const float* __restrict__ b, float* __restrict__ out,
                                  int n, int f, int relu) {
  int idx = blockIdx.x * blockDim.x + threadIdx.x;
  if (idx < n * f) {
    float zv = 0.f;
    for (int z = 0; z < ks; ++z) zv += zp[(size_t)z * mn + idx];
    int i = idx / f, j = idx - i * f;
    float di = dis[i];
    float v = di * zv + 2.0f * di * di * xw[idx] + b[j];
    if (relu) v = fmaxf(v, 0.0f);
    out[idx] = v;
  }
}

// split-K reduce + zero diag + rowsum->dis + f32 + hi/lo bf16 (padded)
static __global__ __launch_bounds__(256) void aug_epi_k(const float* __restrict__ Cp, int ks, int mn,
                                                        int n, int Kpad, float* __restrict__ Af,
                                                        __bf16* __restrict__ bh, __bf16* __restrict__ bl,
                                                        float* __restrict__ dis) {
  __shared__ float sh[4];
  int r = blockIdx.x;
  int tid = threadIdx.x, lane = tid & 63, wave = tid >> 6;
  float ssum = 0.f;
  for (int c = tid; c < Kpad; c += 256) {
    float v = 0.f;
    if (c < n && c != r)
      for (int z = 0; z < ks; ++z) v += Cp[(size_t)z * mn + (size_t)r * n + c];
    if (c < n) Af[(size_t)r * n + c] = v;
    __bf16 h = (__bf16)v;
    bh[(size_t)r * Kpad + c] = h;
    bl[(size_t)r * Kpad + c] = (__bf16)(v - (float)h);
    ssum += v;
  }
#pragma unroll
  for (int o = 32; o > 0; o >>= 1) ssum += __shfl_down(ssum, o, 64);
  if (lane == 0) sh[wave] = ssum;
  __syncthreads();
  if (tid == 0) dis[r] = rsqrtf(sh[0] + sh[1] + sh[2] + sh[3] + 2.0f);
}

// ---------------- pooling ----------------
static __global__ void norm_k(const float* __restrict__ w, int n, float* __restrict__ out) {
  float s = 0.f;
  for (int i = threadIdx.x; i < n; i += blockDim.x) { float v = w[i]; s += v * v; }
  __shared__ float sh[8];
  int lane = threadIdx.x & 63, wid = threadIdx.x >> 6;
#pragma unroll
  for (int o = 32; o > 0; o >>= 1) s += __shfl_down(s, o, 64);
  if (lane == 0) sh[wid] = s;
  __syncthreads();
  if (threadIdx.x == 0) {
    float t = 0.f;
    int nw = (blockDim.x + 63) >> 6;
    for (int w2 = 0; w2 < nw; ++w2) t += sh[w2];
    out[0] = sqrtf(t);
  }
}

static __global__ void score_k(const float* __restrict__ x, const float* __restrict__ w,
                               const float* __restrict__ nrm, float* __restrict__ sc, int f) {
  int row = blockIdx.x;
  float s = 0.f;
  for (int j = threadIdx.x; j < f; j += blockDim.x) s += x[(size_t)row * f + j] * w[j];
  __shared__ float sh[8];
  int lane = threadIdx.x & 63, wid = threadIdx.x >> 6;
#pragma unroll
  for (int o = 32; o > 0; o >>= 1) s += __shfl_down(s, o, 64);
  if (lane == 0) sh[wid] = s;
  __syncthreads();
  if (threadIdx.x == 0) {
    float t = 0.f;
    int nw = (blockDim.x + 63) >> 6;
    for (int w2 = 0; w2 < nw; ++w2) t += sh[w2];
    sc[row] = tanhf(t / nrm[0]);
  }
}

// exact jax.lax.top_k: wave-per-candidate; lanes split the scan, shfl-reduce rank
static __global__ __launch_bounds__(256) void topk_rank_k(const float* __restrict__ sc, int n, int k,
                                                          int* __restrict__ perm, float* __restrict__ sv) {
  __shared__ float s[N0 + 8];
  int tid = threadIdx.x, lane = tid & 63, wave = tid >> 6;
  for (int i = tid; i < n; i += 256) s[i] = sc[i];
  __syncthreads();
  int i = blockIdx.x * 4 + wave;
  if (i < n) {
    float si = s[i];
    int rank = 0;
    for (int j = lane; j < n; j += 64) {
      float sj = s[j];
      rank += (sj > si) || (sj == si && j < i);
    }
#pragma unroll
    for (int o = 32; o > 0; o >>= 1) rank += __shfl_down(rank, o, 64);
    if (lane == 0 && rank < k) { perm[rank] = i; sv[rank] = si; }
  }
}

static __global__ void setpos_k(const int* __restrict__ perm, int k, int* __restrict__ pos) {
  int i = blockIdx.x * blockDim.x + threadIdx.x;
  if (i < k) pos[perm[i]] = i;
}

static __global__ void unpool_hilo_k(const float* __restrict__ base, const float* __restrict__ up,
                                     const int* __restrict__ pos, __bf16* __restrict__ oh,
                                     __bf16* __restrict__ ol, int n) {
  int idx = blockIdx.x * blockDim.x + threadIdx.x;
  if (idx < n * HIDF) {
    int i = idx >> 8;
    int p = pos[i];
    float v = base[idx] + (p >= 0 ? up[(size_t)p * HIDF + (idx & 255)] : 0.f);
    __bf16 h = (__bf16)v;
    oh[idx] = h;
    ol[idx] = (__bf16)(v - (float)h);
  }
}

static __global__ void log_softmax_k(const float* __restrict__ h, float* __restrict__ out, int f) {
  int row = blockIdx.x;
  int j = threadIdx.x;  // blockDim = 64 == f
  float vv = h[row * f + j];
  float m = vv;
#pragma unroll
  for (int o = 32; o > 0; o >>= 1) m = fmaxf(m, __shfl_xor(m, o, 64));
  float e = expf(vv - m), s = e;
#pragma unroll
  for (int o = 32; o > 0; o >>= 1) s += __shfl_xor(s, o, 64);
  out[row * f + j] = vv - m - logf(s);
}

// ---------------- host ----------------
extern "C" void kernel_launch(void* const* d_in, const int* in_sizes, int n_in,
                              void* d_out, int out_size, void* d_ws, size_t ws_size,
                              hipStream_t stream) {
  const float* x  = (const float*)d_in[0];
  const int* ei   = (const int*)d_in[1];
  const float* W0 = (const float*)d_in[2];
  const float* b0 = (const float*)d_in[3];
  const float* W1 = (const float*)d_in[4];
  const float* b1 = (const float*)d_in[5];
  const float* W2 = (const float*)d_in[6];
  const float* b2 = (const float*)d_in[7];
  const float* W3 = (const float*)d_in[8];
  const float* b3 = (const float*)d_in[9];
  const float* p1 = (const float*)d_in[10];
  const float* p2 = (const float*)d_in[11];
  const float* p3 = (const float*)d_in[12];
  const float* U0 = (const float*)d_in[13];
  const float* c0 = (const float*)d_in[14];
  const float* U1 = (const float*)d_in[15];
  const float* c1 = (const float*)d_in[16];
  const float* U2 = (const float*)d_in[17];
  const float* c2 = (const float*)d_in[18];
  (void)in_sizes; (void)n_in; (void)out_size; (void)ws_size;

  char* basep = (char*)d_ws;
  size_t off = 0;
  auto alloc = [&](size_t bytes) {
    void* p = basep + off;
    off += (bytes + 255) & ~(size_t)255;
    return p;
  };

  // fp32 mats
  float* A1  = (float*)alloc((size_t)KP1 * KP1 * 4);
  float* A2  = (float*)alloc((size_t)KP2 * KP2 * 4);
  float* A3  = (float*)alloc((size_t)KP3 * KP3 * 4);
  float* xw  = (float*)alloc((size_t)N0 * HIDF * 4);
  float* zb  = (float*)alloc((size_t)N0 * HIDF * 4);
  float* x0  = (float*)alloc((size_t)N0 * HIDF * 4);
  float* x1  = (float*)alloc((size_t)KP1 * HIDF * 4);
  float* x2  = (float*)alloc((size_t)KP2 * HIDF * 4);
  float* x3  = (float*)alloc((size_t)KP3 * HIDF * 4);
  float* hb  = (float*)alloc((size_t)N0 * HIDF * 4);
  float* xfin = (float*)alloc((size_t)N0 * OUTC * 4);
  float* Cpart = (float*)alloc((size_t)32 * 1024 * 1024);  // split-K partials (max 24.6 MB)
  // bf16 scratch
  __bf16* bfAh = (__bf16*)alloc((size_t)N0 * INC * 2);
  __bf16* bfAl = (__bf16*)alloc((size_t)N0 * INC * 2);
  __bf16* bfBh = (__bf16*)alloc((size_t)HIDF * KP1P * 2);
  __bf16* bfBl = (__bf16*)alloc((size_t)HIDF * KP1P * 2);
  __bf16* A1bf  = (__bf16*)alloc((size_t)KP1 * KP1P * 2);
  __bf16* A1tbf = (__bf16*)alloc((size_t)KP1 * KP1P * 2);
  __bf16* Ag    = (__bf16*)alloc((size_t)KP2 * KP1P * 2);
  __bf16* Bg    = (__bf16*)alloc((size_t)KP2 * KP1P * 2);
  __bf16* A2bh  = (__bf16*)alloc((size_t)KP2 * KP2P * 2);
  __bf16* A2bl  = (__bf16*)alloc((size_t)KP2 * KP2P * 2);
  __bf16* A2tbh = (__bf16*)alloc((size_t)KP2 * KP2P * 2);
  __bf16* A2tbl = (__bf16*)alloc((size_t)KP2 * KP2P * 2);
  __bf16* Agh   = (__bf16*)alloc((size_t)KP3 * KP2P * 2);
  __bf16* Agl   = (__bf16*)alloc((size_t)KP3 * KP2P * 2);
  __bf16* Bgh   = (__bf16*)alloc((size_t)KP3 * KP2P * 2);
  __bf16* Bgl   = (__bf16*)alloc((size_t)KP3 * KP2P * 2);
  __bf16* A3bh  = (__bf16*)alloc((size_t)KP3 * KP3P * 2);
  __bf16* A3bl  = (__bf16*)alloc((size_t)KP3 * KP3P * 2);
  // small
  float* sc   = (float*)alloc(N0 * 4);
  float* sv   = (float*)alloc(KP1 * 4);
  int* perm1  = (int*)alloc(KP1 * 4);
  int* perm2  = (int*)alloc(KP2 * 4);
  int* perm3  = (int*)alloc(KP3 * 4);
  int* pos1   = (int*)alloc(N0 * 4);
  int* pos2   = (int*)alloc(KP1 * 4);
  int* pos3   = (int*)alloc(KP2 * 4);
  float* dis0 = (float*)alloc(N0 * 4);
  float* dis1 = (float*)alloc(KP1 * 4);
  float* dis2 = (float*)alloc(KP2 * 4);
  float* dis3 = (float*)alloc(KP3 * 4);
  float* nrm  = (float*)alloc(256);
  int* cnt_d  = (int*)alloc(N0 * 4);
  int* st_d   = (int*)alloc((N0 + 4) * 4);
  int* fl_d   = (int*)alloc(N0 * 4);
  int* bk_d   = (int*)alloc(NE * 4);

  // bm selects tile: 128 -> mgemm_k<128,128>, else mgemm_k<64,64>
  auto mg = [&](int bm, const __bf16* a0, const __bf16* a1, const __bf16* a2,
                const __bf16* bb0, const __bf16* bb1, const __bf16* bb2,
                int nseg, float* Cp, int M, int N, int Kp, int ks, int kchunk) {
    if (bm == 128) {
      dim3 g((N + 127) / 128, (M + 127) / 128, ks);
      mgemm_k<128, 128><<<g, 256, 0, stream>>>(a0, a1, a2, bb0, bb1, bb2, nseg, Cp, M, N, Kp, kchunk);
    } else {
      dim3 g((N + 63) / 64, (M + 63) / 64, ks);
      mgemm_k<64, 64><<<g, 256, 0, stream>>>(a0, a1, a2, bb0, bb1, bb2, nseg, Cp, M, N, Kp, kchunk);
    }
  };

  // weight GEMM (bfAh/bfAl hold hi/lo A [n][Kp]); result reduced into xw
  auto wgemm = [&](const float* W, int fin, int fout, int n, int bm, int ks, int kchunk) {
    int Kp = (fin + 63) & ~63;
    dim3 tg(Kp / 32, (fout + 31) / 32);
    tconv_k<<<tg, 256, 0, stream>>>(W, fin, fout, Kp, bfBh, bfBl, nullptr);
    mg(bm, bfAh, bfAh, bfAl, bfBh, bfBl, bfBh, 3, Cpart, n, fout, Kp, ks, kchunk);
    int mn = n * fout;
    reduce_k<<<(mn + 255) / 256, 256, 0, stream>>>(Cpart, ks, mn, xw);
  };

  // dense propagation: out = relu?(dis*(A@(dis*xw)) + 2 dis^2 xw + b)
  auto prop = [&](const __bf16* Abh, const __bf16* Abl, int asegs, int n, int Kp, int bm,
                  int ks, int kchunk, const float* disv, const float* bias, float* outx, int relu) {
    dim3 tg(Kp / 32, HIDF / 32);
    tconv_k<<<tg, 256, 0, stream>>>(xw, n, HIDF, Kp, bfBh, bfBl, disv);
    if (asegs == 1) mg(bm, Abh, Abh, nullptr, bfBh, bfBl, nullptr, 2, Cpart, n, HIDF, Kp, ks, kchunk);
    else            mg(bm, Abh, Abh, Abl, bfBh, bfBl, bfBh, 3, Cpart, n, HIDF, Kp, ks, kchunk);
    conv_epi_k<<<(n * HIDF + 255) / 256, 256, 0, stream>>>(Cpart, ks, n * HIDF, xw, disv, bias,
                                                           outx, n, HIDF, relu);
  };

  auto pool = [&](const float* xfeat, int n, const float* p, int k, int* perm, int* pos) {
    norm_k<<<1, 256, 0, stream>>>(p, HIDF, nrm);
    score_k<<<n, 256, 0, stream>>>(xfeat, p, nrm, sc, HIDF);
    topk_rank_k<<<(n + 3) / 4, 256, 0, stream>>>(sc, n, k, perm, sv);
    hipMemsetAsync(pos, 0xFF, n * 4, stream);
    setpos_k<<<(k + 255) / 256, 256, 0, stream>>>(perm, k, pos);
  };

  // ---- CSR build ----
  hipMemsetAsync(cnt_d, 0, N0 * 4, stream);
  hipMemsetAsync(fl_d, 0, N0 * 4, stream);
  count_k<<<(NE + 255) / 256, 256, 0, stream>>>(ei, cnt_d);
  scan_excl_k<<<1, 1024, 0, stream>>>(cnt_d, st_d, N0);
  scatter_k<<<(NE + 255) / 256, 256, 0, stream>>>(ei, st_d, fl_d, bk_d);
  dis0_k<<<(N0 + 255) / 256, 256, 0, stream>>>(cnt_d, dis0);

  // ---- down conv 0 (sparse propagation) ----
  conv_hilo_k<<<((size_t)N0 * INC + 255) / 256, 256, 0, stream>>>(x, N0, INC, INC, bfAh, bfAl);
  wgemm(W0, INC, HIDF, N0, 128, 8, 64);
  spmm_sc_k<<<N0, HIDF, 0, stream>>>(st_d, bk_d, xw, dis0, zb, HIDF);
  conv_epi_k<<<(N0 * HIDF + 255) / 256, 256, 0, stream>>>(zb, 1, 0, xw, dis0, b0, x0, N0, HIDF, 1);

  // ---- pool 1 + masked augment(A) ----
  pool(x0, N0, p1, KP1, perm1, pos1);
  augA_masked_k<<<KP1, 256, 0, stream>>>(st_d, bk_d, perm1, pos1, A1, A1bf, dis1);

  // ---- conv 1 ----
  ghilo_k<<<((size_t)KP1 * HIDF + 255) / 256, 256, 0, stream>>>(x0, perm1, sv, bfAh, bfAl, KP1);
  wgemm(W1, HIDF, HIDF, KP1, 64, 4, 64);
  prop(A1bf, nullptr, 1, KP1, KP1P, 128, 8, 256, dis1, b1, x1, 1);

  // ---- pool 2 + masked augment(A1): A2 = A1[perm2,:] @ (A1+2I)[:,perm2] ----
  pool(x1, KP1, p2, KP2, perm2, pos2);
  {
    dim3 tg(KP1P / 32, (KP1 + 31) / 32);
    tconv_k<<<tg, 256, 0, stream>>>(A1, KP1, KP1, KP1P, A1tbf, nullptr, nullptr);
  }
  grows_k<<<((size_t)KP2 * (KP1P / 8) + 255) / 256, 256, 0, stream>>>(A1bf, perm2, Ag, KP2, KP1P, 0);
  grows_k<<<((size_t)KP2 * (KP1P / 8) + 255) / 256, 256, 0, stream>>>(A1tbf, perm2, Bg, KP2, KP1P, 1);
  mg(128, Ag, nullptr, nullptr, Bg, nullptr, nullptr, 1, Cpart, KP2, KP2, KP1P, 4, 512);
  aug_epi_k<<<KP2, 256, 0, stream>>>(Cpart, 4, KP2 * KP2, KP2, KP2P, A2, A2bh, A2bl, dis2);

  // ---- conv 2 ----
  ghilo_k<<<((size_t)KP2 * HIDF + 255) / 256, 256, 0, stream>>>(x1, perm2, sv, bfAh, bfAl, KP2);
  wgemm(W2, HIDF, HIDF, KP2, 64, 4, 64);
  prop(A2bh, A2bl, 2, KP2, KP2P, 128, 16, 64, dis2, b2, x2, 1);

  // ---- pool 3 + masked augment(A2), hi/lo 3-seg ----
  pool(x2, KP2, p3, KP3, perm3, pos3);
  {
    dim3 tg(KP2P / 32, (KP2 + 31) / 32);
    tconv_k<<<tg, 256, 0, stream>>>(A2, KP2, KP2, KP2P, A2tbh, A2tbl, nullptr);
  }
  grows_k<<<((size_t)KP3 * (KP2P / 8) + 255) / 256, 256, 0, stream>>>(A2bh, perm3, Agh, KP3, KP2P, 0);
  grows_k<<<((size_t)KP3 * (KP2P / 8) + 255) / 256, 256, 0, stream>>>(A2bl, perm3, Agl, KP3, KP2P, 0);
  grows_k<<<((size_t)KP3 * (KP2P / 8) + 255) / 256, 256, 0, stream>>>(A2tbh, perm3, Bgh, KP3, KP2P, 0);
  grows_k<<<((size_t)KP3 * (KP2P / 8) + 255) / 256, 256, 0, stream>>>(A2tbl, perm3, Bgl, KP3, KP2P, 1);
  mg(128, Agh, Agh, Agl, Bgh, Bgl, Bgh, 3, Cpart, KP3, KP3, KP2P, 16, 64);
  aug_epi_k<<<KP3, 256, 0, stream>>>(Cpart, 16, KP3 * KP3, KP3, KP3P, A3, A3bh, A3bl, dis3);

  // ---- conv 3 ----
  ghilo_k<<<((size_t)KP3 * HIDF + 255) / 256, 256, 0, stream>>>(x2, perm3, sv, bfAh, bfAl, KP3);
  wgemm(W3, HIDF, HIDF, KP3, 64, 4, 64);
  prop(A3bh, A3bl, 2, KP3, KP3P, 64, 8, 64, dis3, b3, x3, 1);

  // ---- up path ----
  unpool_hilo_k<<<(KP2 * HIDF + 255) / 256, 256, 0, stream>>>(x2, x3, pos3, bfAh, bfAl, KP2);
  wgemm(U0, HIDF, HIDF, KP2, 64, 4, 64);
  prop(A2bh, A2bl, 2, KP2, KP2P, 128, 16, 64, dis2, c0, hb, 1);

  unpool_hilo_k<<<(KP1 * HIDF + 255) / 256, 256, 0, stream>>>(x1, hb, pos2, bfAh, bfAl, KP1);
  wgemm(U1, HIDF, HIDF, KP1, 64, 4, 64);
  prop(A1bf, nullptr, 1, KP1, KP1P, 128, 8, 256, dis1, c1, hb, 1);

  unpool_hilo_k<<<(N0 * HIDF + 255) / 256, 256, 0, stream>>>(x0, hb, pos1, bfAh, bfAl, N0);
  wgemm(U2, HIDF, OUTC, N0, 64, 4, 64);
  spmm_sc_k<<<N0, OUTC, 0, stream>>>(st_d, bk_d, xw, dis0, zb, OUTC);
  conv_epi_k<<<(N0 * OUTC + 255) / 256, 256, 0, stream>>>(zb, 1, 0, xw, dis0, c2, xfin, N0, OUTC, 0);

  // ---- log_softmax ----
  log_softmax_k<<<N0, 64, 0, stream>>>(xfin, (float*)d_out, OUTC);
}

// Round 6
// 471.820 us; speedup vs baseline: 7.8162x; 1.2265x over previous
//
#include <hip/hip_runtime.h>
#include <math.h>
#include <stdint.h>

#define N0   3000
#define NE   96000
#define INC  512
#define HIDF 256
#define OUTC 64
#define KP1  2000
#define KP2  1000
#define KP3  500
#define KP1P 2048
#define KP2P 1024
#define KP3P 512

typedef __bf16 bf16x8 __attribute__((ext_vector_type(8)));
typedef float f32x4 __attribute__((ext_vector_type(4)));

// global_load_lds: per-lane global src, wave-uniform LDS base (HW adds lane*16)
#define GLDS16(gp, lp)                                                   \
  __builtin_amdgcn_global_load_lds(                                      \
      (__attribute__((address_space(1))) void*)(gp),                     \
      (__attribute__((address_space(3))) void*)(lp), 16, 0, 0)

// ---------------- CSR build (in-edges by dst) ----------------
static __global__ void count_k(const int* __restrict__ ei, int* __restrict__ cd) {
  int e = blockIdx.x * blockDim.x + threadIdx.x;
  if (e < NE) atomicAdd(&cd[ei[NE + e]], 1);
}

static __global__ __launch_bounds__(1024) void scan_excl_k(const int* __restrict__ cnt,
                                                           int* __restrict__ start, int n) {
  __shared__ int s[4096];
  int tid = threadIdx.x;
  for (int i = tid; i < 4096; i += blockDim.x) s[i] = (i < n) ? cnt[i] : 0;
  __syncthreads();
  for (int d = 1; d < 4096; d <<= 1) {
    int v[4]; int r = 0;
    for (int i = tid; i < 4096; i += blockDim.x, ++r) v[r] = (i >= d) ? s[i - d] : 0;
    __syncthreads();
    r = 0;
    for (int i = tid; i < 4096; i += blockDim.x, ++r) s[i] += v[r];
    __syncthreads();
  }
  for (int i = tid; i < n; i += blockDim.x) start[i] = (i == 0) ? 0 : s[i - 1];
  if (tid == 0) start[n] = s[n - 1];
}

static __global__ void scatter_k(const int* __restrict__ ei, const int* __restrict__ sd,
                                 int* __restrict__ fd, int* __restrict__ bd) {
  int e = blockIdx.x * blockDim.x + threadIdx.x;
  if (e < NE) {
    int d = ei[NE + e];
    bd[sd[d] + atomicAdd(&fd[d], 1)] = ei[e];
  }
}

static __global__ void dis0_k(const int* __restrict__ cd, float* __restrict__ dis0) {
  int i = blockIdx.x * blockDim.x + threadIdx.x;
  if (i < N0) dis0[i] = rsqrtf((float)cd[i] + 2.0f);
}

// ---------------- masked augment level 0 ----------------
static __global__ __launch_bounds__(256) void augA_masked_k(
    const int* __restrict__ st, const int* __restrict__ bk,
    const int* __restrict__ perm, const int* __restrict__ pos,
    float* __restrict__ A1, __bf16* __restrict__ A1bf, float* __restrict__ dis1) {
  __shared__ float row[KP1];
  __shared__ float sh[4];
  int tid = threadIdx.x, lane = tid & 63, wave = tid >> 6;
  int r = blockIdx.x;
  int vi = perm[r];
  for (int c = tid; c < KP1; c += 256) row[c] = 0.f;
  __syncthreads();
  int b = st[vi], e = st[vi + 1];
  for (int t = b + wave; t < e; t += 4) {
    int k = bk[t];
    int jb = st[k], je = st[k + 1];
    for (int u = jb + lane; u < je; u += 64) {
      int p = pos[bk[u]];
      if (p >= 0) atomicAdd(&row[p], 1.0f);
    }
  }
  if (wave == 0)
    for (int t = b + lane; t < e; t += 64) {
      int p = pos[bk[t]];
      if (p >= 0) atomicAdd(&row[p], 2.0f);
    }
  __syncthreads();
  if (tid == 0) row[r] = 0.f;
  __syncthreads();
  float s = 0.f;
  for (int c = tid; c < KP1P; c += 256) {
    float v = (c < KP1) ? row[c] : 0.f;
    if (c < KP1) A1[(size_t)r * KP1 + c] = v;
    A1bf[(size_t)r * KP1P + c] = (__bf16)v;  // small counts: exact in bf16
    s += v;
  }
#pragma unroll
  for (int o = 32; o > 0; o >>= 1) s += __shfl_down(s, o, 64);
  if (lane == 0) sh[wave] = s;
  __syncthreads();
  if (tid == 0) dis1[r] = rsqrtf(sh[0] + sh[1] + sh[2] + sh[3] + 2.0f);
}

// ---------------- SpMM with fused source scaling ----------------
static __global__ void spmm_sc_k(const int* __restrict__ start, const int* __restrict__ idx,
                                 const float* __restrict__ xw, const float* __restrict__ dis,
                                 float* __restrict__ out, int F) {
  int row = blockIdx.x;
  int b = start[row], e = start[row + 1];
  int f = threadIdx.x;  // blockDim == F
  __shared__ int nb[256];
  __shared__ float nd[256];
  float acc = 0.f;
  for (int t0 = b; t0 < e; t0 += blockDim.x) {
    int m = min((int)blockDim.x, e - t0);
    __syncthreads();
    if (f < m) { int s = idx[t0 + f]; nb[f] = s; nd[f] = dis[s]; }
    __syncthreads();
    for (int t = 0; t < m; ++t) acc += xw[(size_t)nb[t] * F + f] * nd[t];
  }
  out[(size_t)row * F + f] = acc;
}

// ---------------- converters ----------------
static __global__ void conv_hilo_k(const float* __restrict__ in, int R, int C, int Cp,
                                   __bf16* __restrict__ oh, __bf16* __restrict__ ol) {
  int idx = blockIdx.x * blockDim.x + threadIdx.x;
  if (idx < R * Cp) {
    int r = idx / Cp, c = idx - r * Cp;
    float v = (c < C) ? in[(size_t)r * C + c] : 0.f;
    __bf16 h = (__bf16)v;
    oh[idx] = h;
    if (ol) ol[idx] = (__bf16)(v - (float)h);
  }
}

// transpose+convert (weights): f32 in[R][C] -> bf16 out[C][Rp] hi/lo
static __global__ __launch_bounds__(256) void tconv_k(const float* __restrict__ in, int R, int C, int Rp,
                                                      __bf16* __restrict__ oh, __bf16* __restrict__ ol) {
  __shared__ float t[32][33];
  int r0 = blockIdx.x * 32, c0 = blockIdx.y * 32;
  int lr = threadIdx.x >> 5, lc = threadIdx.x & 31;
#pragma unroll
  for (int i = 0; i < 4; ++i) {
    int r = r0 + lr + i * 8, c = c0 + lc;
    t[lr + i * 8][lc] = (r < R && c < C) ? in[(size_t)r * C + c] : 0.f;
  }
  __syncthreads();
#pragma unroll
  for (int i = 0; i < 4; ++i) {
    int c = c0 + lr + i * 8, r = r0 + lc;
    if (c < C) {
      float v = t[lc][lr + i * 8];
      __bf16 h = (__bf16)v;
      oh[(size_t)c * Rp + r] = h;
      if (ol) ol[(size_t)c * Rp + r] = (__bf16)(v - (float)h);
    }
  }
}

// fused: reduce split-K partials -> xw f32 [R][C], and transposed dis-scaled hi/lo [C][Rp]
static __global__ __launch_bounds__(256) void redtconv_k(const float* __restrict__ Cp, int ks, int mn,
                                                         int R, int C, int Rp,
                                                         __bf16* __restrict__ oh, __bf16* __restrict__ ol,
                                                         const float* __restrict__ disv,
                                                         float* __restrict__ xw_out) {
  __shared__ float t[32][33];
  int r0 = blockIdx.x * 32, c0 = blockIdx.y * 32;
  int lr = threadIdx.x >> 5, lc = threadIdx.x & 31;
#pragma unroll
  for (int i = 0; i < 4; ++i) {
    int r = r0 + lr + i * 8, c = c0 + lc;
    float v = 0.f;
    if (r < R && c < C) {
      size_t idx = (size_t)r * C + c;
      for (int z = 0; z < ks; ++z) v += Cp[(size_t)z * mn + idx];
      xw_out[idx] = v;
    }
    t[lr + i * 8][lc] = v;
  }
  __syncthreads();
#pragma unroll
  for (int i = 0; i < 4; ++i) {
    int c = c0 + lr + i * 8, r = r0 + lc;
    if (c < C) {
      float v = t[lc][lr + i * 8];
      if (r < R) v *= disv[r];
      __bf16 h = (__bf16)v;
      oh[(size_t)c * Rp + r] = h;
      ol[(size_t)c * Rp + r] = (__bf16)(v - (float)h);
    }
  }
}

// gather rows for 1-seg pair (level-2 aug); +2I exact on src2 (small values)
static __global__ void grows2_k(const __bf16* __restrict__ s1, const __bf16* __restrict__ s2,
                                const int* __restrict__ perm, __bf16* __restrict__ d1,
                                __bf16* __restrict__ d2, int k, int L) {
  int idx = blockIdx.x * blockDim.x + threadIdx.x;
  int nv = L >> 3;
  if (idx < k * nv) {
    int r = idx / nv, c8 = (idx - r * nv) << 3;
    int sr = perm[r];
    bf16x8 v1 = *(const bf16x8*)(s1 + (size_t)sr * L + c8);
    bf16x8 v2 = *(const bf16x8*)(s2 + (size_t)sr * L + c8);
    if (sr >= c8 && sr < c8 + 8) v2[sr - c8] = (__bf16)((float)v2[sr - c8] + 2.0f);
    *(bf16x8*)(d1 + (size_t)r * L + c8) = v1;
    *(bf16x8*)(d2 + (size_t)r * L + c8) = v2;
  }
}

// gather rows for hi/lo pairs (level-3 aug); +2I on B with exact re-split
static __global__ void grows4_k(const __bf16* __restrict__ ah, const __bf16* __restrict__ al,
                                const __bf16* __restrict__ bh, const __bf16* __restrict__ bl,
                                const int* __restrict__ perm,
                                __bf16* __restrict__ dah, __bf16* __restrict__ dal,
                                __bf16* __restrict__ dbh, __bf16* __restrict__ dbl,
                                int k, int L) {
  int idx = blockIdx.x * blockDim.x + threadIdx.x;
  int nv = L >> 3;
  if (idx < k * nv) {
    int r = idx / nv, c8 = (idx - r * nv) << 3;
    int sr = perm[r];
    bf16x8 vah = *(const bf16x8*)(ah + (size_t)sr * L + c8);
    bf16x8 val = *(const bf16x8*)(al + (size_t)sr * L + c8);
    bf16x8 vbh = *(const bf16x8*)(bh + (size_t)sr * L + c8);
    bf16x8 vbl = *(const bf16x8*)(bl + (size_t)sr * L + c8);
    if (sr >= c8 && sr < c8 + 8) {
      int e = sr - c8;
      float v = (float)vbh[e] + (float)vbl[e] + 2.0f;
      __bf16 h = (__bf16)v;
      vbh[e] = h;
      vbl[e] = (__bf16)(v - (float)h);
    }
    *(bf16x8*)(dah + (size_t)r * L + c8) = vah;
    *(bf16x8*)(dal + (size_t)r * L + c8) = val;
    *(bf16x8*)(dbh + (size_t)r * L + c8) = vbh;
    *(bf16x8*)(dbl + (size_t)r * L + c8) = vbl;
  }
}

static __global__ void ghilo_k(const float* __restrict__ src, const int* __restrict__ perm,
                               const float* __restrict__ sv, __bf16* __restrict__ oh,
                               __bf16* __restrict__ ol, int k) {
  int idx = blockIdx.x * blockDim.x + threadIdx.x;
  if (idx < k * HIDF) {
    int r = idx >> 8;
    float v = src[(size_t)perm[r] * HIDF + (idx & 255)] * sv[r];
    __bf16 h = (__bf16)v;
    oh[idx] = h;
    ol[idx] = (__bf16)(v - (float)h);
  }
}

// ---------------- MFMA GEMM: split-K partials, global_load_lds, double-buffered ----------------
// A segs [M][Kp] bf16 row-major, B segs [N][Kp] row-major (B^T). Kp % kchunk == 0, kchunk % 64 == 0.
// LDS linear row-major [row][64]; XOR swizzle applied on the GLOBAL source col and on ds_read.
template <int BM, int BN>
static __global__ __launch_bounds__(256) void mgemm_k(
    const __bf16* __restrict__ A0, const __bf16* __restrict__ A1g, const __bf16* __restrict__ A2g,
    const __bf16* __restrict__ B0, const __bf16* __restrict__ B1g, const __bf16* __restrict__ B2g,
    int nseg, float* __restrict__ Cp, int M, int N, int Kp, int kchunk) {
  constexpr int FM = BM / 32, FN = BN / 32;
  __shared__ __bf16 As[2][BM * 64];
  __shared__ __bf16 Bs[2][BN * 64];
  int tid = threadIdx.x;
  int lane = tid & 63, wave = tid >> 6;
  int wx = wave & 1, wy = wave >> 1;
  int l15 = lane & 15, l4 = lane >> 4;
  int brow = blockIdx.y * BM, bcol = blockIdx.x * BN;
  int wrow = wy * (BM / 2), wcol = wx * (BN / 2);
  int srow = lane >> 3, slot = lane & 7;
  int k_beg = blockIdx.z * kchunk;
  int ksteps = kchunk >> 6;
  int nsteps = nseg * ksteps;
  const __bf16* segA[3] = {A0, A1g, A2g};
  const __bf16* segB[3] = {B0, B1g, B2g};

  auto stage = [&](int buf, int t) {
    int seg = t / ksteps;
    int k0 = k_beg + ((t - seg * ksteps) << 6);
    const __bf16* Ag = segA[seg];
    const __bf16* Bg = segB[seg];
#pragma unroll
    for (int i = 0; i < BM / 32; ++i) {
      int rl = (i * 4 + wave) * 8 + srow;
      int gr = brow + rl;
      if (gr >= M) gr = M - 1;
      int col = k0 + ((slot ^ (rl & 7)) << 3);
      GLDS16(Ag + (size_t)gr * Kp + col, &As[buf][(i * 4 + wave) * 8 * 64]);
    }
#pragma unroll
    for (int i = 0; i < BN / 32; ++i) {
      int rl = (i * 4 + wave) * 8 + srow;
      int gc = bcol + rl;
      if (gc >= N) gc = N - 1;
      int col = k0 + ((slot ^ (rl & 7)) << 3);
      GLDS16(Bg + (size_t)gc * Kp + col, &Bs[buf][(i * 4 + wave) * 8 * 64]);
    }
  };

  f32x4 acc[FM][FN] = {};
  stage(0, 0);
  __syncthreads();
  int cur = 0;
  for (int t = 0; t < nsteps; ++t) {
    if (t + 1 < nsteps) stage(cur ^ 1, t + 1);
#pragma unroll
    for (int sub = 0; sub < 2; ++sub) {
      bf16x8 af[FM], bfv[FN];
#pragma unroll
      for (int i = 0; i < FM; ++i) {
        int r = wrow + i * 16 + l15;
        af[i] = *(const bf16x8*)(&As[cur][r * 64 + (((sub * 4 + l4) ^ (r & 7)) << 3)]);
      }
#pragma unroll
      for (int j = 0; j < FN; ++j) {
        int r = wcol + j * 16 + l15;
        bfv[j] = *(const bf16x8*)(&Bs[cur][r * 64 + (((sub * 4 + l4) ^ (r & 7)) << 3)]);
      }
#pragma unroll
      for (int i = 0; i < FM; ++i)
#pragma unroll
        for (int j = 0; j < FN; ++j)
          acc[i][j] = __builtin_amdgcn_mfma_f32_16x16x32_bf16(af[i], bfv[j], acc[i][j], 0, 0, 0);
    }
    __syncthreads();
    cur ^= 1;
  }
  size_t zoff = (size_t)blockIdx.z * M * N;
#pragma unroll
  for (int i = 0; i < FM; ++i)
#pragma unroll
    for (int j = 0; j < FN; ++j) {
      int col = bcol + wcol + j * 16 + l15;
      if (col < N) {
#pragma unroll
        for (int q = 0; q < 4; ++q) {
          int row = brow + wrow + i * 16 + l4 * 4 + q;
          if (row < M) Cp[zoff + (size_t)row * N + col] = acc[i][j][q];
        }
      }
    }
}

// ---------------- reductions / epilogues ----------------
static __global__ void reduce_k(const float* __restrict__ p, int ks, int mn, float* __restrict__ out) {
  int idx = blockIdx.x * blockDim.x + threadIdx.x;
  if (idx < mn) {
    float s = 0.f;
    for (int z = 0; z < ks; ++z) s += p[(size_t)z * mn + idx];
    out[idx] = s;
  }
}

static __global__ void conv_epi_k(const float* __restrict__ zp, int ks, int mn,
                                  const float* __restrict__ xw, const float* __restrict__ dis,
                                  const float* __restrict__ b, float* __restrict__ out,
                                  int n, int f, int relu) {
  int idx = blockIdx.x * blockDim.x + threadIdx.x;
  if (idx < n * f) {
    float zv = 0.f;
    for (int z = 0; z < ks; ++z) zv += zp[(size_t)z * mn + idx];
    int i = idx / f, j = idx - i * f;
    float di = dis[i];
    float v = di * zv + 2.0f * di * di * xw[idx] + b[j];
    if (relu) v = fmaxf(v, 0.0f);
    out[idx] = v;
  }
}

// split-K reduce + zero diag + rowsum->dis + f32 + hi/lo bf16 (padded)
static __global__ __launch_bounds__(256) void aug_epi_k(const float* __restrict__ Cp, int ks, int mn,
                                                        int n, int Kpad, float* __restrict__ Af,
                                                        __bf16* __restrict__ bh, __bf16* __restrict__ bl,
                                                        float* __restrict__ dis) {
  __shared__ float sh[4];
  int r = blockIdx.x;
  int tid = threadIdx.x, lane = tid & 63, wave = tid >> 6;
  float ssum = 0.f;
  for (int c = tid; c < Kpad; c += 256) {
    float v = 0.f;
    if (c < n && c != r)
      for (int z = 0; z < ks; ++z) v += Cp[(size_t)z * mn + (size_t)r * n + c];
    if (c < n) Af[(size_t)r * n + c] = v;
    __bf16 h = (__bf16)v;
    bh[(size_t)r * Kpad + c] = h;
    bl[(size_t)r * Kpad + c] = (__bf16)(v - (float)h);
    ssum += v;
  }
#pragma unroll
  for (int o = 32; o > 0; o >>= 1) ssum += __shfl_down(ssum, o, 64);
  if (lane == 0) sh[wave] = ssum;
  __syncthreads();
  if (tid == 0) dis[r] = rsqrtf(sh[0] + sh[1] + sh[2] + sh[3] + 2.0f);
}

// ---------------- pooling ----------------
// score with fused ||w||: each block computes both reductions
static __global__ void score_k(const float* __restrict__ x, const float* __restrict__ w,
                               float* __restrict__ sc, int f) {
  int row = blockIdx.x;
  float s = 0.f, q = 0.f;
  for (int j = threadIdx.x; j < f; j += blockDim.x) {
    float wv = w[j];
    q += wv * wv;
    s += x[(size_t)row * f + j] * wv;
  }
  __shared__ float sh[8], sh2[8];
  int lane = threadIdx.x & 63, wid = threadIdx.x >> 6;
#pragma unroll
  for (int o = 32; o > 0; o >>= 1) { s += __shfl_down(s, o, 64); q += __shfl_down(q, o, 64); }
  if (lane == 0) { sh[wid] = s; sh2[wid] = q; }
  __syncthreads();
  if (threadIdx.x == 0) {
    float t = 0.f, t2 = 0.f;
    int nw = (blockDim.x + 63) >> 6;
    for (int w2 = 0; w2 < nw; ++w2) { t += sh[w2]; t2 += sh2[w2]; }
    sc[row] = tanhf(t / sqrtf(t2));
  }
}

// exact jax.lax.top_k: wave-per-candidate; also writes pos[] (no memset needed)
static __global__ __launch_bounds__(256) void topk_rank_k(const float* __restrict__ sc, int n, int k,
                                                          int* __restrict__ perm, float* __restrict__ sv,
                                                          int* __restrict__ pos) {
  __shared__ float s[N0 + 8];
  int tid = threadIdx.x, lane = tid & 63, wave = tid >> 6;
  for (int i = tid; i < n; i += 256) s[i] = sc[i];
  __syncthreads();
  int i = blockIdx.x * 4 + wave;
  if (i < n) {
    float si = s[i];
    int rank = 0;
    for (int j = lane; j < n; j += 64) {
      float sj = s[j];
      rank += (sj > si) || (sj == si && j < i);
    }
#pragma unroll
    for (int o = 32; o > 0; o >>= 1) rank += __shfl_down(rank, o, 64);
    if (lane == 0) {
      pos[i] = (rank < k) ? rank : -1;
      if (rank < k) { perm[rank] = i; sv[rank] = si; }
    }
  }
}

static __global__ void unpool_hilo_k(const float* __restrict__ base, const float* __restrict__ up,
                                     const int* __restrict__ pos, __bf16* __restrict__ oh,
                                     __bf16* __restrict__ ol, int n) {
  int idx = blockIdx.x * blockDim.x + threadIdx.x;
  if (idx < n * HIDF) {
    int i = idx >> 8;
    int p = pos[i];
    float v = base[idx] + (p >= 0 ? up[(size_t)p * HIDF + (idx & 255)] : 0.f);
    __bf16 h = (__bf16)v;
    oh[idx] = h;
    ol[idx] = (__bf16)(v - (float)h);
  }
}

static __global__ void log_softmax_k(const float* __restrict__ h, float* __restrict__ out, int f) {
  int row = blockIdx.x;
  int j = threadIdx.x;  // blockDim = 64 == f
  float vv = h[row * f + j];
  float m = vv;
#pragma unroll
  for (int o = 32; o > 0; o >>= 1) m = fmaxf(m, __shfl_xor(m, o, 64));
  float e = expf(vv - m), s = e;
#pragma unroll
  for (int o = 32; o > 0; o >>= 1) s += __shfl_xor(s, o, 64);
  out[row * f + j] = vv - m - logf(s);
}

// ---------------- host ----------------
extern "C" void kernel_launch(void* const* d_in, const int* in_sizes, int n_in,
                              void* d_out, int out_size, void* d_ws, size_t ws_size,
                              hipStream_t stream) {
  const float* x  = (const float*)d_in[0];
  const int* ei   = (const int*)d_in[1];
  const float* W0 = (const float*)d_in[2];
  const float* b0 = (const float*)d_in[3];
  const float* W1 = (const float*)d_in[4];
  const float* b1 = (const float*)d_in[5];
  const float* W2 = (const float*)d_in[6];
  const float* b2 = (const float*)d_in[7];
  const float* W3 = (const float*)d_in[8];
  const float* b3 = (const float*)d_in[9];
  const float* p1 = (const float*)d_in[10];
  const float* p2 = (const float*)d_in[11];
  const float* p3 = (const float*)d_in[12];
  const float* U0 = (const float*)d_in[13];
  const float* c0 = (const float*)d_in[14];
  const float* U1 = (const float*)d_in[15];
  const float* c1 = (const float*)d_in[16];
  const float* U2 = (const float*)d_in[17];
  const float* c2 = (const float*)d_in[18];
  (void)in_sizes; (void)n_in; (void)out_size; (void)ws_size;

  char* basep = (char*)d_ws;
  size_t off = 0;
  auto alloc = [&](size_t bytes) {
    void* p = basep + off;
    off += (bytes + 255) & ~(size_t)255;
    return p;
  };

  // fp32 mats
  float* A1  = (float*)alloc((size_t)KP1 * KP1 * 4);
  float* A2  = (float*)alloc((size_t)KP2 * KP2 * 4);
  float* A3  = (float*)alloc((size_t)KP3 * KP3 * 4);
  float* xw  = (float*)alloc((size_t)N0 * HIDF * 4);
  float* zb  = (float*)alloc((size_t)N0 * HIDF * 4);
  float* x0  = (float*)alloc((size_t)N0 * HIDF * 4);
  float* x1  = (float*)alloc((size_t)KP1 * HIDF * 4);
  float* x2  = (float*)alloc((size_t)KP2 * HIDF * 4);
  float* x3  = (float*)alloc((size_t)KP3 * HIDF * 4);
  float* hb  = (float*)alloc((size_t)N0 * HIDF * 4);
  float* xfin = (float*)alloc((size_t)N0 * OUTC * 4);
  float* Cpart = (float*)alloc((size_t)36 * 1024 * 1024);  // split-K partials (max 32.8 MB)
  // bf16 scratch
  __bf16* bfAh = (__bf16*)alloc((size_t)N0 * INC * 2);
  __bf16* bfAl = (__bf16*)alloc((size_t)N0 * INC * 2);
  __bf16* bfBh = (__bf16*)alloc((size_t)HIDF * KP1P * 2);
  __bf16* bfBl = (__bf16*)alloc((size_t)HIDF * KP1P * 2);
  __bf16* A1bf  = (__bf16*)alloc((size_t)KP1 * KP1P * 2);
  __bf16* A1tbf = (__bf16*)alloc((size_t)KP1 * KP1P * 2);
  __bf16* Ag    = (__bf16*)alloc((size_t)KP2 * KP1P * 2);
  __bf16* Bg    = (__bf16*)alloc((size_t)KP2 * KP1P * 2);
  __bf16* A2bh  = (__bf16*)alloc((size_t)KP2 * KP2P * 2);
  __bf16* A2bl  = (__bf16*)alloc((size_t)KP2 * KP2P * 2);
  __bf16* A2tbh = (__bf16*)alloc((size_t)KP2 * KP2P * 2);
  __bf16* A2tbl = (__bf16*)alloc((size_t)KP2 * KP2P * 2);
  __bf16* Agh   = (__bf16*)alloc((size_t)KP3 * KP2P * 2);
  __bf16* Agl   = (__bf16*)alloc((size_t)KP3 * KP2P * 2);
  __bf16* Bgh   = (__bf16*)alloc((size_t)KP3 * KP2P * 2);
  __bf16* Bgl   = (__bf16*)alloc((size_t)KP3 * KP2P * 2);
  __bf16* A3bh  = (__bf16*)alloc((size_t)KP3 * KP3P * 2);
  __bf16* A3bl  = (__bf16*)alloc((size_t)KP3 * KP3P * 2);
  // small
  float* sc   = (float*)alloc(N0 * 4);
  float* sv   = (float*)alloc(KP1 * 4);
  int* perm1  = (int*)alloc(KP1 * 4);
  int* perm2  = (int*)alloc(KP2 * 4);
  int* perm3  = (int*)alloc(KP3 * 4);
  int* pos1   = (int*)alloc(N0 * 4);
  int* pos2   = (int*)alloc(KP1 * 4);
  int* pos3   = (int*)alloc(KP2 * 4);
  float* dis0 = (float*)alloc(N0 * 4);
  float* dis1 = (float*)alloc(KP1 * 4);
  float* dis2 = (float*)alloc(KP2 * 4);
  float* dis3 = (float*)alloc(KP3 * 4);
  int* cnt_d  = (int*)alloc(N0 * 4);
  int* st_d   = (int*)alloc((N0 + 4) * 4);
  int* fl_d   = (int*)alloc(N0 * 4);
  int* bk_d   = (int*)alloc(NE * 4);

  auto mg = [&](int bm, const __bf16* a0, const __bf16* a1, const __bf16* a2,
                const __bf16* bb0, const __bf16* bb1, const __bf16* bb2,
                int nseg, float* Cp, int M, int N, int Kp, int ks, int kchunk) {
    if (bm == 128) {
      dim3 g((N + 127) / 128, (M + 127) / 128, ks);
      mgemm_k<128, 128><<<g, 256, 0, stream>>>(a0, a1, a2, bb0, bb1, bb2, nseg, Cp, M, N, Kp, kchunk);
    } else {
      dim3 g((N + 63) / 64, (M + 63) / 64, ks);
      mgemm_k<64, 64><<<g, 256, 0, stream>>>(a0, a1, a2, bb0, bb1, bb2, nseg, Cp, M, N, Kp, kchunk);
    }
  };

  // weight GEMM into Cpart (bfAh/bfAl hold hi/lo A [n][Kp])
  auto wgemm = [&](const float* W, int fin, int fout, int n, int bm, int ks, int kchunk) {
    int Kp = (fin + 63) & ~63;
    dim3 tg(Kp / 32, (fout + 31) / 32);
    tconv_k<<<tg, 256, 0, stream>>>(W, fin, fout, Kp, bfBh, bfBl);
    mg(bm, bfAh, bfAh, bfAl, bfBh, bfBl, bfBh, 3, Cpart, n, fout, Kp, ks, kchunk);
  };

  // dense conv tail: redtconv (reduce+xw+B-op) -> prop mgemm -> epi
  auto prop = [&](int ksw, const __bf16* Abh, const __bf16* Abl, int asegs, int n, int Kp, int bm,
                  int ks, int kchunk, const float* disv, const float* bias, float* outx, int relu) {
    dim3 tg(Kp / 32, HIDF / 32);
    redtconv_k<<<tg, 256, 0, stream>>>(Cpart, ksw, n * HIDF, n, HIDF, Kp, bfBh, bfBl, disv, xw);
    if (asegs == 1) mg(bm, Abh, Abh, nullptr, bfBh, bfBl, nullptr, 2, Cpart, n, HIDF, Kp, ks, kchunk);
    else            mg(bm, Abh, Abh, Abl, bfBh, bfBl, bfBh, 3, Cpart, n, HIDF, Kp, ks, kchunk);
    conv_epi_k<<<(n * HIDF + 255) / 256, 256, 0, stream>>>(Cpart, ks, n * HIDF, xw, disv, bias,
                                                           outx, n, HIDF, relu);
  };

  auto pool = [&](const float* xfeat, int n, const float* p, int k, int* perm, int* pos) {
    score_k<<<n, 256, 0, stream>>>(xfeat, p, sc, HIDF);
    topk_rank_k<<<(n + 3) / 4, 256, 0, stream>>>(sc, n, k, perm, sv, pos);
  };

  // ---- CSR build ----
  hipMemsetAsync(cnt_d, 0, N0 * 4, stream);
  hipMemsetAsync(fl_d, 0, N0 * 4, stream);
  count_k<<<(NE + 255) / 256, 256, 0, stream>>>(ei, cnt_d);
  scan_excl_k<<<1, 1024, 0, stream>>>(cnt_d, st_d, N0);
  scatter_k<<<(NE + 255) / 256, 256, 0, stream>>>(ei, st_d, fl_d, bk_d);
  dis0_k<<<(N0 + 255) / 256, 256, 0, stream>>>(cnt_d, dis0);

  // ---- down conv 0 (sparse propagation) ----
  conv_hilo_k<<<((size_t)N0 * INC + 255) / 256, 256, 0, stream>>>(x, N0, INC, INC, bfAh, bfAl);
  wgemm(W0, INC, HIDF, N0, 64, 4, 128);
  reduce_k<<<(N0 * HIDF + 255) / 256, 256, 0, stream>>>(Cpart, 4, N0 * HIDF, xw);
  spmm_sc_k<<<N0, HIDF, 0, stream>>>(st_d, bk_d, xw, dis0, zb, HIDF);
  conv_epi_k<<<(N0 * HIDF + 255) / 256, 256, 0, stream>>>(zb, 1, 0, xw, dis0, b0, x0, N0, HIDF, 1);

  // ---- pool 1 + masked augment(A) ----
  pool(x0, N0, p1, KP1, perm1, pos1);
  augA_masked_k<<<KP1, 256, 0, stream>>>(st_d, bk_d, perm1, pos1, A1, A1bf, dis1);

  // ---- conv 1 ----
  ghilo_k<<<((size_t)KP1 * HIDF + 255) / 256, 256, 0, stream>>>(x0, perm1, sv, bfAh, bfAl, KP1);
  wgemm(W1, HIDF, HIDF, KP1, 64, 4, 64);
  prop(4, A1bf, nullptr, 1, KP1, KP1P, 128, 16, 128, dis1, b1, x1, 1);

  // ---- pool 2 + masked augment(A1): A2 = A1[perm2,:] @ (A1+2I)[:,perm2] ----
  pool(x1, KP1, p2, KP2, perm2, pos2);
  {
    dim3 tg(KP1P / 32, (KP1 + 31) / 32);
    tconv_k<<<tg, 256, 0, stream>>>(A1, KP1, KP1, KP1P, A1tbf, nullptr);
  }
  grows2_k<<<((size_t)KP2 * (KP1P / 8) + 255) / 256, 256, 0, stream>>>(A1bf, A1tbf, perm2, Ag, Bg,
                                                                       KP2, KP1P);
  mg(128, Ag, nullptr, nullptr, Bg, nullptr, nullptr, 1, Cpart, KP2, KP2, KP1P, 8, 256);
  aug_epi_k<<<KP2, 256, 0, stream>>>(Cpart, 8, KP2 * KP2, KP2, KP2P, A2, A2bh, A2bl, dis2);

  // ---- conv 2 ----
  ghilo_k<<<((size_t)KP2 * HIDF + 255) / 256, 256, 0, stream>>>(x1, perm2, sv, bfAh, bfAl, KP2);
  wgemm(W2, HIDF, HIDF, KP2, 64, 4, 64);
  prop(4, A2bh, A2bl, 2, KP2, KP2P, 64, 8, 128, dis2, b2, x2, 1);

  // ---- pool 3 + masked augment(A2), hi/lo 3-seg ----
  pool(x2, KP2, p3, KP3, perm3, pos3);
  {
    dim3 tg(KP2P / 32, (KP2 + 31) / 32);
    tconv_k<<<tg, 256, 0, stream>>>(A2, KP2, KP2, KP2P, A2tbh, A2tbl);
  }
  grows4_k<<<((size_t)KP3 * (KP2P / 8) + 255) / 256, 256, 0, stream>>>(
      A2bh, A2bl, A2tbh, A2tbl, perm3, Agh, Agl, Bgh, Bgl, KP3, KP2P);
  mg(64, Agh, Agh, Agl, Bgh, Bgl, Bgh, 3, Cpart, KP3, KP3, KP2P, 8, 128);
  aug_epi_k<<<KP3, 256, 0, stream>>>(Cpart, 8, KP3 * KP3, KP3, KP3P, A3, A3bh, A3bl, dis3);

  // ---- conv 3 ----
  ghilo_k<<<((size_t)KP3 * HIDF + 255) / 256, 256, 0, stream>>>(x2, perm3, sv, bfAh, bfAl, KP3);
  wgemm(W3, HIDF, HIDF, KP3, 64, 4, 64);
  prop(4, A3bh, A3bl, 2, KP3, KP3P, 64, 8, 64, dis3, b3, x3, 1);

  // ---- up path ----
  unpool_hilo_k<<<(KP2 * HIDF + 255) / 256, 256, 0, stream>>>(x2, x3, pos3, bfAh, bfAl, KP2);
  wgemm(U0, HIDF, HIDF, KP2, 64, 4, 64);
  prop(4, A2bh, A2bl, 2, KP2, KP2P, 64, 8, 128, dis2, c0, hb, 1);

  unpool_hilo_k<<<(KP1 * HIDF + 255) / 256, 256, 0, stream>>>(x1, hb, pos2, bfAh, bfAl, KP1);
  wgemm(U1, HIDF, HIDF, KP1, 64, 4, 64);
  prop(4, A1bf, nullptr, 1, KP1, KP1P, 128, 16, 128, dis1, c1, hb, 1);

  unpool_hilo_k<<<(N0 * HIDF + 255) / 256, 256, 0, stream>>>(x0, hb, pos1, bfAh, bfAl, N0);
  wgemm(U2, HIDF, OUTC, N0, 64, 4, 64);
  reduce_k<<<(N0 * OUTC + 255) / 256, 256, 0, stream>>>(Cpart, 4, N0 * OUTC, xw);
  spmm_sc_k<<<N0, OUTC, 0, stream>>>(st_d, bk_d, xw, dis0, zb, OUTC);
  conv_epi_k<<<(N0 * OUTC + 255) / 256, 256, 0, stream>>>(zb, 1, 0, xw, dis0, c2, xfin, N0, OUTC, 0);

  // ---- log_softmax ----
  log_softmax_k<<<N0, 64, 0, stream>>>(xfin, (float*)d_out, OUTC);
}

// Round 7
// 450.106 us; speedup vs baseline: 8.1933x; 1.0482x over previous
//
#include <hip/hip_runtime.h>
#include <math.h>
#include <stdint.h>

#define N0   3000
#define NE   96000
#define INC  512
#define HIDF 256
#define OUTC 64
#define KP1  2000
#define KP2  1000
#define KP3  500
#define KP1P 2048
#define KP2P 1024
#define KP3P 512

typedef __bf16 bf16x8 __attribute__((ext_vector_type(8)));
typedef float f32x4 __attribute__((ext_vector_type(4)));

// global_load_lds: per-lane global src, wave-uniform LDS base (HW adds lane*16)
#define GLDS16(gp, lp)                                                   \
  __builtin_amdgcn_global_load_lds(                                      \
      (__attribute__((address_space(1))) void*)(gp),                     \
      (__attribute__((address_space(3))) void*)(lp), 16, 0, 0)

// ---------------- CSR build (in-edges by dst) ----------------
static __global__ void count_k(const int* __restrict__ ei, int* __restrict__ cd) {
  int e = blockIdx.x * blockDim.x + threadIdx.x;
  if (e < NE) atomicAdd(&cd[ei[NE + e]], 1);
}

// exclusive scan over counts + fused dis0 = rsqrt(cnt+2)
static __global__ __launch_bounds__(1024) void scan_excl_k(const int* __restrict__ cnt,
                                                           int* __restrict__ start, int n,
                                                           float* __restrict__ dis0) {
  __shared__ int s[4096];
  int tid = threadIdx.x;
  for (int i = tid; i < 4096; i += blockDim.x) s[i] = (i < n) ? cnt[i] : 0;
  __syncthreads();
  for (int d = 1; d < 4096; d <<= 1) {
    int v[4]; int r = 0;
    for (int i = tid; i < 4096; i += blockDim.x, ++r) v[r] = (i >= d) ? s[i - d] : 0;
    __syncthreads();
    r = 0;
    for (int i = tid; i < 4096; i += blockDim.x, ++r) s[i] += v[r];
    __syncthreads();
  }
  for (int i = tid; i < n; i += blockDim.x) {
    start[i] = (i == 0) ? 0 : s[i - 1];
    dis0[i] = rsqrtf((float)cnt[i] + 2.0f);
  }
  if (tid == 0) start[n] = s[n - 1];
}

static __global__ void scatter_k(const int* __restrict__ ei, const int* __restrict__ sd,
                                 int* __restrict__ fd, int* __restrict__ bd) {
  int e = blockIdx.x * blockDim.x + threadIdx.x;
  if (e < NE) {
    int d = ei[NE + e];
    bd[sd[d] + atomicAdd(&fd[d], 1)] = ei[e];
  }
}

// ---------------- masked augment level 0 (bf16 out only; counts exact) ----------------
static __global__ __launch_bounds__(256) void augA_masked_k(
    const int* __restrict__ st, const int* __restrict__ bk,
    const int* __restrict__ perm, const int* __restrict__ pos,
    __bf16* __restrict__ A1bf, float* __restrict__ dis1) {
  __shared__ float row[KP1];
  __shared__ float sh[4];
  int tid = threadIdx.x, lane = tid & 63, wave = tid >> 6;
  int r = blockIdx.x;
  int vi = perm[r];
  for (int c = tid; c < KP1; c += 256) row[c] = 0.f;
  __syncthreads();
  int b = st[vi], e = st[vi + 1];
  for (int t = b + wave; t < e; t += 4) {
    int k = bk[t];
    int jb = st[k], je = st[k + 1];
    for (int u = jb + lane; u < je; u += 64) {
      int p = pos[bk[u]];
      if (p >= 0) atomicAdd(&row[p], 1.0f);
    }
  }
  if (wave == 0)
    for (int t = b + lane; t < e; t += 64) {
      int p = pos[bk[t]];
      if (p >= 0) atomicAdd(&row[p], 2.0f);
    }
  __syncthreads();
  if (tid == 0) row[r] = 0.f;
  __syncthreads();
  float s = 0.f;
  for (int c = tid; c < KP1P; c += 256) {
    float v = (c < KP1) ? row[c] : 0.f;
    A1bf[(size_t)r * KP1P + c] = (__bf16)v;
    s += v;
  }
#pragma unroll
  for (int o = 32; o > 0; o >>= 1) s += __shfl_down(s, o, 64);
  if (lane == 0) sh[wave] = s;
  __syncthreads();
  if (tid == 0) dis1[r] = rsqrtf(sh[0] + sh[1] + sh[2] + sh[3] + 2.0f);
}

// ---------------- SpMM with fused source scaling ----------------
static __global__ void spmm_sc_k(const int* __restrict__ start, const int* __restrict__ idx,
                                 const float* __restrict__ xw, const float* __restrict__ dis,
                                 float* __restrict__ out, int F) {
  int row = blockIdx.x;
  int b = start[row], e = start[row + 1];
  int f = threadIdx.x;  // blockDim == F
  __shared__ int nb[256];
  __shared__ float nd[256];
  float acc = 0.f;
  for (int t0 = b; t0 < e; t0 += blockDim.x) {
    int m = min((int)blockDim.x, e - t0);
    __syncthreads();
    if (f < m) { int s = idx[t0 + f]; nb[f] = s; nd[f] = dis[s]; }
    __syncthreads();
    for (int t = 0; t < m; ++t) acc += xw[(size_t)nb[t] * F + f] * nd[t];
  }
  out[(size_t)row * F + f] = acc;
}

// ---------------- converters ----------------
static __global__ void conv_hilo_k(const float* __restrict__ in, int R, int C, int Cp,
                                   __bf16* __restrict__ oh, __bf16* __restrict__ ol) {
  int idx = blockIdx.x * blockDim.x + threadIdx.x;
  if (idx < R * Cp) {
    int r = idx / Cp, c = idx - r * Cp;
    float v = (c < C) ? in[(size_t)r * C + c] : 0.f;
    __bf16 h = (__bf16)v;
    oh[idx] = h;
    if (ol) ol[idx] = (__bf16)(v - (float)h);
  }
}

// batched weight transpose+hilo: 7 descriptors, grid.z selects
struct TDesc { const float* in; __bf16* oh; __bf16* ol; int R, C, Rp; };
struct TDescs { TDesc d[7]; };
static __global__ __launch_bounds__(256) void wtconv_k(TDescs ds) {
  TDesc d = ds.d[blockIdx.z];
  int r0 = blockIdx.x * 32, c0 = blockIdx.y * 32;
  if (r0 >= d.Rp || c0 >= d.C) return;
  __shared__ float t[32][33];
  int lr = threadIdx.x >> 5, lc = threadIdx.x & 31;
#pragma unroll
  for (int i = 0; i < 4; ++i) {
    int r = r0 + lr + i * 8, c = c0 + lc;
    t[lr + i * 8][lc] = (r < d.R && c < d.C) ? d.in[(size_t)r * d.C + c] : 0.f;
  }
  __syncthreads();
#pragma unroll
  for (int i = 0; i < 4; ++i) {
    int c = c0 + lr + i * 8, r = r0 + lc;
    if (c < d.C) {
      float v = t[lc][lr + i * 8];
      __bf16 h = (__bf16)v;
      d.oh[(size_t)c * d.Rp + r] = h;
      d.ol[(size_t)c * d.Rp + r] = (__bf16)(v - (float)h);
    }
  }
}

// bf16 transpose (optional lo pair): out[c][r] = (r < Rin) ? in[r][c] : 0
static __global__ __launch_bounds__(256) void btrans_k(const __bf16* __restrict__ ih,
                                                       const __bf16* __restrict__ il,
                                                       __bf16* __restrict__ oh, __bf16* __restrict__ ol,
                                                       int Rin, int Ls, int Cout, int Lo) {
  __shared__ __bf16 th[32][40], tl[32][40];
  int r0 = blockIdx.x * 32, c0 = blockIdx.y * 32;
  int lr = threadIdx.x >> 5, lc = threadIdx.x & 31;
#pragma unroll
  for (int i = 0; i < 4; ++i) {
    int r = r0 + lr + i * 8, c = c0 + lc;
    bool ok = (r < Rin);
    th[lr + i * 8][lc] = ok ? ih[(size_t)r * Ls + c] : (__bf16)0.f;
    if (il) tl[lr + i * 8][lc] = ok ? il[(size_t)r * Ls + c] : (__bf16)0.f;
  }
  __syncthreads();
#pragma unroll
  for (int i = 0; i < 4; ++i) {
    int c = c0 + lr + i * 8, r = r0 + lc;
    if (c < Cout) {
      oh[(size_t)c * Lo + r] = th[lc][lr + i * 8];
      if (ol) ol[(size_t)c * Lo + r] = tl[lc][lr + i * 8];
    }
  }
}

// fused: reduce split-K partials -> xw f32 [R][C], and transposed dis-scaled hi/lo [C][Rp]
static __global__ __launch_bounds__(256) void redtconv_k(const float* __restrict__ Cp, int ks, int mn,
                                                         int R, int C, int Rp,
                                                         __bf16* __restrict__ oh, __bf16* __restrict__ ol,
                                                         const float* __restrict__ disv,
                                                         float* __restrict__ xw_out) {
  __shared__ float t[32][33];
  int r0 = blockIdx.x * 32, c0 = blockIdx.y * 32;
  int lr = threadIdx.x >> 5, lc = threadIdx.x & 31;
#pragma unroll
  for (int i = 0; i < 4; ++i) {
    int r = r0 + lr + i * 8, c = c0 + lc;
    float v = 0.f;
    if (r < R && c < C) {
      size_t idx = (size_t)r * C + c;
      for (int z = 0; z < ks; ++z) v += Cp[(size_t)z * mn + idx];
      xw_out[idx] = v;
    }
    t[lr + i * 8][lc] = v;
  }
  __syncthreads();
#pragma unroll
  for (int i = 0; i < 4; ++i) {
    int c = c0 + lr + i * 8, r = r0 + lc;
    if (c < C) {
      float v = t[lc][lr + i * 8];
      if (r < R) v *= disv[r];
      __bf16 h = (__bf16)v;
      oh[(size_t)c * Rp + r] = h;
      ol[(size_t)c * Rp + r] = (__bf16)(v - (float)h);
    }
  }
}

// gather rows for 1-seg pair (level-2 aug); +2I exact
static __global__ void grows2_k(const __bf16* __restrict__ s1, const __bf16* __restrict__ s2,
                                const int* __restrict__ perm, __bf16* __restrict__ d1,
                                __bf16* __restrict__ d2, int k, int L) {
  int idx = blockIdx.x * blockDim.x + threadIdx.x;
  int nv = L >> 3;
  if (idx < k * nv) {
    int r = idx / nv, c8 = (idx - r * nv) << 3;
    int sr = perm[r];
    bf16x8 v1 = *(const bf16x8*)(s1 + (size_t)sr * L + c8);
    bf16x8 v2 = *(const bf16x8*)(s2 + (size_t)sr * L + c8);
    if (sr >= c8 && sr < c8 + 8) v2[sr - c8] = (__bf16)((float)v2[sr - c8] + 2.0f);
    *(bf16x8*)(d1 + (size_t)r * L + c8) = v1;
    *(bf16x8*)(d2 + (size_t)r * L + c8) = v2;
  }
}

// gather rows for hi/lo pairs (level-3 aug); +2I with exact re-split
static __global__ void grows4_k(const __bf16* __restrict__ ah, const __bf16* __restrict__ al,
                                const __bf16* __restrict__ bh, const __bf16* __restrict__ bl,
                                const int* __restrict__ perm,
                                __bf16* __restrict__ dah, __bf16* __restrict__ dal,
                                __bf16* __restrict__ dbh, __bf16* __restrict__ dbl,
                                int k, int L) {
  int idx = blockIdx.x * blockDim.x + threadIdx.x;
  int nv = L >> 3;
  if (idx < k * nv) {
    int r = idx / nv, c8 = (idx - r * nv) << 3;
    int sr = perm[r];
    bf16x8 vah = *(const bf16x8*)(ah + (size_t)sr * L + c8);
    bf16x8 val = *(const bf16x8*)(al + (size_t)sr * L + c8);
    bf16x8 vbh = *(const bf16x8*)(bh + (size_t)sr * L + c8);
    bf16x8 vbl = *(const bf16x8*)(bl + (size_t)sr * L + c8);
    if (sr >= c8 && sr < c8 + 8) {
      int e = sr - c8;
      float v = (float)vbh[e] + (float)vbl[e] + 2.0f;
      __bf16 h = (__bf16)v;
      vbh[e] = h;
      vbl[e] = (__bf16)(v - (float)h);
    }
    *(bf16x8*)(dah + (size_t)r * L + c8) = vah;
    *(bf16x8*)(dal + (size_t)r * L + c8) = val;
    *(bf16x8*)(dbh + (size_t)r * L + c8) = vbh;
    *(bf16x8*)(dbl + (size_t)r * L + c8) = vbl;
  }
}

static __global__ void ghilo_k(const float* __restrict__ src, const int* __restrict__ perm,
                               const float* __restrict__ sv, __bf16* __restrict__ oh,
                               __bf16* __restrict__ ol, int k) {
  int idx = blockIdx.x * blockDim.x + threadIdx.x;
  if (idx < k * HIDF) {
    int r = idx >> 8;
    float v = src[(size_t)perm[r] * HIDF + (idx & 255)] * sv[r];
    __bf16 h = (__bf16)v;
    oh[idx] = h;
    ol[idx] = (__bf16)(v - (float)h);
  }
}

// ---------------- MFMA GEMM: split-K partials, global_load_lds, double-buffered ----------------
template <int BM, int BN>
static __global__ __launch_bounds__(256) void mgemm_k(
    const __bf16* __restrict__ A0, const __bf16* __restrict__ A1g, const __bf16* __restrict__ A2g,
    const __bf16* __restrict__ B0, const __bf16* __restrict__ B1g, const __bf16* __restrict__ B2g,
    int nseg, float* __restrict__ Cp, int M, int N, int Kp, int kchunk) {
  constexpr int FM = BM / 32, FN = BN / 32;
  __shared__ __bf16 As[2][BM * 64];
  __shared__ __bf16 Bs[2][BN * 64];
  int tid = threadIdx.x;
  int lane = tid & 63, wave = tid >> 6;
  int wx = wave & 1, wy = wave >> 1;
  int l15 = lane & 15, l4 = lane >> 4;
  int brow = blockIdx.y * BM, bcol = blockIdx.x * BN;
  int wrow = wy * (BM / 2), wcol = wx * (BN / 2);
  int srow = lane >> 3, slot = lane & 7;
  int k_beg = blockIdx.z * kchunk;
  int ksteps = kchunk >> 6;
  int nsteps = nseg * ksteps;
  const __bf16* segA[3] = {A0, A1g, A2g};
  const __bf16* segB[3] = {B0, B1g, B2g};

  auto stage = [&](int buf, int t) {
    int seg = t / ksteps;
    int k0 = k_beg + ((t - seg * ksteps) << 6);
    const __bf16* Ag = segA[seg];
    const __bf16* Bg = segB[seg];
#pragma unroll
    for (int i = 0; i < BM / 32; ++i) {
      int rl = (i * 4 + wave) * 8 + srow;
      int gr = brow + rl;
      if (gr >= M) gr = M - 1;
      int col = k0 + ((slot ^ (rl & 7)) << 3);
      GLDS16(Ag + (size_t)gr * Kp + col, &As[buf][(i * 4 + wave) * 8 * 64]);
    }
#pragma unroll
    for (int i = 0; i < BN / 32; ++i) {
      int rl = (i * 4 + wave) * 8 + srow;
      int gc = bcol + rl;
      if (gc >= N) gc = N - 1;
      int col = k0 + ((slot ^ (rl & 7)) << 3);
      GLDS16(Bg + (size_t)gc * Kp + col, &Bs[buf][(i * 4 + wave) * 8 * 64]);
    }
  };

  f32x4 acc[FM][FN] = {};
  stage(0, 0);
  __syncthreads();
  int cur = 0;
  for (int t = 0; t < nsteps; ++t) {
    if (t + 1 < nsteps) stage(cur ^ 1, t + 1);
#pragma unroll
    for (int sub = 0; sub < 2; ++sub) {
      bf16x8 af[FM], bfv[FN];
#pragma unroll
      for (int i = 0; i < FM; ++i) {
        int r = wrow + i * 16 + l15;
        af[i] = *(const bf16x8*)(&As[cur][r * 64 + (((sub * 4 + l4) ^ (r & 7)) << 3)]);
      }
#pragma unroll
      for (int j = 0; j < FN; ++j) {
        int r = wcol + j * 16 + l15;
        bfv[j] = *(const bf16x8*)(&Bs[cur][r * 64 + (((sub * 4 + l4) ^ (r & 7)) << 3)]);
      }
#pragma unroll
      for (int i = 0; i < FM; ++i)
#pragma unroll
        for (int j = 0; j < FN; ++j)
          acc[i][j] = __builtin_amdgcn_mfma_f32_16x16x32_bf16(af[i], bfv[j], acc[i][j], 0, 0, 0);
    }
    __syncthreads();
    cur ^= 1;
  }
  size_t zoff = (size_t)blockIdx.z * M * N;
#pragma unroll
  for (int i = 0; i < FM; ++i)
#pragma unroll
    for (int j = 0; j < FN; ++j) {
      int col = bcol + wcol + j * 16 + l15;
      if (col < N) {
#pragma unroll
        for (int q = 0; q < 4; ++q) {
          int row = brow + wrow + i * 16 + l4 * 4 + q;
          if (row < M) Cp[zoff + (size_t)row * N + col] = acc[i][j][q];
        }
      }
    }
}

// ---------------- reductions / epilogues ----------------
static __global__ void reduce_k(const float* __restrict__ p, int ks, int mn, float* __restrict__ out) {
  int idx = blockIdx.x * blockDim.x + threadIdx.x;
  if (idx < mn) {
    float s = 0.f;
    for (int z = 0; z < ks; ++z) s += p[(size_t)z * mn + idx];
    out[idx] = s;
  }
}

static __global__ void conv_epi_k(const float* __restrict__ zp, int ks, int mn,
                                  const float* __restrict__ xw, const float* __restrict__ dis,
                                  const float* __restrict__ b, float* __restrict__ out,
                                  int n, int f, int relu) {
  int idx = blockIdx.x * blockDim.x + threadIdx.x;
  if (idx < n * f) {
    float zv = 0.f;
    for (int z = 0; z < ks; ++z) zv += zp[(size_t)z * mn + idx];
    int i = idx / f, j = idx - i * f;
    float di = dis[i];
    float v = di * zv + 2.0f * di * di * xw[idx] + b[j];
    if (relu) v = fmaxf(v, 0.0f);
    out[idx] = v;
  }
}

// split-K reduce + zero diag + rowsum->dis + hi/lo bf16 (padded)
static __global__ __launch_bounds__(256) void aug_epi_k(const float* __restrict__ Cp, int ks, int mn,
                                                        int n, int Kpad,
                                                        __bf16* __restrict__ bh, __bf16* __restrict__ bl,
                                                        float* __restrict__ dis) {
  __shared__ float sh[4];
  int r = blockIdx.x;
  int tid = threadIdx.x, lane = tid & 63, wave = tid >> 6;
  float ssum = 0.f;
  for (int c = tid; c < Kpad; c += 256) {
    float v = 0.f;
    if (c < n && c != r)
      for (int z = 0; z < ks; ++z) v += Cp[(size_t)z * mn + (size_t)r * n + c];
    __bf16 h = (__bf16)v;
    bh[(size_t)r * Kpad + c] = h;
    bl[(size_t)r * Kpad + c] = (__bf16)(v - (float)h);
    ssum += v;
  }
#pragma unroll
  for (int o = 32; o > 0; o >>= 1) ssum += __shfl_down(ssum, o, 64);
  if (lane == 0) sh[wave] = ssum;
  __syncthreads();
  if (tid == 0) dis[r] = rsqrtf(sh[0] + sh[1] + sh[2] + sh[3] + 2.0f);
}

// ---------------- pooling ----------------
static __global__ void score_k(const float* __restrict__ x, const float* __restrict__ w,
                               float* __restrict__ sc, int f) {
  int row = blockIdx.x;
  float s = 0.f, q = 0.f;
  for (int j = threadIdx.x; j < f; j += blockDim.x) {
    float wv = w[j];
    q += wv * wv;
    s += x[(size_t)row * f + j] * wv;
  }
  __shared__ float sh[8], sh2[8];
  int lane = threadIdx.x & 63, wid = threadIdx.x >> 6;
#pragma unroll
  for (int o = 32; o > 0; o >>= 1) { s += __shfl_down(s, o, 64); q += __shfl_down(q, o, 64); }
  if (lane == 0) { sh[wid] = s; sh2[wid] = q; }
  __syncthreads();
  if (threadIdx.x == 0) {
    float t = 0.f, t2 = 0.f;
    int nw = (blockDim.x + 63) >> 6;
    for (int w2 = 0; w2 < nw; ++w2) { t += sh[w2]; t2 += sh2[w2]; }
    sc[row] = tanhf(t / sqrtf(t2));
  }
}

// exact jax.lax.top_k: wave-per-candidate; also writes pos[]
static __global__ __launch_bounds__(256) void topk_rank_k(const float* __restrict__ sc, int n, int k,
                                                          int* __restrict__ perm, float* __restrict__ sv,
                                                          int* __restrict__ pos) {
  __shared__ float s[N0 + 8];
  int tid = threadIdx.x, lane = tid & 63, wave = tid >> 6;
  for (int i = tid; i < n; i += 256) s[i] = sc[i];
  __syncthreads();
  int i = blockIdx.x * 4 + wave;
  if (i < n) {
    float si = s[i];
    int rank = 0;
    for (int j = lane; j < n; j += 64) {
      float sj = s[j];
      rank += (sj > si) || (sj == si && j < i);
    }
#pragma unroll
    for (int o = 32; o > 0; o >>= 1) rank += __shfl_down(rank, o, 64);
    if (lane == 0) {
      pos[i] = (rank < k) ? rank : -1;
      if (rank < k) { perm[rank] = i; sv[rank] = si; }
    }
  }
}

static __global__ void unpool_hilo_k(const float* __restrict__ base, const float* __restrict__ up,
                                     const int* __restrict__ pos, __bf16* __restrict__ oh,
                                     __bf16* __restrict__ ol, int n) {
  int idx = blockIdx.x * blockDim.x + threadIdx.x;
  if (idx < n * HIDF) {
    int i = idx >> 8;
    int p = pos[i];
    float v = base[idx] + (p >= 0 ? up[(size_t)p * HIDF + (idx & 255)] : 0.f);
    __bf16 h = (__bf16)v;
    oh[idx] = h;
    ol[idx] = (__bf16)(v - (float)h);
  }
}

// fused final epilogue + log_softmax (f == OUTC == 64, one wave per row)
static __global__ void epilsm_k(const float* __restrict__ zb, const float* __restrict__ xw,
                                const float* __restrict__ dis, const float* __restrict__ b,
                                float* __restrict__ out) {
  int r = blockIdx.x, j = threadIdx.x;
  float di = dis[r];
  float v = di * zb[r * OUTC + j] + 2.0f * di * di * xw[r * OUTC + j] + b[j];
  float m = v;
#pragma unroll
  for (int o = 32; o > 0; o >>= 1) m = fmaxf(m, __shfl_xor(m, o, 64));
  float e = expf(v - m), s = e;
#pragma unroll
  for (int o = 32; o > 0; o >>= 1) s += __shfl_xor(s, o, 64);
  out[r * OUTC + j] = v - m - logf(s);
}

// ---------------- host ----------------
extern "C" void kernel_launch(void* const* d_in, const int* in_sizes, int n_in,
                              void* d_out, int out_size, void* d_ws, size_t ws_size,
                              hipStream_t stream) {
  const float* x  = (const float*)d_in[0];
  const int* ei   = (const int*)d_in[1];
  const float* W0 = (const float*)d_in[2];
  const float* b0 = (const float*)d_in[3];
  const float* W1 = (const float*)d_in[4];
  const float* b1 = (const float*)d_in[5];
  const float* W2 = (const float*)d_in[6];
  const float* b2 = (const float*)d_in[7];
  const float* W3 = (const float*)d_in[8];
  const float* b3 = (const float*)d_in[9];
  const float* p1 = (const float*)d_in[10];
  const float* p2 = (const float*)d_in[11];
  const float* p3 = (const float*)d_in[12];
  const float* U0 = (const float*)d_in[13];
  const float* c0 = (const float*)d_in[14];
  const float* U1 = (const float*)d_in[15];
  const float* c1 = (const float*)d_in[16];
  const float* U2 = (const float*)d_in[17];
  const float* c2 = (const float*)d_in[18];
  (void)in_sizes; (void)n_in; (void)out_size; (void)ws_size;

  char* basep = (char*)d_ws;
  size_t off = 0;
  auto alloc = [&](size_t bytes) {
    void* p = basep + off;
    off += (bytes + 255) & ~(size_t)255;
    return p;
  };

  // fp32
  float* xw  = (float*)alloc((size_t)N0 * HIDF * 4);
  float* zb  = (float*)alloc((size_t)N0 * HIDF * 4);
  float* x0  = (float*)alloc((size_t)N0 * HIDF * 4);
  float* x1  = (float*)alloc((size_t)KP1 * HIDF * 4);
  float* x2  = (float*)alloc((size_t)KP2 * HIDF * 4);
  float* x3  = (float*)alloc((size_t)KP3 * HIDF * 4);
  float* hb  = (float*)alloc((size_t)N0 * HIDF * 4);
  float* Cpart = (float*)alloc((size_t)20 * 1024 * 1024);  // split-K partials (max 16 MB)
  // bf16
  __bf16* bfAh = (__bf16*)alloc((size_t)N0 * INC * 2);
  __bf16* bfAl = (__bf16*)alloc((size_t)N0 * INC * 2);
  __bf16* bfBh = (__bf16*)alloc((size_t)HIDF * KP1P * 2);
  __bf16* bfBl = (__bf16*)alloc((size_t)HIDF * KP1P * 2);
  __bf16* A1bf  = (__bf16*)alloc((size_t)KP1 * KP1P * 2);
  __bf16* A1tbf = (__bf16*)alloc((size_t)KP1 * KP1P * 2);
  __bf16* Ag    = (__bf16*)alloc((size_t)KP2 * KP1P * 2);
  __bf16* Bg    = (__bf16*)alloc((size_t)KP2 * KP1P * 2);
  __bf16* A2bh  = (__bf16*)alloc((size_t)KP2 * KP2P * 2);
  __bf16* A2bl  = (__bf16*)alloc((size_t)KP2 * KP2P * 2);
  __bf16* A2tbh = (__bf16*)alloc((size_t)KP2 * KP2P * 2);
  __bf16* A2tbl = (__bf16*)alloc((size_t)KP2 * KP2P * 2);
  __bf16* Agh   = (__bf16*)alloc((size_t)KP3 * KP2P * 2);
  __bf16* Agl   = (__bf16*)alloc((size_t)KP3 * KP2P * 2);
  __bf16* Bgh   = (__bf16*)alloc((size_t)KP3 * KP2P * 2);
  __bf16* Bgl   = (__bf16*)alloc((size_t)KP3 * KP2P * 2);
  __bf16* A3bh  = (__bf16*)alloc((size_t)KP3 * KP3P * 2);
  __bf16* A3bl  = (__bf16*)alloc((size_t)KP3 * KP3P * 2);
  // weight operands (persist per call)
  __bf16* w0h = (__bf16*)alloc((size_t)HIDF * 512 * 2);
  __bf16* w0l = (__bf16*)alloc((size_t)HIDF * 512 * 2);
  __bf16* w1h = (__bf16*)alloc((size_t)HIDF * 256 * 2);
  __bf16* w1l = (__bf16*)alloc((size_t)HIDF * 256 * 2);
  __bf16* w2h = (__bf16*)alloc((size_t)HIDF * 256 * 2);
  __bf16* w2l = (__bf16*)alloc((size_t)HIDF * 256 * 2);
  __bf16* w3h = (__bf16*)alloc((size_t)HIDF * 256 * 2);
  __bf16* w3l = (__bf16*)alloc((size_t)HIDF * 256 * 2);
  __bf16* u0h = (__bf16*)alloc((size_t)HIDF * 256 * 2);
  __bf16* u0l = (__bf16*)alloc((size_t)HIDF * 256 * 2);
  __bf16* u1h = (__bf16*)alloc((size_t)HIDF * 256 * 2);
  __bf16* u1l = (__bf16*)alloc((size_t)HIDF * 256 * 2);
  __bf16* u2h = (__bf16*)alloc((size_t)OUTC * 256 * 2);
  __bf16* u2l = (__bf16*)alloc((size_t)OUTC * 256 * 2);
  // small
  float* sc   = (float*)alloc(N0 * 4);
  float* sv   = (float*)alloc(KP1 * 4);
  int* perm1  = (int*)alloc(KP1 * 4);
  int* perm2  = (int*)alloc(KP2 * 4);
  int* perm3  = (int*)alloc(KP3 * 4);
  int* pos1   = (int*)alloc(N0 * 4);
  int* pos2   = (int*)alloc(KP1 * 4);
  int* pos3   = (int*)alloc(KP2 * 4);
  float* dis0 = (float*)alloc(N0 * 4);
  float* dis1 = (float*)alloc(KP1 * 4);
  float* dis2 = (float*)alloc(KP2 * 4);
  float* dis3 = (float*)alloc(KP3 * 4);
  int* cf     = (int*)alloc((size_t)2 * 3072 * 4);  // cnt_d | fl_d, one memset
  int* cnt_d  = cf;
  int* fl_d   = cf + 3072;
  int* st_d   = (int*)alloc((N0 + 4) * 4);
  int* bk_d   = (int*)alloc(NE * 4);

  auto mg = [&](int bm, int bn, const __bf16* a0, const __bf16* a1, const __bf16* a2,
                const __bf16* bb0, const __bf16* bb1, const __bf16* bb2,
                int nseg, int M, int N, int Kp, int ks, int kchunk) {
    dim3 g((N + bn - 1) / bn, (M + bm - 1) / bm, ks);
    if (bm == 128 && bn == 128)
      mgemm_k<128, 128><<<g, 256, 0, stream>>>(a0, a1, a2, bb0, bb1, bb2, nseg, Cpart, M, N, Kp, kchunk);
    else if (bm == 128)
      mgemm_k<128, 64><<<g, 256, 0, stream>>>(a0, a1, a2, bb0, bb1, bb2, nseg, Cpart, M, N, Kp, kchunk);
    else
      mgemm_k<64, 64><<<g, 256, 0, stream>>>(a0, a1, a2, bb0, bb1, bb2, nseg, Cpart, M, N, Kp, kchunk);
  };

  // weight GEMM into Cpart (bfAh/bfAl hold hi/lo A [n][Kp])
  auto wgemm = [&](const __bf16* wh, const __bf16* wl, int fin, int fout, int n, int bm,
                   int ks, int kchunk) {
    int Kp = (fin + 63) & ~63;
    mg(bm, 64, bfAh, bfAh, bfAl, wh, wl, wh, 3, n, fout, Kp, ks, kchunk);
  };

  // dense conv tail: redtconv -> prop mgemm -> epi
  auto prop = [&](int ksw, const __bf16* Abh, const __bf16* Abl, int asegs, int n, int Kp, int bm,
                  int ks, int kchunk, const float* disv, const float* bias, float* outx, int relu) {
    dim3 tg(Kp / 32, HIDF / 32);
    redtconv_k<<<tg, 256, 0, stream>>>(Cpart, ksw, n * HIDF, n, HIDF, Kp, bfBh, bfBl, disv, xw);
    if (asegs == 1) mg(bm, 64, Abh, Abh, nullptr, bfBh, bfBl, nullptr, 2, n, HIDF, Kp, ks, kchunk);
    else            mg(bm, 64, Abh, Abh, Abl, bfBh, bfBl, bfBh, 3, n, HIDF, Kp, ks, kchunk);
    conv_epi_k<<<(n * HIDF + 255) / 256, 256, 0, stream>>>(Cpart, ks, n * HIDF, xw, disv, bias,
                                                           outx, n, HIDF, relu);
  };

  auto pool = [&](const float* xfeat, int n, const float* p, int k, int* perm, int* pos) {
    score_k<<<n, 256, 0, stream>>>(xfeat, p, sc, HIDF);
    topk_rank_k<<<(n + 3) / 4, 256, 0, stream>>>(sc, n, k, perm, sv, pos);
  };

  // ---- CSR build + all weight conversions ----
  hipMemsetAsync(cf, 0, (size_t)2 * 3072 * 4, stream);
  count_k<<<(NE + 255) / 256, 256, 0, stream>>>(ei, cnt_d);
  {
    TDescs ds;
    ds.d[0] = {W0, w0h, w0l, INC, HIDF, 512};
    ds.d[1] = {W1, w1h, w1l, HIDF, HIDF, 256};
    ds.d[2] = {W2, w2h, w2l, HIDF, HIDF, 256};
    ds.d[3] = {W3, w3h, w3l, HIDF, HIDF, 256};
    ds.d[4] = {U0, u0h, u0l, HIDF, HIDF, 256};
    ds.d[5] = {U1, u1h, u1l, HIDF, HIDF, 256};
    ds.d[6] = {U2, u2h, u2l, HIDF, OUTC, 256};
    wtconv_k<<<dim3(16, 8, 7), 256, 0, stream>>>(ds);
  }
  scan_excl_k<<<1, 1024, 0, stream>>>(cnt_d, st_d, N0, dis0);
  scatter_k<<<(NE + 255) / 256, 256, 0, stream>>>(ei, st_d, fl_d, bk_d);

  // ---- down conv 0 (sparse propagation) ----
  conv_hilo_k<<<((size_t)N0 * INC + 255) / 256, 256, 0, stream>>>(x, N0, INC, INC, bfAh, bfAl);
  wgemm(w0h, w0l, INC, HIDF, N0, 128, 4, 128);
  reduce_k<<<(N0 * HIDF + 255) / 256, 256, 0, stream>>>(Cpart, 4, N0 * HIDF, xw);
  spmm_sc_k<<<N0, HIDF, 0, stream>>>(st_d, bk_d, xw, dis0, zb, HIDF);
  conv_epi_k<<<(N0 * HIDF + 255) / 256, 256, 0, stream>>>(zb, 1, 0, xw, dis0, b0, x0, N0, HIDF, 1);

  // ---- pool 1 + masked augment(A) ----
  pool(x0, N0, p1, KP1, perm1, pos1);
  augA_masked_k<<<KP1, 256, 0, stream>>>(st_d, bk_d, perm1, pos1, A1bf, dis1);

  // ---- conv 1 ----
  ghilo_k<<<((size_t)KP1 * HIDF + 255) / 256, 256, 0, stream>>>(x0, perm1, sv, bfAh, bfAl, KP1);
  wgemm(w1h, w1l, HIDF, HIDF, KP1, 128, 4, 64);
  prop(4, A1bf, nullptr, 1, KP1, KP1P, 128, 4, 512, dis1, b1, x1, 1);

  // ---- pool 2 + masked augment(A1): A2 = A1[perm2,:] @ (A1+2I)[:,perm2] ----
  pool(x1, KP1, p2, KP2, perm2, pos2);
  btrans_k<<<dim3(KP1P / 32, (KP1 + 31) / 32), 256, 0, stream>>>(A1bf, nullptr, A1tbf, nullptr,
                                                                 KP1, KP1P, KP1, KP1P);
  grows2_k<<<((size_t)KP2 * (KP1P / 8) + 255) / 256, 256, 0, stream>>>(A1bf, A1tbf, perm2, Ag, Bg,
                                                                       KP2, KP1P);
  mg(128, 128, Ag, nullptr, nullptr, Bg, nullptr, nullptr, 1, KP2, KP2, KP1P, 4, 512);
  aug_epi_k<<<KP2, 256, 0, stream>>>(Cpart, 4, KP2 * KP2, KP2, KP2P, A2bh, A2bl, dis2);

  // ---- conv 2 ----
  ghilo_k<<<((size_t)KP2 * HIDF + 255) / 256, 256, 0, stream>>>(x1, perm2, sv, bfAh, bfAl, KP2);
  wgemm(w2h, w2l, HIDF, HIDF, KP2, 64, 4, 64);
  prop(4, A2bh, A2bl, 2, KP2, KP2P, 128, 8, 128, dis2, b2, x2, 1);

  // ---- pool 3 + masked augment(A2), hi/lo 3-seg ----
  pool(x2, KP2, p3, KP3, perm3, pos3);
  btrans_k<<<dim3(KP2P / 32, (KP2 + 31) / 32), 256, 0, stream>>>(A2bh, A2bl, A2tbh, A2tbl,
                                                                 KP2, KP2P, KP2, KP2P);
  grows4_k<<<((size_t)KP3 * (KP2P / 8) + 255) / 256, 256, 0, stream>>>(
      A2bh, A2bl, A2tbh, A2tbl, perm3, Agh, Agl, Bgh, Bgl, KP3, KP2P);
  mg(64, 64, Agh, Agh, Agl, Bgh, Bgl, Bgh, 3, KP3, KP3, KP2P, 4, 256);
  aug_epi_k<<<KP3, 256, 0, stream>>>(Cpart, 4, KP3 * KP3, KP3, KP3P, A3bh, A3bl, dis3);

  // ---- conv 3 ----
  ghilo_k<<<((size_t)KP3 * HIDF + 255) / 256, 256, 0, stream>>>(x2, perm3, sv, bfAh, bfAl, KP3);
  wgemm(w3h, w3l, HIDF, HIDF, KP3, 64, 4, 64);
  prop(4, A3bh, A3bl, 2, KP3, KP3P, 64, 8, 64, dis3, b3, x3, 1);

  // ---- up path ----
  unpool_hilo_k<<<(KP2 * HIDF + 255) / 256, 256, 0, stream>>>(x2, x3, pos3, bfAh, bfAl, KP2);
  wgemm(u0h, u0l, HIDF, HIDF, KP2, 64, 4, 64);
  prop(4, A2bh, A2bl, 2, KP2, KP2P, 128, 8, 128, dis2, c0, hb, 1);

  unpool_hilo_k<<<(KP1 * HIDF + 255) / 256, 256, 0, stream>>>(x1, hb, pos2, bfAh, bfAl, KP1);
  wgemm(u1h, u1l, HIDF, HIDF, KP1, 128, 4, 64);
  prop(4, A1bf, nullptr, 1, KP1, KP1P, 128, 4, 512, dis1, c1, hb, 1);

  unpool_hilo_k<<<(N0 * HIDF + 255) / 256, 256, 0, stream>>>(x0, hb, pos1, bfAh, bfAl, N0);
  wgemm(u2h, u2l, HIDF, OUTC, N0, 64, 4, 64);
  reduce_k<<<(N0 * OUTC + 255) / 256, 256, 0, stream>>>(Cpart, 4, N0 * OUTC, xw);
  spmm_sc_k<<<N0, OUTC, 0, stream>>>(st_d, bk_d, xw, dis0, zb, OUTC);
  epilsm_k<<<N0, OUTC, 0, stream>>>(zb, xw, dis0, c2, (float*)d_out);
}